// Round 9
// baseline (215.889 us; speedup 1.0000x reference)
//
#include <hip/hip_runtime.h>
#include <hip/hip_bf16.h>
#include <math.h>

#define N_NODES 50000
#define N_EDGES 800000
#define F_IN 256
#define HID 32
#define HEADS 4
#define HC 128            // HID*HEADS
#define CLASSES 40
#define LAYERS 2
#define SLOPE 0.1f
#define EE (N_EDGES + N_NODES)   // edges + self loops

#define BSHIFT 9
#define NBUCK 98          // ceil(50000 / 512)
#define CHUNK 4096        // edges per block in bucket passes
#define NBLK_E ((EE + CHUNK - 1) / CHUNK)

typedef unsigned short ushortT;
typedef unsigned int uintT;
typedef __attribute__((ext_vector_type(8))) short short8v;   // 8 bf16 = 4 VGPRs
typedef __attribute__((ext_vector_type(4))) float f32x4;

__device__ __forceinline__ ushortT f2bu(float f) {
    __hip_bfloat16 h = __float2bfloat16(f);
    ushortT u; __builtin_memcpy(&u, &h, 2); return u;
}

// ---------- weight transpose+convert: W[K][128] fp32 -> WT[128][K] bf16 ----------
__global__ void wconv(const float* __restrict__ W, ushortT* __restrict__ WT, int K) {
    int i = blockIdx.x * 256 + threadIdx.x;
    if (i >= K * 128) return;
    int r = i >> 7, c = i & 127;
    WT[(size_t)c * K + r] = f2bu(W[i]);
}

// Wout[128][40] fp32 -> WT[48][128] bf16, cols 40..47 zero
__global__ void wconv_cls(const float* __restrict__ W, ushortT* __restrict__ WT) {
    int i = blockIdx.x * 256 + threadIdx.x;
    if (i >= 48 * 128) return;
    int c = i >> 7, k = i & 127;
    WT[i] = (c < CLASSES) ? f2bu(W[k * CLASSES + c]) : (ushortT)0;
}

// ---------- MFMA bf16 GEMM, N fixed 128, optional fused attention-dot epilogue ----------
#define AS_LD 40
template<bool AF32>
__global__ __launch_bounds__(256) void gemm_mfma(const void* __restrict__ Aptr,
                                                 const ushortT* __restrict__ BT,
                                                 ushortT* __restrict__ Cb,
                                                 const float* __restrict__ att,  // may be null
                                                 float* __restrict__ asrc,
                                                 float* __restrict__ adst,
                                                 int M, int K) {
    __shared__ ushortT As[64 * AS_LD];    // [row][k<32]
    __shared__ ushortT Bs[128 * AS_LD];   // [col][k<32]
    int t = threadIdx.x;
    int w = t >> 6, lane = t & 63;
    int row0 = blockIdx.x * 64;
    int ar = t >> 2, ak = (t & 3) * 8;
    int bcol = t >> 1, bks = (t & 1) * 16;
    int wr = w * 16;
    int arow = wr + (lane & 15);
    int ak8 = (lane >> 4) * 8;
    f32x4 acc[8] = {};

    for (int k0 = 0; k0 < K; k0 += 32) {
        int grow = row0 + ar;
        if (AF32) {
            const float* A = (const float*)Aptr;
            float4 v0 = make_float4(0.f, 0.f, 0.f, 0.f), v1 = v0;
            if (grow < M) {
                const float* ap = A + (size_t)grow * K + k0 + ak;
                v0 = *(const float4*)ap;
                v1 = *(const float4*)(ap + 4);
            }
            uint4 p;
            p.x = (uintT)f2bu(v0.x) | ((uintT)f2bu(v0.y) << 16);
            p.y = (uintT)f2bu(v0.z) | ((uintT)f2bu(v0.w) << 16);
            p.z = (uintT)f2bu(v1.x) | ((uintT)f2bu(v1.y) << 16);
            p.w = (uintT)f2bu(v1.z) | ((uintT)f2bu(v1.w) << 16);
            *(uint4*)&As[ar * AS_LD + ak] = p;
        } else {
            const ushortT* A = (const ushortT*)Aptr;
            uint4 p = make_uint4(0, 0, 0, 0);
            if (grow < M) p = *(const uint4*)(A + (size_t)grow * K + k0 + ak);
            *(uint4*)&As[ar * AS_LD + ak] = p;
        }
        {
            const ushortT* bp = BT + (size_t)bcol * K + k0 + bks;
            *(uint4*)&Bs[bcol * AS_LD + bks]     = *(const uint4*)bp;
            *(uint4*)&Bs[bcol * AS_LD + bks + 8] = *(const uint4*)(bp + 8);
        }
        __syncthreads();
        short8v a = *(short8v*)&As[arow * AS_LD + ak8];
#pragma unroll
        for (int c = 0; c < 8; ++c) {
            short8v b = *(short8v*)&Bs[(c * 16 + (lane & 15)) * AS_LD + ak8];
            acc[c] = __builtin_amdgcn_mfma_f32_16x16x32_bf16(a, b, acc[c], 0, 0, 0);
        }
        __syncthreads();
    }
    int cl = lane & 15;
    int r0 = row0 + wr + ((lane >> 4) << 2);
#pragma unroll
    for (int c = 0; c < 8; ++c) {
        int cc = c * 16 + cl;
#pragma unroll
        for (int r = 0; r < 4; ++r) {
            int rr = r0 + r;
            if (rr < M) Cb[(size_t)rr * 128 + cc] = f2bu(acc[c][r]);
        }
    }
    // fused attention dots: asrc/adst[row][h] = dot(hp_row[h*32..], att[h][..])
    if (att) {
#pragma unroll
        for (int h = 0; h < HEADS; ++h) {
            float as0 = att[h * 64 + cl];
            float as1 = att[h * 64 + 16 + cl];
            float ad0 = att[h * 64 + 32 + cl];
            float ad1 = att[h * 64 + 48 + cl];
#pragma unroll
            for (int r = 0; r < 4; ++r) {
                float ps = acc[2 * h][r] * as0 + acc[2 * h + 1][r] * as1;
                float pd = acc[2 * h][r] * ad0 + acc[2 * h + 1][r] * ad1;
#pragma unroll
                for (int off = 1; off < 16; off <<= 1) {
                    ps += __shfl_xor(ps, off);
                    pd += __shfl_xor(pd, off);
                }
                int rr = r0 + r;
                if (cl == 0 && rr < M) {
                    asrc[rr * 4 + h] = ps;
                    adst[rr * 4 + h] = pd;
                }
            }
        }
    }
}

// ---------- fused MFMA classifier + in-register log_softmax ----------
__global__ __launch_bounds__(256) void cls_mfma(const ushortT* __restrict__ A,
                                                const ushortT* __restrict__ BT,
                                                float* __restrict__ out, int M) {
    __shared__ ushortT As[64 * AS_LD];
    __shared__ ushortT Bs[48 * AS_LD];
    int t = threadIdx.x;
    int w = t >> 6, lane = t & 63;
    int row0 = blockIdx.x * 64;
    int ar = t >> 2, ak = (t & 3) * 8;
    int wr = w * 16;
    int arow = wr + (lane & 15);
    int ak8 = (lane >> 4) * 8;
    f32x4 acc[3] = {};

    for (int k0 = 0; k0 < 128; k0 += 32) {
        int grow = row0 + ar;
        uint4 p = make_uint4(0, 0, 0, 0);
        if (grow < M) p = *(const uint4*)(A + (size_t)grow * 128 + k0 + ak);
        *(uint4*)&As[ar * AS_LD + ak] = p;
        if (t < 96) {
            int bcol = t >> 1, bks = (t & 1) * 16;
            const ushortT* bp = BT + bcol * 128 + k0 + bks;
            *(uint4*)&Bs[bcol * AS_LD + bks]     = *(const uint4*)bp;
            *(uint4*)&Bs[bcol * AS_LD + bks + 8] = *(const uint4*)(bp + 8);
        }
        __syncthreads();
        short8v a = *(short8v*)&As[arow * AS_LD + ak8];
#pragma unroll
        for (int c = 0; c < 3; ++c) {
            short8v b = *(short8v*)&Bs[(c * 16 + (lane & 15)) * AS_LD + ak8];
            acc[c] = __builtin_amdgcn_mfma_f32_16x16x32_bf16(a, b, acc[c], 0, 0, 0);
        }
        __syncthreads();
    }
    int cl = lane & 15;
    int r0 = row0 + wr + ((lane >> 4) << 2);
#pragma unroll
    for (int r = 0; r < 4; ++r) {
        float v0 = acc[0][r], v1 = acc[1][r];
        float v2 = (cl < 8) ? acc[2][r] : -1e30f;
        float m = fmaxf(fmaxf(v0, v1), v2);
#pragma unroll
        for (int off = 1; off < 16; off <<= 1) m = fmaxf(m, __shfl_xor(m, off));
        float e = __expf(v0 - m) + __expf(v1 - m) + ((cl < 8) ? __expf(v2 - m) : 0.f);
#pragma unroll
        for (int off = 1; off < 16; off <<= 1) e += __shfl_xor(e, off);
        float ls = m + __logf(e);
        int rr = r0 + r;
        if (rr < M) {
            float* o = out + (size_t)rr * CLASSES;
            o[cl] = v0 - ls;
            o[16 + cl] = v1 - ls;
            if (cl < 8) o[32 + cl] = v2 - ls;
        }
    }
}

// ---------- CSR build via two-level bucket sort ----------
__global__ __launch_bounds__(256) void bucket_count(const int* __restrict__ ei,
                                                    int* __restrict__ bcnt) {
    __shared__ int hist[NBUCK];
    int t = threadIdx.x;
    if (t < NBUCK) hist[t] = 0;
    __syncthreads();
    int base = blockIdx.x * CHUNK;
    int end = min(base + CHUNK, EE);
    for (int i = base + t; i < end; i += 256) {
        int d = (i < N_EDGES) ? ei[N_EDGES + i] : (i - N_EDGES);
        atomicAdd(&hist[d >> BSHIFT], 1);
    }
    __syncthreads();
    if (t < NBUCK && hist[t]) atomicAdd(&bcnt[t], hist[t]);
}

__global__ void bucket_scan(const int* __restrict__ bcnt, int* __restrict__ bbase,
                            int* __restrict__ gcur, int* __restrict__ rowptr) {
    if (threadIdx.x == 0) {
        int run = 0;
        for (int b = 0; b < NBUCK; ++b) { bbase[b] = run; gcur[b] = run; run += bcnt[b]; }
        bbase[NBUCK] = run;
        rowptr[N_NODES] = run;   // == EE
    }
}

__global__ __launch_bounds__(256) void bucket_scatter(const int* __restrict__ ei,
                                                      int* __restrict__ gcur,
                                                      uintT* __restrict__ ebuf) {
    __shared__ int hist[NBUCK];
    __shared__ int rbase[NBUCK];
    int t = threadIdx.x;
    if (t < NBUCK) hist[t] = 0;
    __syncthreads();
    int base = blockIdx.x * CHUNK;
    int end = min(base + CHUNK, EE);
    for (int i = base + t; i < end; i += 256) {
        int d = (i < N_EDGES) ? ei[N_EDGES + i] : (i - N_EDGES);
        atomicAdd(&hist[d >> BSHIFT], 1);
    }
    __syncthreads();
    if (t < NBUCK) {
        int c = hist[t];
        rbase[t] = c ? atomicAdd(&gcur[t], c) : 0;
    }
    __syncthreads();
    if (t < NBUCK) hist[t] = 0;
    __syncthreads();
    for (int i = base + t; i < end; i += 256) {
        int s, d;
        if (i < N_EDGES) { s = ei[i]; d = ei[N_EDGES + i]; } else { s = d = i - N_EDGES; }
        int b = d >> BSHIFT;
        int pos = rbase[b] + atomicAdd(&hist[b], 1);
        ebuf[pos] = ((uintT)s << BSHIFT) | (uintT)(d & 511);   // src(16b) | local dst(9b)
    }
}

__global__ __launch_bounds__(256) void csr_local(const uintT* __restrict__ ebuf,
                                                 const int* __restrict__ bbase,
                                                 int* __restrict__ rowptr,
                                                 int* __restrict__ ssrc) {
    __shared__ int cnt[512];
    __shared__ int cur[512];
    __shared__ int wsum[4];
    int b = blockIdx.x;
    int t = threadIdx.x;
    int node0 = b << BSHIFT;
    int nb = min(512, N_NODES - node0);
    int beg = bbase[b], end = bbase[b + 1];
    cnt[t] = 0; cnt[t + 256] = 0;
    __syncthreads();
    for (int i = beg + t; i < end; i += 256)
        atomicAdd(&cnt[ebuf[i] & 511], 1);
    __syncthreads();
    int v0 = cnt[2 * t], v1 = cnt[2 * t + 1];
    int s = v0 + v1;
    int lane = t & 63, w = t >> 6;
    int x = s;
#pragma unroll
    for (int off = 1; off < 64; off <<= 1) { int y = __shfl_up(x, off); if (lane >= off) x += y; }
    if (lane == 63) wsum[w] = x;
    __syncthreads();
    if (t == 0) { int run = 0; for (int k = 0; k < 4; ++k) { int tmp = wsum[k]; wsum[k] = run; run += tmp; } }
    __syncthreads();
    int excl = wsum[w] + x - s;
    cnt[2 * t] = excl; cnt[2 * t + 1] = excl + v0;
    cur[2 * t] = excl; cur[2 * t + 1] = excl + v0;
    if (2 * t < nb)     rowptr[node0 + 2 * t]     = beg + excl;
    if (2 * t + 1 < nb) rowptr[node0 + 2 * t + 1] = beg + excl + v0;
    __syncthreads();
    for (int i = beg + t; i < end; i += 256) {
        uintT e = ebuf[i];
        int pos = beg + atomicAdd(&cur[e & 511], 1);
        ssrc[pos] = (int)(e >> BSHIFT);
    }
}

// ---------- fused per-node GAT aggregate ----------
__device__ __forceinline__ float lrelu(float v) { return v > 0.f ? v : SLOPE * v; }

#define WPB 4   // waves (nodes) per block
__global__ __launch_bounds__(256) void gat_gather(
    const int* __restrict__ rowptr, const int* __restrict__ ssrc,
    const float* __restrict__ asrc, const float* __restrict__ adst,
    const ushortT* __restrict__ hpb, const float* __restrict__ bias,
    ushortT* __restrict__ foutB)
{
    __shared__ float s_exp[WPB][64][4];
    __shared__ int   s_src[WPB][64];
    __shared__ float s_m[WPB][4];
    int w = threadIdx.x >> 6;
    int lane = threadIdx.x & 63;
    int node = blockIdx.x * WPB + w;
    if (node >= N_NODES) return;
    int beg = rowptr[node];
    int deg = rowptr[node + 1] - beg;
    float4 ad = *(const float4*)(adst + (size_t)node * 4);
    int g  = lane >> 4;      // 16-lane group (reduce group / edge quarter)
    int i0 = lane & 15;
    int ch8 = lane & 15;     // channel group: channels ch8*8 .. ch8*8+7
    int hd = ch8 >> 2;       // head of this lane's channels
    float acc8[8] = {};
    float zinv;

    if (deg <= 64) {
        // ---- fast path: one edge pass, logits cached in LDS ----
        float4 lg = make_float4(-1e30f, -1e30f, -1e30f, -1e30f);
        int soff = 0;
        if (lane < deg) {
            int s = ssrc[beg + lane];
            float4 a = *(const float4*)(asrc + (size_t)s * 4);
            lg.x = lrelu(a.x + ad.x);
            lg.y = lrelu(a.y + ad.y);
            lg.z = lrelu(a.z + ad.z);
            lg.w = lrelu(a.w + ad.w);
            soff = s * HC;
        }
        s_src[w][lane] = soff;
        *(float4*)&s_exp[w][lane][0] = lg;
        asm volatile("s_waitcnt lgkmcnt(0)" ::: "memory");
        // transpose-reduce max: group g reduces channel g over 64 edges
        float mg =     s_exp[w][i0][g];
        mg = fmaxf(mg, s_exp[w][i0 + 16][g]);
        mg = fmaxf(mg, s_exp[w][i0 + 32][g]);
        mg = fmaxf(mg, s_exp[w][i0 + 48][g]);
#pragma unroll
        for (int off = 1; off < 16; off <<= 1) mg = fmaxf(mg, __shfl_xor(mg, off));
        if (i0 == 0) s_m[w][g] = mg;
        asm volatile("s_waitcnt lgkmcnt(0)" ::: "memory");
        float4 m = *(float4*)&s_m[w][0];
        float4 ex;
        ex.x = __expf(lg.x - m.x);   // inactive lanes: lg=-1e30 -> 0
        ex.y = __expf(lg.y - m.y);
        ex.z = __expf(lg.z - m.z);
        ex.w = __expf(lg.w - m.w);
        *(float4*)&s_exp[w][lane][0] = ex;
        // z: 64-lane butterfly on float4 (all lanes get all heads)
        float4 zp = ex;
#pragma unroll
        for (int off = 1; off < 64; off <<= 1) {
            zp.x += __shfl_xor(zp.x, off);
            zp.y += __shfl_xor(zp.y, off);
            zp.z += __shfl_xor(zp.z, off);
            zp.w += __shfl_xor(zp.w, off);
        }
        zinv = 1.f / ((hd == 0) ? zp.x : (hd == 1) ? zp.y : (hd == 2) ? zp.z : zp.w);
        asm volatile("s_waitcnt lgkmcnt(0)" ::: "memory");
        // ---- gather: 4 edges/iteration, quarter g owns edge it*4+g, 8 ch/lane ----
        int nIt = (deg + 3) >> 2;
        for (int it = 0; it < nIt; ++it) {
            int edge = it * 4 + g;
            int eC = min(edge, deg - 1);
            float e = (edge < deg) ? s_exp[w][eC][hd] : 0.f;
            int off = s_src[w][eC];
            uint4 u = *(const uint4*)(hpb + off + ch8 * 8);
            acc8[0] = fmaf(__uint_as_float(u.x << 16),         e, acc8[0]);
            acc8[1] = fmaf(__uint_as_float(u.x & 0xffff0000u), e, acc8[1]);
            acc8[2] = fmaf(__uint_as_float(u.y << 16),         e, acc8[2]);
            acc8[3] = fmaf(__uint_as_float(u.y & 0xffff0000u), e, acc8[3]);
            acc8[4] = fmaf(__uint_as_float(u.z << 16),         e, acc8[4]);
            acc8[5] = fmaf(__uint_as_float(u.z & 0xffff0000u), e, acc8[5]);
            acc8[6] = fmaf(__uint_as_float(u.w << 16),         e, acc8[6]);
            acc8[7] = fmaf(__uint_as_float(u.w & 0xffff0000u), e, acc8[7]);
        }
    } else {
        // ---- general path (deg > 64): two-pass, chunked ----
        float4 m = make_float4(-1e30f, -1e30f, -1e30f, -1e30f);
        for (int i = lane; i < deg; i += 64) {
            int s = ssrc[beg + i];
            float4 a = *(const float4*)(asrc + (size_t)s * 4);
            m.x = fmaxf(m.x, lrelu(a.x + ad.x));
            m.y = fmaxf(m.y, lrelu(a.y + ad.y));
            m.z = fmaxf(m.z, lrelu(a.z + ad.z));
            m.w = fmaxf(m.w, lrelu(a.w + ad.w));
        }
#pragma unroll
        for (int off = 1; off < 64; off <<= 1) {
            m.x = fmaxf(m.x, __shfl_xor(m.x, off));
            m.y = fmaxf(m.y, __shfl_xor(m.y, off));
            m.z = fmaxf(m.z, __shfl_xor(m.z, off));
            m.w = fmaxf(m.w, __shfl_xor(m.w, off));
        }
        float4 zp = make_float4(0.f, 0.f, 0.f, 0.f);
        for (int c0 = 0; c0 < deg; c0 += 64) {
            int n_ch = min(64, deg - c0);
            if (lane < n_ch) {
                int s = ssrc[beg + c0 + lane];
                float4 a = *(const float4*)(asrc + (size_t)s * 4);
                float4 ex;
                ex.x = __expf(lrelu(a.x + ad.x) - m.x);
                ex.y = __expf(lrelu(a.y + ad.y) - m.y);
                ex.z = __expf(lrelu(a.z + ad.z) - m.z);
                ex.w = __expf(lrelu(a.w + ad.w) - m.w);
                *(float4*)&s_exp[w][lane][0] = ex;
                s_src[w][lane] = s * HC;
                zp.x += ex.x; zp.y += ex.y; zp.z += ex.z; zp.w += ex.w;
            }
            asm volatile("s_waitcnt lgkmcnt(0)" ::: "memory");
            int nIt = (n_ch + 3) >> 2;
            for (int it = 0; it < nIt; ++it) {
                int edge = it * 4 + g;
                int eC = min(edge, n_ch - 1);
                float e = (edge < n_ch) ? s_exp[w][eC][hd] : 0.f;
                int off = s_src[w][eC];
                uint4 u = *(const uint4*)(hpb + off + ch8 * 8);
                acc8[0] = fmaf(__uint_as_float(u.x << 16),         e, acc8[0]);
                acc8[1] = fmaf(__uint_as_float(u.x & 0xffff0000u), e, acc8[1]);
                acc8[2] = fmaf(__uint_as_float(u.y << 16),         e, acc8[2]);
                acc8[3] = fmaf(__uint_as_float(u.y & 0xffff0000u), e, acc8[3]);
                acc8[4] = fmaf(__uint_as_float(u.z << 16),         e, acc8[4]);
                acc8[5] = fmaf(__uint_as_float(u.z & 0xffff0000u), e, acc8[5]);
                acc8[6] = fmaf(__uint_as_float(u.w << 16),         e, acc8[6]);
                acc8[7] = fmaf(__uint_as_float(u.w & 0xffff0000u), e, acc8[7]);
            }
        }
#pragma unroll
        for (int off = 1; off < 64; off <<= 1) {
            zp.x += __shfl_xor(zp.x, off);
            zp.y += __shfl_xor(zp.y, off);
            zp.z += __shfl_xor(zp.z, off);
            zp.w += __shfl_xor(zp.w, off);
        }
        zinv = 1.f / ((hd == 0) ? zp.x : (hd == 1) ? zp.y : (hd == 2) ? zp.z : zp.w);
    }

    // ---- cross-quarter reduce: quarters 0..3 hold partial sums of same channels ----
#pragma unroll
    for (int j = 0; j < 8; ++j) {
        acc8[j] += __shfl_xor(acc8[j], 16);
        acc8[j] += __shfl_xor(acc8[j], 32);
    }
    if (g == 0) {
        const float* bp = bias + ch8 * 8;
        uint4 pOut;
        uintT pr[4];
#pragma unroll
        for (int p = 0; p < 4; ++p) {
            float v0 = acc8[2 * p] * zinv + bp[2 * p];
            float v1 = acc8[2 * p + 1] * zinv + bp[2 * p + 1];
            v0 = v0 > 0.f ? v0 : __expf(v0) - 1.f;
            v1 = v1 > 0.f ? v1 : __expf(v1) - 1.f;
            pr[p] = (uintT)f2bu(v0) | ((uintT)f2bu(v1) << 16);
        }
        pOut.x = pr[0]; pOut.y = pr[1]; pOut.z = pr[2]; pOut.w = pr[3];
        *(uint4*)(foutB + (size_t)node * HC + ch8 * 8) = pOut;
    }
}

extern "C" void kernel_launch(void* const* d_in, const int* in_sizes, int n_in,
                              void* d_out, int out_size, void* d_ws, size_t ws_size,
                              hipStream_t stream) {
    const float* x      = (const float*)d_in[0];
    const int*   ei     = (const int*)d_in[1];
    const float* w_in   = (const float*)d_in[2];
    const float* Ws     = (const float*)d_in[3];
    const float* atts   = (const float*)d_in[4];
    const float* biases = (const float*)d_in[5];
    const float* w_out  = (const float*)d_in[6];
    float* out = (float*)d_out;

    // workspace partition
    char* wp = (char*)d_ws;
    ushortT* hb0 = (ushortT*)wp; wp += (size_t)N_NODES * HC * 2;   // bf16 h / final gat out
    ushortT* hb1 = (ushortT*)wp; wp += (size_t)N_NODES * HC * 2;   // bf16 gat_l0 out
    ushortT* hpb = (ushortT*)wp; wp += (size_t)N_NODES * HC * 2;   // bf16 hp
    float* asrc  = (float*)wp;   wp += (size_t)N_NODES * HEADS * 4;
    float* adst  = (float*)wp;   wp += (size_t)N_NODES * HEADS * 4;
    int* rowptr  = (int*)wp;     wp += (size_t)(N_NODES + 4) * 4;
    int* ssrc    = (int*)wp;     wp += (size_t)EE * 4;
    uintT* ebuf  = (uintT*)wp;   wp += (size_t)EE * 4;
    int* bcnt    = (int*)wp;     wp += (size_t)(NBUCK + 4) * 4;
    int* bbase   = (int*)wp;     wp += (size_t)(NBUCK + 4) * 4;
    int* gcur    = (int*)wp;     wp += (size_t)(NBUCK + 4) * 4;
    ushortT* w_inT = (ushortT*)wp; wp += (size_t)HC * F_IN * 2;
    ushortT* WsT   = (ushortT*)wp; wp += (size_t)LAYERS * HC * HC * 2;
    ushortT* woutT = (ushortT*)wp; wp += (size_t)48 * HC * 2;

    // ---- CSR build: two-level bucket sort ----
    hipMemsetAsync(bcnt, 0, (size_t)NBUCK * 4, stream);
    bucket_count<<<NBLK_E, 256, 0, stream>>>(ei, bcnt);
    bucket_scan<<<1, 64, 0, stream>>>(bcnt, bbase, gcur, rowptr);
    bucket_scatter<<<NBLK_E, 256, 0, stream>>>(ei, gcur, ebuf);
    csr_local<<<NBUCK, 256, 0, stream>>>(ebuf, bbase, rowptr, ssrc);

    // ---- weight convert+transpose ----
    wconv<<<(F_IN * HC + 255) / 256, 256, 0, stream>>>(w_in, w_inT, F_IN);
    wconv<<<(HC * HC + 255) / 256, 256, 0, stream>>>(Ws, WsT, HC);
    wconv<<<(HC * HC + 255) / 256, 256, 0, stream>>>(Ws + (size_t)HC * HC, WsT + (size_t)HC * HC, HC);
    wconv_cls<<<(48 * HC + 255) / 256, 256, 0, stream>>>(w_out, woutT);

    int gblk = (N_NODES + 63) / 64;
    // h = x @ w_in  -> bf16 only
    gemm_mfma<true><<<gblk, 256, 0, stream>>>(x, w_inT, hb0, nullptr, nullptr, nullptr,
                                              N_NODES, F_IN);

    const ushortT* hin_b = hb0;
    ushortT* gout[LAYERS] = { hb1, hb0 };
    for (int l = 0; l < LAYERS; ++l) {
        gemm_mfma<false><<<gblk, 256, 0, stream>>>(hin_b, WsT + (size_t)l * HC * HC, hpb,
                                                   atts + (size_t)l * HEADS * 2 * HID,
                                                   asrc, adst, N_NODES, HC);
        gat_gather<<<(N_NODES + WPB - 1) / WPB, 64 * WPB, 0, stream>>>(
            rowptr, ssrc, asrc, adst, hpb, biases + (size_t)l * HC, gout[l]);
        hin_b = gout[l];
    }

    cls_mfma<<<gblk, 256, 0, stream>>>(hb0, woutT, out, N_NODES);
}

// Round 10
// 206.280 us; speedup vs baseline: 1.0466x; 1.0466x over previous
//
#include <hip/hip_runtime.h>
#include <hip/hip_bf16.h>
#include <math.h>

#define N_NODES 50000
#define N_EDGES 800000
#define F_IN 256
#define HID 32
#define HEADS 4
#define HC 128            // HID*HEADS
#define CLASSES 40
#define LAYERS 2
#define SLOPE 0.1f
#define EE (N_EDGES + N_NODES)   // edges + self loops

#define BSHIFT 9
#define NBUCK 98          // ceil(50000 / 512)
#define CHUNK 4096        // edges per block in bucket passes
#define NBLK_E ((EE + CHUNK - 1) / CHUNK)

typedef unsigned short ushortT;
typedef unsigned int uintT;
typedef __attribute__((ext_vector_type(8))) short short8v;   // 8 bf16 = 4 VGPRs
typedef __attribute__((ext_vector_type(4))) float f32x4;

__device__ __forceinline__ ushortT f2bu(float f) {
    __hip_bfloat16 h = __float2bfloat16(f);
    ushortT u; __builtin_memcpy(&u, &h, 2); return u;
}

// ---------- weight transpose+convert: W[K][128] fp32 -> WT[128][K] bf16 ----------
__global__ void wconv(const float* __restrict__ W, ushortT* __restrict__ WT, int K) {
    int i = blockIdx.x * 256 + threadIdx.x;
    if (i >= K * 128) return;
    int r = i >> 7, c = i & 127;
    WT[(size_t)c * K + r] = f2bu(W[i]);
}

// Wout[128][40] fp32 -> WT[48][128] bf16, cols 40..47 zero
__global__ void wconv_cls(const float* __restrict__ W, ushortT* __restrict__ WT) {
    int i = blockIdx.x * 256 + threadIdx.x;
    if (i >= 48 * 128) return;
    int c = i >> 7, k = i & 127;
    WT[i] = (c < CLASSES) ? f2bu(W[k * CLASSES + c]) : (ushortT)0;
}

// ---------- MFMA bf16 GEMM, N fixed 128, optional fused attention-dot epilogue ----------
#define AS_LD 40
template<bool AF32>
__global__ __launch_bounds__(256) void gemm_mfma(const void* __restrict__ Aptr,
                                                 const ushortT* __restrict__ BT,
                                                 ushortT* __restrict__ Cb,
                                                 const float* __restrict__ att,  // may be null
                                                 float* __restrict__ asrc,
                                                 float* __restrict__ adst,
                                                 int M, int K) {
    __shared__ ushortT As[64 * AS_LD];    // [row][k<32]
    __shared__ ushortT Bs[128 * AS_LD];   // [col][k<32]
    int t = threadIdx.x;
    int w = t >> 6, lane = t & 63;
    int row0 = blockIdx.x * 64;
    int ar = t >> 2, ak = (t & 3) * 8;
    int bcol = t >> 1, bks = (t & 1) * 16;
    int wr = w * 16;
    int arow = wr + (lane & 15);
    int ak8 = (lane >> 4) * 8;
    f32x4 acc[8] = {};

    for (int k0 = 0; k0 < K; k0 += 32) {
        int grow = row0 + ar;
        if (AF32) {
            const float* A = (const float*)Aptr;
            float4 v0 = make_float4(0.f, 0.f, 0.f, 0.f), v1 = v0;
            if (grow < M) {
                const float* ap = A + (size_t)grow * K + k0 + ak;
                v0 = *(const float4*)ap;
                v1 = *(const float4*)(ap + 4);
            }
            uint4 p;
            p.x = (uintT)f2bu(v0.x) | ((uintT)f2bu(v0.y) << 16);
            p.y = (uintT)f2bu(v0.z) | ((uintT)f2bu(v0.w) << 16);
            p.z = (uintT)f2bu(v1.x) | ((uintT)f2bu(v1.y) << 16);
            p.w = (uintT)f2bu(v1.z) | ((uintT)f2bu(v1.w) << 16);
            *(uint4*)&As[ar * AS_LD + ak] = p;
        } else {
            const ushortT* A = (const ushortT*)Aptr;
            uint4 p = make_uint4(0, 0, 0, 0);
            if (grow < M) p = *(const uint4*)(A + (size_t)grow * K + k0 + ak);
            *(uint4*)&As[ar * AS_LD + ak] = p;
        }
        {
            const ushortT* bp = BT + (size_t)bcol * K + k0 + bks;
            *(uint4*)&Bs[bcol * AS_LD + bks]     = *(const uint4*)bp;
            *(uint4*)&Bs[bcol * AS_LD + bks + 8] = *(const uint4*)(bp + 8);
        }
        __syncthreads();
        short8v a = *(short8v*)&As[arow * AS_LD + ak8];
#pragma unroll
        for (int c = 0; c < 8; ++c) {
            short8v b = *(short8v*)&Bs[(c * 16 + (lane & 15)) * AS_LD + ak8];
            acc[c] = __builtin_amdgcn_mfma_f32_16x16x32_bf16(a, b, acc[c], 0, 0, 0);
        }
        __syncthreads();
    }
    int cl = lane & 15;
    int r0 = row0 + wr + ((lane >> 4) << 2);
#pragma unroll
    for (int c = 0; c < 8; ++c) {
        int cc = c * 16 + cl;
#pragma unroll
        for (int r = 0; r < 4; ++r) {
            int rr = r0 + r;
            if (rr < M) Cb[(size_t)rr * 128 + cc] = f2bu(acc[c][r]);
        }
    }
    // fused attention dots: asrc/adst[row][h] = dot(hp_row[h*32..], att[h][..])
    if (att) {
#pragma unroll
        for (int h = 0; h < HEADS; ++h) {
            float as0 = att[h * 64 + cl];
            float as1 = att[h * 64 + 16 + cl];
            float ad0 = att[h * 64 + 32 + cl];
            float ad1 = att[h * 64 + 48 + cl];
#pragma unroll
            for (int r = 0; r < 4; ++r) {
                float ps = acc[2 * h][r] * as0 + acc[2 * h + 1][r] * as1;
                float pd = acc[2 * h][r] * ad0 + acc[2 * h + 1][r] * ad1;
#pragma unroll
                for (int off = 1; off < 16; off <<= 1) {
                    ps += __shfl_xor(ps, off);
                    pd += __shfl_xor(pd, off);
                }
                int rr = r0 + r;
                if (cl == 0 && rr < M) {
                    asrc[rr * 4 + h] = ps;
                    adst[rr * 4 + h] = pd;
                }
            }
        }
    }
}

// ---------- fused MFMA classifier + in-register log_softmax ----------
__global__ __launch_bounds__(256) void cls_mfma(const ushortT* __restrict__ A,
                                                const ushortT* __restrict__ BT,
                                                float* __restrict__ out, int M) {
    __shared__ ushortT As[64 * AS_LD];
    __shared__ ushortT Bs[48 * AS_LD];
    int t = threadIdx.x;
    int w = t >> 6, lane = t & 63;
    int row0 = blockIdx.x * 64;
    int ar = t >> 2, ak = (t & 3) * 8;
    int wr = w * 16;
    int arow = wr + (lane & 15);
    int ak8 = (lane >> 4) * 8;
    f32x4 acc[3] = {};

    for (int k0 = 0; k0 < 128; k0 += 32) {
        int grow = row0 + ar;
        uint4 p = make_uint4(0, 0, 0, 0);
        if (grow < M) p = *(const uint4*)(A + (size_t)grow * 128 + k0 + ak);
        *(uint4*)&As[ar * AS_LD + ak] = p;
        if (t < 96) {
            int bcol = t >> 1, bks = (t & 1) * 16;
            const ushortT* bp = BT + bcol * 128 + k0 + bks;
            *(uint4*)&Bs[bcol * AS_LD + bks]     = *(const uint4*)bp;
            *(uint4*)&Bs[bcol * AS_LD + bks + 8] = *(const uint4*)(bp + 8);
        }
        __syncthreads();
        short8v a = *(short8v*)&As[arow * AS_LD + ak8];
#pragma unroll
        for (int c = 0; c < 3; ++c) {
            short8v b = *(short8v*)&Bs[(c * 16 + (lane & 15)) * AS_LD + ak8];
            acc[c] = __builtin_amdgcn_mfma_f32_16x16x32_bf16(a, b, acc[c], 0, 0, 0);
        }
        __syncthreads();
    }
    int cl = lane & 15;
    int r0 = row0 + wr + ((lane >> 4) << 2);
#pragma unroll
    for (int r = 0; r < 4; ++r) {
        float v0 = acc[0][r], v1 = acc[1][r];
        float v2 = (cl < 8) ? acc[2][r] : -1e30f;
        float m = fmaxf(fmaxf(v0, v1), v2);
#pragma unroll
        for (int off = 1; off < 16; off <<= 1) m = fmaxf(m, __shfl_xor(m, off));
        float e = __expf(v0 - m) + __expf(v1 - m) + ((cl < 8) ? __expf(v2 - m) : 0.f);
#pragma unroll
        for (int off = 1; off < 16; off <<= 1) e += __shfl_xor(e, off);
        float ls = m + __logf(e);
        int rr = r0 + r;
        if (rr < M) {
            float* o = out + (size_t)rr * CLASSES;
            o[cl] = v0 - ls;
            o[16 + cl] = v1 - ls;
            if (cl < 8) o[32 + cl] = v2 - ls;
        }
    }
}

// ---------- CSR build via two-level bucket sort ----------
__global__ __launch_bounds__(256) void bucket_count(const int* __restrict__ ei,
                                                    int* __restrict__ bcnt) {
    __shared__ int hist[NBUCK];
    int t = threadIdx.x;
    if (t < NBUCK) hist[t] = 0;
    __syncthreads();
    int base = blockIdx.x * CHUNK;
    int end = min(base + CHUNK, EE);
    for (int i = base + t; i < end; i += 256) {
        int d = (i < N_EDGES) ? ei[N_EDGES + i] : (i - N_EDGES);
        atomicAdd(&hist[d >> BSHIFT], 1);
    }
    __syncthreads();
    if (t < NBUCK && hist[t]) atomicAdd(&bcnt[t], hist[t]);
}

__global__ void bucket_scan(const int* __restrict__ bcnt, int* __restrict__ bbase,
                            int* __restrict__ gcur, int* __restrict__ rowptr) {
    if (threadIdx.x == 0) {
        int run = 0;
        for (int b = 0; b < NBUCK; ++b) { bbase[b] = run; gcur[b] = run; run += bcnt[b]; }
        bbase[NBUCK] = run;
        rowptr[N_NODES] = run;   // == EE
    }
}

__global__ __launch_bounds__(256) void bucket_scatter(const int* __restrict__ ei,
                                                      int* __restrict__ gcur,
                                                      uintT* __restrict__ ebuf) {
    __shared__ int hist[NBUCK];
    __shared__ int rbase[NBUCK];
    int t = threadIdx.x;
    if (t < NBUCK) hist[t] = 0;
    __syncthreads();
    int base = blockIdx.x * CHUNK;
    int end = min(base + CHUNK, EE);
    for (int i = base + t; i < end; i += 256) {
        int d = (i < N_EDGES) ? ei[N_EDGES + i] : (i - N_EDGES);
        atomicAdd(&hist[d >> BSHIFT], 1);
    }
    __syncthreads();
    if (t < NBUCK) {
        int c = hist[t];
        rbase[t] = c ? atomicAdd(&gcur[t], c) : 0;
    }
    __syncthreads();
    if (t < NBUCK) hist[t] = 0;
    __syncthreads();
    for (int i = base + t; i < end; i += 256) {
        int s, d;
        if (i < N_EDGES) { s = ei[i]; d = ei[N_EDGES + i]; } else { s = d = i - N_EDGES; }
        int b = d >> BSHIFT;
        int pos = rbase[b] + atomicAdd(&hist[b], 1);
        ebuf[pos] = ((uintT)s << BSHIFT) | (uintT)(d & 511);   // src(16b) | local dst(9b)
    }
}

__global__ __launch_bounds__(256) void csr_local(const uintT* __restrict__ ebuf,
                                                 const int* __restrict__ bbase,
                                                 int* __restrict__ rowptr,
                                                 int* __restrict__ ssrc) {
    __shared__ int cnt[512];
    __shared__ int cur[512];
    __shared__ int wsum[4];
    int b = blockIdx.x;
    int t = threadIdx.x;
    int node0 = b << BSHIFT;
    int nb = min(512, N_NODES - node0);
    int beg = bbase[b], end = bbase[b + 1];
    cnt[t] = 0; cnt[t + 256] = 0;
    __syncthreads();
    for (int i = beg + t; i < end; i += 256)
        atomicAdd(&cnt[ebuf[i] & 511], 1);
    __syncthreads();
    int v0 = cnt[2 * t], v1 = cnt[2 * t + 1];
    int s = v0 + v1;
    int lane = t & 63, w = t >> 6;
    int x = s;
#pragma unroll
    for (int off = 1; off < 64; off <<= 1) { int y = __shfl_up(x, off); if (lane >= off) x += y; }
    if (lane == 63) wsum[w] = x;
    __syncthreads();
    if (t == 0) { int run = 0; for (int k = 0; k < 4; ++k) { int tmp = wsum[k]; wsum[k] = run; run += tmp; } }
    __syncthreads();
    int excl = wsum[w] + x - s;
    cnt[2 * t] = excl; cnt[2 * t + 1] = excl + v0;
    cur[2 * t] = excl; cur[2 * t + 1] = excl + v0;
    if (2 * t < nb)     rowptr[node0 + 2 * t]     = beg + excl;
    if (2 * t + 1 < nb) rowptr[node0 + 2 * t + 1] = beg + excl + v0;
    __syncthreads();
    for (int i = beg + t; i < end; i += 256) {
        uintT e = ebuf[i];
        int pos = beg + atomicAdd(&cur[e & 511], 1);
        ssrc[pos] = (int)(e >> BSHIFT);
    }
}

// ---------- fused per-node GAT aggregate (R8-proven memory pattern) ----------
__device__ __forceinline__ float lrelu(float v) { return v > 0.f ? v : SLOPE * v; }

#define WPB 4   // waves (nodes) per block
__global__ __launch_bounds__(256) void gat_gather(
    const int* __restrict__ rowptr, const int* __restrict__ ssrc,
    const float* __restrict__ asrc, const float* __restrict__ adst,
    const ushortT* __restrict__ hpb, const float* __restrict__ bias,
    ushortT* __restrict__ foutB)
{
    __shared__ float s_exp[WPB][64][4];
    __shared__ int   s_src[WPB][64];
    __shared__ float s_m[WPB][4];
    int w = threadIdx.x >> 6;
    int lane = threadIdx.x & 63;
    int node = blockIdx.x * WPB + w;
    if (node >= N_NODES) return;
    int beg = rowptr[node];
    int deg = rowptr[node + 1] - beg;
    float4 ad = *(const float4*)(adst + (size_t)node * 4);
    int g = lane >> 4;       // lane's head / reduce group (channels 2*lane,2*lane+1)
    int i0 = lane & 15;
    float acc0 = 0.f, acc1 = 0.f;
    float zinv;
    const ushortT* hrow = hpb + lane * 2;

    if (deg <= 64) {
        // ---- fast path: one edge pass, logits cached in LDS ----
        float4 lg = make_float4(-1e30f, -1e30f, -1e30f, -1e30f);
        int soff = 0;
        if (lane < deg) {
            int s = ssrc[beg + lane];
            float4 a = *(const float4*)(asrc + (size_t)s * 4);
            lg.x = lrelu(a.x + ad.x);
            lg.y = lrelu(a.y + ad.y);
            lg.z = lrelu(a.z + ad.z);
            lg.w = lrelu(a.w + ad.w);
            soff = s * HC;
        }
        s_src[w][lane] = soff;
        *(float4*)&s_exp[w][lane][0] = lg;
        asm volatile("s_waitcnt lgkmcnt(0)" ::: "memory");
        // transpose-reduce max: group g reduces channel g over 64 edges
        float mg =     s_exp[w][i0][g];
        mg = fmaxf(mg, s_exp[w][i0 + 16][g]);
        mg = fmaxf(mg, s_exp[w][i0 + 32][g]);
        mg = fmaxf(mg, s_exp[w][i0 + 48][g]);
#pragma unroll
        for (int off = 1; off < 16; off <<= 1) mg = fmaxf(mg, __shfl_xor(mg, off));
        if (i0 == 0) s_m[w][g] = mg;
        asm volatile("s_waitcnt lgkmcnt(0)" ::: "memory");
        float4 m = *(float4*)&s_m[w][0];
        float4 ex;
        ex.x = __expf(lg.x - m.x);   // inactive lanes: lg=-1e30 -> 0
        ex.y = __expf(lg.y - m.y);
        ex.z = __expf(lg.z - m.z);
        ex.w = __expf(lg.w - m.w);
        *(float4*)&s_exp[w][lane][0] = ex;
        asm volatile("s_waitcnt lgkmcnt(0)" ::: "memory");
        // transpose-reduce z for own head g
        float zg = s_exp[w][i0][g];
        zg +=      s_exp[w][i0 + 16][g];
        zg +=      s_exp[w][i0 + 32][g];
        zg +=      s_exp[w][i0 + 48][g];
#pragma unroll
        for (int off = 1; off < 16; off <<= 1) zg += __shfl_xor(zg, off);
        zinv = 1.f / zg;
        // ---- weighted gather: 2 ch/lane, 4B loads, unroll-4 gives 4 rows in flight ----
#pragma unroll 4
        for (int i = 0; i < deg; ++i) {
            float e = s_exp[w][i][g];
            int off = s_src[w][i];
            uintT u = *(const uintT*)(hrow + off);
            float h0 = __uint_as_float(u << 16);
            float h1 = __uint_as_float(u & 0xffff0000u);
            acc0 = fmaf(h0, e, acc0);
            acc1 = fmaf(h1, e, acc1);
        }
    } else {
        // ---- general path (deg > 64): two-pass, chunked ----
        float4 m = make_float4(-1e30f, -1e30f, -1e30f, -1e30f);
        for (int i = lane; i < deg; i += 64) {
            int s = ssrc[beg + i];
            float4 a = *(const float4*)(asrc + (size_t)s * 4);
            m.x = fmaxf(m.x, lrelu(a.x + ad.x));
            m.y = fmaxf(m.y, lrelu(a.y + ad.y));
            m.z = fmaxf(m.z, lrelu(a.z + ad.z));
            m.w = fmaxf(m.w, lrelu(a.w + ad.w));
        }
#pragma unroll
        for (int off = 1; off < 64; off <<= 1) {
            m.x = fmaxf(m.x, __shfl_xor(m.x, off));
            m.y = fmaxf(m.y, __shfl_xor(m.y, off));
            m.z = fmaxf(m.z, __shfl_xor(m.z, off));
            m.w = fmaxf(m.w, __shfl_xor(m.w, off));
        }
        float4 zp = make_float4(0.f, 0.f, 0.f, 0.f);
        for (int c0 = 0; c0 < deg; c0 += 64) {
            int n_ch = min(64, deg - c0);
            if (lane < n_ch) {
                int s = ssrc[beg + c0 + lane];
                float4 a = *(const float4*)(asrc + (size_t)s * 4);
                float4 ex;
                ex.x = __expf(lrelu(a.x + ad.x) - m.x);
                ex.y = __expf(lrelu(a.y + ad.y) - m.y);
                ex.z = __expf(lrelu(a.z + ad.z) - m.z);
                ex.w = __expf(lrelu(a.w + ad.w) - m.w);
                *(float4*)&s_exp[w][lane][0] = ex;
                s_src[w][lane] = s * HC;
                zp.x += ex.x; zp.y += ex.y; zp.z += ex.z; zp.w += ex.w;
            }
            asm volatile("s_waitcnt lgkmcnt(0)" ::: "memory");
#pragma unroll 4
            for (int i = 0; i < n_ch; ++i) {
                float e = s_exp[w][i][g];
                int off = s_src[w][i];
                uintT u = *(const uintT*)(hrow + off);
                float h0 = __uint_as_float(u << 16);
                float h1 = __uint_as_float(u & 0xffff0000u);
                acc0 = fmaf(h0, e, acc0);
                acc1 = fmaf(h1, e, acc1);
            }
        }
#pragma unroll
        for (int off = 1; off < 64; off <<= 1) {
            zp.x += __shfl_xor(zp.x, off);
            zp.y += __shfl_xor(zp.y, off);
            zp.z += __shfl_xor(zp.z, off);
            zp.w += __shfl_xor(zp.w, off);
        }
        float zh = (g == 0) ? zp.x : (g == 1) ? zp.y : (g == 2) ? zp.z : zp.w;
        zinv = 1.f / zh;
    }

    float b0 = bias[lane * 2], b1 = bias[lane * 2 + 1];
    float v0 = acc0 * zinv + b0; v0 = v0 > 0.f ? v0 : __expf(v0) - 1.f;
    float v1 = acc1 * zinv + b1; v1 = v1 > 0.f ? v1 : __expf(v1) - 1.f;
    *(uintT*)(foutB + (size_t)node * HC + lane * 2) =
        (uintT)f2bu(v0) | ((uintT)f2bu(v1) << 16);
}

extern "C" void kernel_launch(void* const* d_in, const int* in_sizes, int n_in,
                              void* d_out, int out_size, void* d_ws, size_t ws_size,
                              hipStream_t stream) {
    const float* x      = (const float*)d_in[0];
    const int*   ei     = (const int*)d_in[1];
    const float* w_in   = (const float*)d_in[2];
    const float* Ws     = (const float*)d_in[3];
    const float* atts   = (const float*)d_in[4];
    const float* biases = (const float*)d_in[5];
    const float* w_out  = (const float*)d_in[6];
    float* out = (float*)d_out;

    // workspace partition
    char* wp = (char*)d_ws;
    ushortT* hb0 = (ushortT*)wp; wp += (size_t)N_NODES * HC * 2;   // bf16 h / final gat out
    ushortT* hb1 = (ushortT*)wp; wp += (size_t)N_NODES * HC * 2;   // bf16 gat_l0 out
    ushortT* hpb = (ushortT*)wp; wp += (size_t)N_NODES * HC * 2;   // bf16 hp
    float* asrc  = (float*)wp;   wp += (size_t)N_NODES * HEADS * 4;
    float* adst  = (float*)wp;   wp += (size_t)N_NODES * HEADS * 4;
    int* rowptr  = (int*)wp;     wp += (size_t)(N_NODES + 4) * 4;
    int* ssrc    = (int*)wp;     wp += (size_t)EE * 4;
    uintT* ebuf  = (uintT*)wp;   wp += (size_t)EE * 4;
    int* bcnt    = (int*)wp;     wp += (size_t)(NBUCK + 4) * 4;
    int* bbase   = (int*)wp;     wp += (size_t)(NBUCK + 4) * 4;
    int* gcur    = (int*)wp;     wp += (size_t)(NBUCK + 4) * 4;
    ushortT* w_inT = (ushortT*)wp; wp += (size_t)HC * F_IN * 2;
    ushortT* WsT   = (ushortT*)wp; wp += (size_t)LAYERS * HC * HC * 2;
    ushortT* woutT = (ushortT*)wp; wp += (size_t)48 * HC * 2;

    // ---- CSR build: two-level bucket sort ----
    hipMemsetAsync(bcnt, 0, (size_t)NBUCK * 4, stream);
    bucket_count<<<NBLK_E, 256, 0, stream>>>(ei, bcnt);
    bucket_scan<<<1, 64, 0, stream>>>(bcnt, bbase, gcur, rowptr);
    bucket_scatter<<<NBLK_E, 256, 0, stream>>>(ei, gcur, ebuf);
    csr_local<<<NBUCK, 256, 0, stream>>>(ebuf, bbase, rowptr, ssrc);

    // ---- weight convert+transpose ----
    wconv<<<(F_IN * HC + 255) / 256, 256, 0, stream>>>(w_in, w_inT, F_IN);
    wconv<<<(HC * HC + 255) / 256, 256, 0, stream>>>(Ws, WsT, HC);
    wconv<<<(HC * HC + 255) / 256, 256, 0, stream>>>(Ws + (size_t)HC * HC, WsT + (size_t)HC * HC, HC);
    wconv_cls<<<(48 * HC + 255) / 256, 256, 0, stream>>>(w_out, woutT);

    int gblk = (N_NODES + 63) / 64;
    // h = x @ w_in  -> bf16 only
    gemm_mfma<true><<<gblk, 256, 0, stream>>>(x, w_inT, hb0, nullptr, nullptr, nullptr,
                                              N_NODES, F_IN);

    const ushortT* hin_b = hb0;
    ushortT* gout[LAYERS] = { hb1, hb0 };
    for (int l = 0; l < LAYERS; ++l) {
        gemm_mfma<false><<<gblk, 256, 0, stream>>>(hin_b, WsT + (size_t)l * HC * HC, hpb,
                                                   atts + (size_t)l * HEADS * 2 * HID,
                                                   asrc, adst, N_NODES, HC);
        gat_gather<<<(N_NODES + WPB - 1) / WPB, 64 * WPB, 0, stream>>>(
            rowptr, ssrc, asrc, adst, hpb, biases + (size_t)l * HC, gout[l]);
        hin_b = gout[l];
    }

    cls_mfma<<<gblk, 256, 0, stream>>>(hb0, woutT, out, N_NODES);
}

// Round 11
// 187.490 us; speedup vs baseline: 1.1515x; 1.1002x over previous
//
#include <hip/hip_runtime.h>
#include <hip/hip_bf16.h>
#include <math.h>

#define N_NODES 50000
#define N_EDGES 800000
#define F_IN 256
#define HID 32
#define HEADS 4
#define HC 128            // HID*HEADS
#define CLASSES 40
#define LAYERS 2
#define SLOPE 0.1f
#define EE (N_EDGES + N_NODES)   // edges + self loops

#define BSHIFT 9
#define NBUCK 98          // ceil(50000 / 512)
#define CHUNK 4096        // edges per block in bucket passes
#define NBLK_E ((EE + CHUNK - 1) / CHUNK)

typedef unsigned short ushortT;
typedef unsigned int uintT;
typedef __attribute__((ext_vector_type(8))) short short8v;   // 8 bf16 = 4 VGPRs
typedef __attribute__((ext_vector_type(4))) float f32x4;

__device__ __forceinline__ ushortT f2bu(float f) {
    __hip_bfloat16 h = __float2bfloat16(f);
    ushortT u; __builtin_memcpy(&u, &h, 2); return u;
}

// ---------- all weight transposes+converts in one kernel ----------
__global__ void wconv_all(const float* __restrict__ w_in, const float* __restrict__ Ws,
                          const float* __restrict__ w_out, ushortT* __restrict__ w_inT,
                          ushortT* __restrict__ WsT, ushortT* __restrict__ woutT) {
    int i = blockIdx.x * 256 + threadIdx.x;
    if (i < 32768) {                       // w_in[256][128] -> w_inT[128][256]
        int r = i >> 7, c = i & 127;
        w_inT[(size_t)c * F_IN + r] = f2bu(w_in[i]);
    } else if (i < 65536) {                // Ws[2][128][128] -> WsT[2][128][128]^T
        int j = i - 32768;
        int l = j >> 14, jj = j & 16383;
        int r = jj >> 7, c = jj & 127;
        WsT[l * 16384 + c * 128 + r] = f2bu(Ws[j]);
    } else if (i < 65536 + 6144) {         // w_out[128][40] -> woutT[48][128], pad 0
        int j = i - 65536;
        int c = j >> 7, k = j & 127;
        woutT[j] = (c < CLASSES) ? f2bu(w_out[k * CLASSES + c]) : (ushortT)0;
    }
}

// ---------- MFMA bf16 GEMM, N fixed 128, optional fused attention-dot epilogue ----------
#define AS_LD 40
template<bool AF32>
__global__ __launch_bounds__(256) void gemm_mfma(const void* __restrict__ Aptr,
                                                 const ushortT* __restrict__ BT,
                                                 ushortT* __restrict__ Cb,
                                                 const float* __restrict__ att,  // may be null
                                                 float* __restrict__ asrc,
                                                 float* __restrict__ adst,
                                                 int M, int K) {
    __shared__ ushortT As[64 * AS_LD];    // [row][k<32]
    __shared__ ushortT Bs[128 * AS_LD];   // [col][k<32]
    int t = threadIdx.x;
    int w = t >> 6, lane = t & 63;
    int row0 = blockIdx.x * 64;
    int ar = t >> 2, ak = (t & 3) * 8;
    int bcol = t >> 1, bks = (t & 1) * 16;
    int wr = w * 16;
    int arow = wr + (lane & 15);
    int ak8 = (lane >> 4) * 8;
    f32x4 acc[8] = {};

    for (int k0 = 0; k0 < K; k0 += 32) {
        int grow = row0 + ar;
        if (AF32) {
            const float* A = (const float*)Aptr;
            float4 v0 = make_float4(0.f, 0.f, 0.f, 0.f), v1 = v0;
            if (grow < M) {
                const float* ap = A + (size_t)grow * K + k0 + ak;
                v0 = *(const float4*)ap;
                v1 = *(const float4*)(ap + 4);
            }
            uint4 p;
            p.x = (uintT)f2bu(v0.x) | ((uintT)f2bu(v0.y) << 16);
            p.y = (uintT)f2bu(v0.z) | ((uintT)f2bu(v0.w) << 16);
            p.z = (uintT)f2bu(v1.x) | ((uintT)f2bu(v1.y) << 16);
            p.w = (uintT)f2bu(v1.z) | ((uintT)f2bu(v1.w) << 16);
            *(uint4*)&As[ar * AS_LD + ak] = p;
        } else {
            const ushortT* A = (const ushortT*)Aptr;
            uint4 p = make_uint4(0, 0, 0, 0);
            if (grow < M) p = *(const uint4*)(A + (size_t)grow * K + k0 + ak);
            *(uint4*)&As[ar * AS_LD + ak] = p;
        }
        {
            const ushortT* bp = BT + (size_t)bcol * K + k0 + bks;
            *(uint4*)&Bs[bcol * AS_LD + bks]     = *(const uint4*)bp;
            *(uint4*)&Bs[bcol * AS_LD + bks + 8] = *(const uint4*)(bp + 8);
        }
        __syncthreads();
        short8v a = *(short8v*)&As[arow * AS_LD + ak8];
#pragma unroll
        for (int c = 0; c < 8; ++c) {
            short8v b = *(short8v*)&Bs[(c * 16 + (lane & 15)) * AS_LD + ak8];
            acc[c] = __builtin_amdgcn_mfma_f32_16x16x32_bf16(a, b, acc[c], 0, 0, 0);
        }
        __syncthreads();
    }
    int cl = lane & 15;
    int r0 = row0 + wr + ((lane >> 4) << 2);
#pragma unroll
    for (int c = 0; c < 8; ++c) {
        int cc = c * 16 + cl;
#pragma unroll
        for (int r = 0; r < 4; ++r) {
            int rr = r0 + r;
            if (rr < M) Cb[(size_t)rr * 128 + cc] = f2bu(acc[c][r]);
        }
    }
    // fused attention dots: asrc/adst[row][h] = dot(hp_row[h*32..], att[h][..])
    if (att) {
#pragma unroll
        for (int h = 0; h < HEADS; ++h) {
            float as0 = att[h * 64 + cl];
            float as1 = att[h * 64 + 16 + cl];
            float ad0 = att[h * 64 + 32 + cl];
            float ad1 = att[h * 64 + 48 + cl];
#pragma unroll
            for (int r = 0; r < 4; ++r) {
                float ps = acc[2 * h][r] * as0 + acc[2 * h + 1][r] * as1;
                float pd = acc[2 * h][r] * ad0 + acc[2 * h + 1][r] * ad1;
#pragma unroll
                for (int off = 1; off < 16; off <<= 1) {
                    ps += __shfl_xor(ps, off);
                    pd += __shfl_xor(pd, off);
                }
                int rr = r0 + r;
                if (cl == 0 && rr < M) {
                    asrc[rr * 4 + h] = ps;
                    adst[rr * 4 + h] = pd;
                }
            }
        }
    }
}

// ---------- fused MFMA classifier + in-register log_softmax ----------
__global__ __launch_bounds__(256) void cls_mfma(const ushortT* __restrict__ A,
                                                const ushortT* __restrict__ BT,
                                                float* __restrict__ out, int M) {
    __shared__ ushortT As[64 * AS_LD];
    __shared__ ushortT Bs[48 * AS_LD];
    int t = threadIdx.x;
    int w = t >> 6, lane = t & 63;
    int row0 = blockIdx.x * 64;
    int ar = t >> 2, ak = (t & 3) * 8;
    int wr = w * 16;
    int arow = wr + (lane & 15);
    int ak8 = (lane >> 4) * 8;
    f32x4 acc[3] = {};

    for (int k0 = 0; k0 < 128; k0 += 32) {
        int grow = row0 + ar;
        uint4 p = make_uint4(0, 0, 0, 0);
        if (grow < M) p = *(const uint4*)(A + (size_t)grow * 128 + k0 + ak);
        *(uint4*)&As[ar * AS_LD + ak] = p;
        if (t < 96) {
            int bcol = t >> 1, bks = (t & 1) * 16;
            const ushortT* bp = BT + bcol * 128 + k0 + bks;
            *(uint4*)&Bs[bcol * AS_LD + bks]     = *(const uint4*)bp;
            *(uint4*)&Bs[bcol * AS_LD + bks + 8] = *(const uint4*)(bp + 8);
        }
        __syncthreads();
        short8v a = *(short8v*)&As[arow * AS_LD + ak8];
#pragma unroll
        for (int c = 0; c < 3; ++c) {
            short8v b = *(short8v*)&Bs[(c * 16 + (lane & 15)) * AS_LD + ak8];
            acc[c] = __builtin_amdgcn_mfma_f32_16x16x32_bf16(a, b, acc[c], 0, 0, 0);
        }
        __syncthreads();
    }
    int cl = lane & 15;
    int r0 = row0 + wr + ((lane >> 4) << 2);
#pragma unroll
    for (int r = 0; r < 4; ++r) {
        float v0 = acc[0][r], v1 = acc[1][r];
        float v2 = (cl < 8) ? acc[2][r] : -1e30f;
        float m = fmaxf(fmaxf(v0, v1), v2);
#pragma unroll
        for (int off = 1; off < 16; off <<= 1) m = fmaxf(m, __shfl_xor(m, off));
        float e = __expf(v0 - m) + __expf(v1 - m) + ((cl < 8) ? __expf(v2 - m) : 0.f);
#pragma unroll
        for (int off = 1; off < 16; off <<= 1) e += __shfl_xor(e, off);
        float ls = m + __logf(e);
        int rr = r0 + r;
        if (rr < M) {
            float* o = out + (size_t)rr * CLASSES;
            o[cl] = v0 - ls;
            o[16 + cl] = v1 - ls;
            if (cl < 8) o[32 + cl] = v2 - ls;
        }
    }
}

// ---------- CSR build via two-level bucket sort ----------
__global__ __launch_bounds__(256) void bucket_count(const int* __restrict__ ei,
                                                    int* __restrict__ bcnt) {
    __shared__ int hist[NBUCK];
    int t = threadIdx.x;
    if (t < NBUCK) hist[t] = 0;
    __syncthreads();
    int base = blockIdx.x * CHUNK;
    int end = min(base + CHUNK, EE);
    for (int i = base + t; i < end; i += 256) {
        int d = (i < N_EDGES) ? ei[N_EDGES + i] : (i - N_EDGES);
        atomicAdd(&hist[d >> BSHIFT], 1);
    }
    __syncthreads();
    if (t < NBUCK && hist[t]) atomicAdd(&bcnt[t], hist[t]);
}

__global__ void bucket_scan(const int* __restrict__ bcnt, int* __restrict__ bbase,
                            int* __restrict__ gcur, int* __restrict__ rowptr) {
    if (threadIdx.x == 0) {
        int run = 0;
        for (int b = 0; b < NBUCK; ++b) { bbase[b] = run; gcur[b] = run; run += bcnt[b]; }
        bbase[NBUCK] = run;
        rowptr[N_NODES] = run;   // == EE
    }
}

__global__ __launch_bounds__(256) void bucket_scatter(const int* __restrict__ ei,
                                                      int* __restrict__ gcur,
                                                      uintT* __restrict__ ebuf) {
    __shared__ int hist[NBUCK];
    __shared__ int rbase[NBUCK];
    int t = threadIdx.x;
    if (t < NBUCK) hist[t] = 0;
    __syncthreads();
    int base = blockIdx.x * CHUNK;
    int end = min(base + CHUNK, EE);
    for (int i = base + t; i < end; i += 256) {
        int d = (i < N_EDGES) ? ei[N_EDGES + i] : (i - N_EDGES);
        atomicAdd(&hist[d >> BSHIFT], 1);
    }
    __syncthreads();
    if (t < NBUCK) {
        int c = hist[t];
        rbase[t] = c ? atomicAdd(&gcur[t], c) : 0;
    }
    __syncthreads();
    if (t < NBUCK) hist[t] = 0;
    __syncthreads();
    for (int i = base + t; i < end; i += 256) {
        int s, d;
        if (i < N_EDGES) { s = ei[i]; d = ei[N_EDGES + i]; } else { s = d = i - N_EDGES; }
        int b = d >> BSHIFT;
        int pos = rbase[b] + atomicAdd(&hist[b], 1);
        ebuf[pos] = ((uintT)s << BSHIFT) | (uintT)(d & 511);   // src(16b) | local dst(9b)
    }
}

__global__ __launch_bounds__(256) void csr_local(const uintT* __restrict__ ebuf,
                                                 const int* __restrict__ bbase,
                                                 int* __restrict__ rowptr,
                                                 int* __restrict__ ssrc) {
    __shared__ int cnt[512];
    __shared__ int cur[512];
    __shared__ int wsum[4];
    int b = blockIdx.x;
    int t = threadIdx.x;
    int node0 = b << BSHIFT;
    int nb = min(512, N_NODES - node0);
    int beg = bbase[b], end = bbase[b + 1];
    cnt[t] = 0; cnt[t + 256] = 0;
    __syncthreads();
    for (int i = beg + t; i < end; i += 256)
        atomicAdd(&cnt[ebuf[i] & 511], 1);
    __syncthreads();
    int v0 = cnt[2 * t], v1 = cnt[2 * t + 1];
    int s = v0 + v1;
    int lane = t & 63, w = t >> 6;
    int x = s;
#pragma unroll
    for (int off = 1; off < 64; off <<= 1) { int y = __shfl_up(x, off); if (lane >= off) x += y; }
    if (lane == 63) wsum[w] = x;
    __syncthreads();
    if (t == 0) { int run = 0; for (int k = 0; k < 4; ++k) { int tmp = wsum[k]; wsum[k] = run; run += tmp; } }
    __syncthreads();
    int excl = wsum[w] + x - s;
    cnt[2 * t] = excl; cnt[2 * t + 1] = excl + v0;
    cur[2 * t] = excl; cur[2 * t + 1] = excl + v0;
    if (2 * t < nb)     rowptr[node0 + 2 * t]     = beg + excl;
    if (2 * t + 1 < nb) rowptr[node0 + 2 * t + 1] = beg + excl + v0;
    __syncthreads();
    for (int i = beg + t; i < end; i += 256) {
        uintT e = ebuf[i];
        int pos = beg + atomicAdd(&cur[e & 511], 1);
        ssrc[pos] = (int)(e >> BSHIFT);
    }
}

// ---------- GAT aggregate ----------
__device__ __forceinline__ float lrelu(float v) { return v > 0.f ? v : SLOPE * v; }

// single-node path (R10-proven): full wave on one node; sexp/ssrcl/sm are per-wave LDS
__device__ __forceinline__ void gat_one(
    int node, int beg, int deg, int lane,
    const int* __restrict__ ssrc, const float* __restrict__ asrc,
    const float* __restrict__ adst, const ushortT* __restrict__ hpb,
    const float* __restrict__ bias, ushortT* __restrict__ foutB,
    float* sexp, int* ssrcl, float* sm)
{
    float4 ad = *(const float4*)(adst + (size_t)node * 4);
    int g = lane >> 4, i0 = lane & 15;
    float acc0 = 0.f, acc1 = 0.f;
    float zinv;
    const ushortT* hrow = hpb + lane * 2;

    if (deg <= 64) {
        float4 lg = make_float4(-1e30f, -1e30f, -1e30f, -1e30f);
        int soff = 0;
        if (lane < deg) {
            int s = ssrc[beg + lane];
            float4 a = *(const float4*)(asrc + (size_t)s * 4);
            lg.x = lrelu(a.x + ad.x);
            lg.y = lrelu(a.y + ad.y);
            lg.z = lrelu(a.z + ad.z);
            lg.w = lrelu(a.w + ad.w);
            soff = s * HC;
        }
        ssrcl[lane] = soff;
        *(float4*)&sexp[lane * 4] = lg;
        asm volatile("s_waitcnt lgkmcnt(0)" ::: "memory");
        float mg =     sexp[i0 * 4 + g];
        mg = fmaxf(mg, sexp[(i0 + 16) * 4 + g]);
        mg = fmaxf(mg, sexp[(i0 + 32) * 4 + g]);
        mg = fmaxf(mg, sexp[(i0 + 48) * 4 + g]);
#pragma unroll
        for (int off = 1; off < 16; off <<= 1) mg = fmaxf(mg, __shfl_xor(mg, off));
        if (i0 == 0) sm[g] = mg;
        asm volatile("s_waitcnt lgkmcnt(0)" ::: "memory");
        float4 m = *(float4*)&sm[0];
        float4 ex;
        ex.x = __expf(lg.x - m.x);
        ex.y = __expf(lg.y - m.y);
        ex.z = __expf(lg.z - m.z);
        ex.w = __expf(lg.w - m.w);
        *(float4*)&sexp[lane * 4] = ex;
        asm volatile("s_waitcnt lgkmcnt(0)" ::: "memory");
        float zg = sexp[i0 * 4 + g];
        zg +=      sexp[(i0 + 16) * 4 + g];
        zg +=      sexp[(i0 + 32) * 4 + g];
        zg +=      sexp[(i0 + 48) * 4 + g];
#pragma unroll
        for (int off = 1; off < 16; off <<= 1) zg += __shfl_xor(zg, off);
        zinv = 1.f / zg;
#pragma unroll 4
        for (int i = 0; i < deg; ++i) {
            float e = sexp[i * 4 + g];
            int off = ssrcl[i];
            uintT u = *(const uintT*)(hrow + off);
            acc0 = fmaf(__uint_as_float(u << 16),         e, acc0);
            acc1 = fmaf(__uint_as_float(u & 0xffff0000u), e, acc1);
        }
    } else {
        float4 m = make_float4(-1e30f, -1e30f, -1e30f, -1e30f);
        for (int i = lane; i < deg; i += 64) {
            int s = ssrc[beg + i];
            float4 a = *(const float4*)(asrc + (size_t)s * 4);
            m.x = fmaxf(m.x, lrelu(a.x + ad.x));
            m.y = fmaxf(m.y, lrelu(a.y + ad.y));
            m.z = fmaxf(m.z, lrelu(a.z + ad.z));
            m.w = fmaxf(m.w, lrelu(a.w + ad.w));
        }
#pragma unroll
        for (int off = 1; off < 64; off <<= 1) {
            m.x = fmaxf(m.x, __shfl_xor(m.x, off));
            m.y = fmaxf(m.y, __shfl_xor(m.y, off));
            m.z = fmaxf(m.z, __shfl_xor(m.z, off));
            m.w = fmaxf(m.w, __shfl_xor(m.w, off));
        }
        float4 zp = make_float4(0.f, 0.f, 0.f, 0.f);
        for (int c0 = 0; c0 < deg; c0 += 64) {
            int n_ch = min(64, deg - c0);
            if (lane < n_ch) {
                int s = ssrc[beg + c0 + lane];
                float4 a = *(const float4*)(asrc + (size_t)s * 4);
                float4 ex;
                ex.x = __expf(lrelu(a.x + ad.x) - m.x);
                ex.y = __expf(lrelu(a.y + ad.y) - m.y);
                ex.z = __expf(lrelu(a.z + ad.z) - m.z);
                ex.w = __expf(lrelu(a.w + ad.w) - m.w);
                *(float4*)&sexp[lane * 4] = ex;
                ssrcl[lane] = s * HC;
                zp.x += ex.x; zp.y += ex.y; zp.z += ex.z; zp.w += ex.w;
            }
            asm volatile("s_waitcnt lgkmcnt(0)" ::: "memory");
#pragma unroll 4
            for (int i = 0; i < n_ch; ++i) {
                float e = sexp[i * 4 + g];
                int off = ssrcl[i];
                uintT u = *(const uintT*)(hrow + off);
                acc0 = fmaf(__uint_as_float(u << 16),         e, acc0);
                acc1 = fmaf(__uint_as_float(u & 0xffff0000u), e, acc1);
            }
        }
#pragma unroll
        for (int off = 1; off < 64; off <<= 1) {
            zp.x += __shfl_xor(zp.x, off);
            zp.y += __shfl_xor(zp.y, off);
            zp.z += __shfl_xor(zp.z, off);
            zp.w += __shfl_xor(zp.w, off);
        }
        float zh = (g == 0) ? zp.x : (g == 1) ? zp.y : (g == 2) ? zp.z : zp.w;
        zinv = 1.f / zh;
    }

    float b0 = bias[lane * 2], b1 = bias[lane * 2 + 1];
    float v0 = acc0 * zinv + b0; v0 = v0 > 0.f ? v0 : __expf(v0) - 1.f;
    float v1 = acc1 * zinv + b1; v1 = v1 > 0.f ? v1 : __expf(v1) - 1.f;
    *(uintT*)(foutB + (size_t)node * HC + lane * 2) =
        (uintT)f2bu(v0) | ((uintT)f2bu(v1) << 16);
}

// paired kernel: each wave serves 2 consecutive nodes (deg<=32 each, 99.96% of pairs)
#define WPB 4   // waves per block
__global__ __launch_bounds__(256) void gat_gather2(
    const int* __restrict__ rowptr, const int* __restrict__ ssrc,
    const float* __restrict__ asrc, const float* __restrict__ adst,
    const ushortT* __restrict__ hpb, const float* __restrict__ bias,
    ushortT* __restrict__ foutB)
{
    __shared__ __align__(16) float s_exp[WPB][64][4];
    __shared__ int   s_src[WPB][64];
    __shared__ __align__(16) float s_m[WPB][8];
    __shared__ __align__(16) float s_z[WPB][8];
    int w = threadIdx.x >> 6;
    int lane = threadIdx.x & 63;
    int widx = blockIdx.x * WPB + w;
    int n0 = widx * 2;
    if (n0 >= N_NODES) return;
    int beg0 = rowptr[n0];
    int mid  = rowptr[n0 + 1];
    int end1 = rowptr[n0 + 2];
    int deg0 = mid - beg0, deg1 = end1 - mid;

    if (deg0 <= 32 && deg1 <= 32) {
        int half = lane >> 5;        // which node this lane serves
        int ll = lane & 31;
        int nn = n0 + half;
        int mybeg = half ? mid : beg0;
        int mydeg = half ? deg1 : deg0;
        float4 ad = *(const float4*)(adst + (size_t)nn * 4);
        // ---- edge logits (slot ll = edge index) ----
        float4 lg = make_float4(-1e30f, -1e30f, -1e30f, -1e30f);
        int soff = 0;
        if (ll < mydeg) {
            int s = ssrc[mybeg + ll];
            float4 a = *(const float4*)(asrc + (size_t)s * 4);
            lg.x = lrelu(a.x + ad.x);
            lg.y = lrelu(a.y + ad.y);
            lg.z = lrelu(a.z + ad.z);
            lg.w = lrelu(a.w + ad.w);
            soff = s * HC;
        }
        s_src[w][lane] = soff;
        *(float4*)&s_exp[w][lane][0] = lg;
        asm volatile("s_waitcnt lgkmcnt(0)" ::: "memory");
        // ---- 8-group transpose max: grp = (node,head), 8 lanes each ----
        int grp = lane >> 3, gi = lane & 7;
        int gbase = (grp >> 2) << 5;   // 0 or 32
        int gh = grp & 3;
        float mg =     s_exp[w][gbase + gi][gh];
        mg = fmaxf(mg, s_exp[w][gbase + gi +  8][gh]);
        mg = fmaxf(mg, s_exp[w][gbase + gi + 16][gh]);
        mg = fmaxf(mg, s_exp[w][gbase + gi + 24][gh]);
        mg = fmaxf(mg, __shfl_xor(mg, 1));
        mg = fmaxf(mg, __shfl_xor(mg, 2));
        mg = fmaxf(mg, __shfl_xor(mg, 4));
        if (gi == 0) s_m[w][grp] = mg;
        asm volatile("s_waitcnt lgkmcnt(0)" ::: "memory");
        float4 m = *(float4*)&s_m[w][half * 4];
        float4 ex;
        ex.x = __expf(lg.x - m.x);   // pad slots: lg=-1e30 -> 0
        ex.y = __expf(lg.y - m.y);
        ex.z = __expf(lg.z - m.z);
        ex.w = __expf(lg.w - m.w);
        *(float4*)&s_exp[w][lane][0] = ex;
        asm volatile("s_waitcnt lgkmcnt(0)" ::: "memory");
        // ---- 8-group transpose sum for z ----
        float zg = s_exp[w][gbase + gi][gh];
        zg +=      s_exp[w][gbase + gi +  8][gh];
        zg +=      s_exp[w][gbase + gi + 16][gh];
        zg +=      s_exp[w][gbase + gi + 24][gh];
        zg += __shfl_xor(zg, 1);
        zg += __shfl_xor(zg, 2);
        zg += __shfl_xor(zg, 4);
        if (gi == 0) s_z[w][grp] = zg;
        asm volatile("s_waitcnt lgkmcnt(0)" ::: "memory");
        int hd = ll >> 3;            // head of this lane's 4 channels
        float zinv = 1.f / s_z[w][half * 4 + hd];
        // ---- gather: lane owns channels ll*4..+3 of its node; pad edges have e=0 ----
        int maxdeg = max(deg0, deg1);
        int ebase = half << 5;
        const ushortT* hrow = hpb + ll * 4;
        float a0 = 0.f, a1 = 0.f, a2 = 0.f, a3 = 0.f;
#pragma unroll 4
        for (int i = 0; i < maxdeg; ++i) {
            float e = s_exp[w][ebase + i][hd];
            int off = s_src[w][ebase + i];
            uint2 u = *(const uint2*)(hrow + off);
            a0 = fmaf(__uint_as_float(u.x << 16),         e, a0);
            a1 = fmaf(__uint_as_float(u.x & 0xffff0000u), e, a1);
            a2 = fmaf(__uint_as_float(u.y << 16),         e, a2);
            a3 = fmaf(__uint_as_float(u.y & 0xffff0000u), e, a3);
        }
        // ---- normalize + bias + ELU + store (no cross-lane reduce needed) ----
        const float* bp = bias + ll * 4;
        float v0 = a0 * zinv + bp[0]; v0 = v0 > 0.f ? v0 : __expf(v0) - 1.f;
        float v1 = a1 * zinv + bp[1]; v1 = v1 > 0.f ? v1 : __expf(v1) - 1.f;
        float v2 = a2 * zinv + bp[2]; v2 = v2 > 0.f ? v2 : __expf(v2) - 1.f;
        float v3 = a3 * zinv + bp[3]; v3 = v3 > 0.f ? v3 : __expf(v3) - 1.f;
        uint2 o;
        o.x = (uintT)f2bu(v0) | ((uintT)f2bu(v1) << 16);
        o.y = (uintT)f2bu(v2) | ((uintT)f2bu(v3) << 16);
        *(uint2*)(foutB + (size_t)nn * HC + ll * 4) = o;
    } else {
        // rare: run the proven single-node path for each node sequentially
        gat_one(n0,     beg0, deg0, lane, ssrc, asrc, adst, hpb, bias, foutB,
                &s_exp[w][0][0], &s_src[w][0], &s_m[w][0]);
        gat_one(n0 + 1, mid,  deg1, lane, ssrc, asrc, adst, hpb, bias, foutB,
                &s_exp[w][0][0], &s_src[w][0], &s_m[w][0]);
    }
}

extern "C" void kernel_launch(void* const* d_in, const int* in_sizes, int n_in,
                              void* d_out, int out_size, void* d_ws, size_t ws_size,
                              hipStream_t stream) {
    const float* x      = (const float*)d_in[0];
    const int*   ei     = (const int*)d_in[1];
    const float* w_in   = (const float*)d_in[2];
    const float* Ws     = (const float*)d_in[3];
    const float* atts   = (const float*)d_in[4];
    const float* biases = (const float*)d_in[5];
    const float* w_out  = (const float*)d_in[6];
    float* out = (float*)d_out;

    // workspace partition
    char* wp = (char*)d_ws;
    ushortT* hb0 = (ushortT*)wp; wp += (size_t)N_NODES * HC * 2;   // bf16 h / final gat out
    ushortT* hb1 = (ushortT*)wp; wp += (size_t)N_NODES * HC * 2;   // bf16 gat_l0 out
    ushortT* hpb = (ushortT*)wp; wp += (size_t)N_NODES * HC * 2;   // bf16 hp
    float* asrc  = (float*)wp;   wp += (size_t)N_NODES * HEADS * 4;
    float* adst  = (float*)wp;   wp += (size_t)N_NODES * HEADS * 4;
    int* rowptr  = (int*)wp;     wp += (size_t)(N_NODES + 4) * 4;
    int* ssrc    = (int*)wp;     wp += (size_t)EE * 4;
    uintT* ebuf  = (uintT*)wp;   wp += (size_t)EE * 4;
    int* bcnt    = (int*)wp;     wp += (size_t)(NBUCK + 4) * 4;
    int* bbase   = (int*)wp;     wp += (size_t)(NBUCK + 4) * 4;
    int* gcur    = (int*)wp;     wp += (size_t)(NBUCK + 4) * 4;
    ushortT* w_inT = (ushortT*)wp; wp += (size_t)HC * F_IN * 2;
    ushortT* WsT   = (ushortT*)wp; wp += (size_t)LAYERS * HC * HC * 2;
    ushortT* woutT = (ushortT*)wp; wp += (size_t)48 * HC * 2;

    // ---- CSR build: two-level bucket sort ----
    hipMemsetAsync(bcnt, 0, (size_t)NBUCK * 4, stream);
    bucket_count<<<NBLK_E, 256, 0, stream>>>(ei, bcnt);
    bucket_scan<<<1, 64, 0, stream>>>(bcnt, bbase, gcur, rowptr);
    bucket_scatter<<<NBLK_E, 256, 0, stream>>>(ei, gcur, ebuf);
    csr_local<<<NBUCK, 256, 0, stream>>>(ebuf, bbase, rowptr, ssrc);

    // ---- weight convert+transpose (single launch) ----
    wconv_all<<<(32768 + 32768 + 6144 + 255) / 256, 256, 0, stream>>>(
        w_in, Ws, w_out, w_inT, WsT, woutT);

    int gblk = (N_NODES + 63) / 64;
    // h = x @ w_in  -> bf16 only
    gemm_mfma<true><<<gblk, 256, 0, stream>>>(x, w_inT, hb0, nullptr, nullptr, nullptr,
                                              N_NODES, F_IN);

    const ushortT* hin_b = hb0;
    ushortT* gout[LAYERS] = { hb1, hb0 };
    int g2blk = (N_NODES / 2 + WPB - 1) / WPB;
    for (int l = 0; l < LAYERS; ++l) {
        gemm_mfma<false><<<gblk, 256, 0, stream>>>(hin_b, WsT + (size_t)l * HC * HC, hpb,
                                                   atts + (size_t)l * HEADS * 2 * HID,
                                                   asrc, adst, N_NODES, HC);
        gat_gather2<<<g2blk, 64 * WPB, 0, stream>>>(
            rowptr, ssrc, asrc, adst, hpb, biases + (size_t)l * HC, gout[l]);
        hin_b = gout[l];
    }

    cls_mfma<<<gblk, 256, 0, stream>>>(hb0, woutT, out, N_NODES);
}

// Round 12
// 185.443 us; speedup vs baseline: 1.1642x; 1.0110x over previous
//
#include <hip/hip_runtime.h>
#include <hip/hip_bf16.h>
#include <math.h>

#define N_NODES 50000
#define N_EDGES 800000
#define F_IN 256
#define HID 32
#define HEADS 4
#define HC 128            // HID*HEADS
#define CLASSES 40
#define LAYERS 2
#define SLOPE 0.1f
#define EE (N_EDGES + N_NODES)   // edges + self loops

#define BSHIFT 9
#define NBUCK 98          // ceil(50000 / 512)
#define CHUNK 4096        // edges per block in bucket passes
#define NBLK_E ((EE + CHUNK - 1) / CHUNK)

typedef unsigned short ushortT;
typedef unsigned int uintT;
typedef __attribute__((ext_vector_type(8))) short short8v;   // 8 bf16 = 4 VGPRs
typedef __attribute__((ext_vector_type(4))) float f32x4;

__device__ __forceinline__ ushortT f2bu(float f) {
    __hip_bfloat16 h = __float2bfloat16(f);
    ushortT u; __builtin_memcpy(&u, &h, 2); return u;
}

// ---------- all weight transposes+converts + bcnt zero in one kernel ----------
__global__ void wconv_all(const float* __restrict__ w_in, const float* __restrict__ Ws,
                          const float* __restrict__ w_out, ushortT* __restrict__ w_inT,
                          ushortT* __restrict__ WsT, ushortT* __restrict__ woutT,
                          int* __restrict__ bcnt) {
    int i = blockIdx.x * 256 + threadIdx.x;
    if (i < NBUCK) bcnt[i] = 0;            // replaces hipMemsetAsync (saves a fill dispatch)
    if (i < 32768) {                       // w_in[256][128] -> w_inT[128][256]
        int r = i >> 7, c = i & 127;
        w_inT[(size_t)c * F_IN + r] = f2bu(w_in[i]);
    } else if (i < 65536) {                // Ws[2][128][128] -> WsT[2][128][128]^T
        int j = i - 32768;
        int l = j >> 14, jj = j & 16383;
        int r = jj >> 7, c = jj & 127;
        WsT[l * 16384 + c * 128 + r] = f2bu(Ws[j]);
    } else if (i < 65536 + 6144) {         // w_out[128][40] -> woutT[48][128], pad 0
        int j = i - 65536;
        int c = j >> 7, k = j & 127;
        woutT[j] = (c < CLASSES) ? f2bu(w_out[k * CLASSES + c]) : (ushortT)0;
    }
}

// ---------- MFMA bf16 GEMM, N fixed 128, optional fused attention-dot epilogue ----------
#define AS_LD 40
template<bool AF32>
__global__ __launch_bounds__(256) void gemm_mfma(const void* __restrict__ Aptr,
                                                 const ushortT* __restrict__ BT,
                                                 ushortT* __restrict__ Cb,
                                                 const float* __restrict__ att,  // may be null
                                                 float* __restrict__ asrc,
                                                 float* __restrict__ adst,
                                                 int M, int K) {
    __shared__ ushortT As[64 * AS_LD];    // [row][k<32]
    __shared__ ushortT Bs[128 * AS_LD];   // [col][k<32]
    int t = threadIdx.x;
    int w = t >> 6, lane = t & 63;
    int row0 = blockIdx.x * 64;
    int ar = t >> 2, ak = (t & 3) * 8;
    int bcol = t >> 1, bks = (t & 1) * 16;
    int wr = w * 16;
    int arow = wr + (lane & 15);
    int ak8 = (lane >> 4) * 8;
    f32x4 acc[8] = {};

    for (int k0 = 0; k0 < K; k0 += 32) {
        int grow = row0 + ar;
        if (AF32) {
            const float* A = (const float*)Aptr;
            float4 v0 = make_float4(0.f, 0.f, 0.f, 0.f), v1 = v0;
            if (grow < M) {
                const float* ap = A + (size_t)grow * K + k0 + ak;
                v0 = *(const float4*)ap;
                v1 = *(const float4*)(ap + 4);
            }
            uint4 p;
            p.x = (uintT)f2bu(v0.x) | ((uintT)f2bu(v0.y) << 16);
            p.y = (uintT)f2bu(v0.z) | ((uintT)f2bu(v0.w) << 16);
            p.z = (uintT)f2bu(v1.x) | ((uintT)f2bu(v1.y) << 16);
            p.w = (uintT)f2bu(v1.z) | ((uintT)f2bu(v1.w) << 16);
            *(uint4*)&As[ar * AS_LD + ak] = p;
        } else {
            const ushortT* A = (const ushortT*)Aptr;
            uint4 p = make_uint4(0, 0, 0, 0);
            if (grow < M) p = *(const uint4*)(A + (size_t)grow * K + k0 + ak);
            *(uint4*)&As[ar * AS_LD + ak] = p;
        }
        {
            const ushortT* bp = BT + (size_t)bcol * K + k0 + bks;
            *(uint4*)&Bs[bcol * AS_LD + bks]     = *(const uint4*)bp;
            *(uint4*)&Bs[bcol * AS_LD + bks + 8] = *(const uint4*)(bp + 8);
        }
        __syncthreads();
        short8v a = *(short8v*)&As[arow * AS_LD + ak8];
#pragma unroll
        for (int c = 0; c < 8; ++c) {
            short8v b = *(short8v*)&Bs[(c * 16 + (lane & 15)) * AS_LD + ak8];
            acc[c] = __builtin_amdgcn_mfma_f32_16x16x32_bf16(a, b, acc[c], 0, 0, 0);
        }
        __syncthreads();
    }
    int cl = lane & 15;
    int r0 = row0 + wr + ((lane >> 4) << 2);
#pragma unroll
    for (int c = 0; c < 8; ++c) {
        int cc = c * 16 + cl;
#pragma unroll
        for (int r = 0; r < 4; ++r) {
            int rr = r0 + r;
            if (rr < M) Cb[(size_t)rr * 128 + cc] = f2bu(acc[c][r]);
        }
    }
    // fused attention dots: asrc/adst[row][h] = dot(hp_row[h*32..], att[h][..])
    if (att) {
#pragma unroll
        for (int h = 0; h < HEADS; ++h) {
            float as0 = att[h * 64 + cl];
            float as1 = att[h * 64 + 16 + cl];
            float ad0 = att[h * 64 + 32 + cl];
            float ad1 = att[h * 64 + 48 + cl];
#pragma unroll
            for (int r = 0; r < 4; ++r) {
                float ps = acc[2 * h][r] * as0 + acc[2 * h + 1][r] * as1;
                float pd = acc[2 * h][r] * ad0 + acc[2 * h + 1][r] * ad1;
#pragma unroll
                for (int off = 1; off < 16; off <<= 1) {
                    ps += __shfl_xor(ps, off);
                    pd += __shfl_xor(pd, off);
                }
                int rr = r0 + r;
                if (cl == 0 && rr < M) {
                    asrc[rr * 4 + h] = ps;
                    adst[rr * 4 + h] = pd;
                }
            }
        }
    }
}

// ---------- fused MFMA classifier + in-register log_softmax ----------
__global__ __launch_bounds__(256) void cls_mfma(const ushortT* __restrict__ A,
                                                const ushortT* __restrict__ BT,
                                                float* __restrict__ out, int M) {
    __shared__ ushortT As[64 * AS_LD];
    __shared__ ushortT Bs[48 * AS_LD];
    int t = threadIdx.x;
    int w = t >> 6, lane = t & 63;
    int row0 = blockIdx.x * 64;
    int ar = t >> 2, ak = (t & 3) * 8;
    int wr = w * 16;
    int arow = wr + (lane & 15);
    int ak8 = (lane >> 4) * 8;
    f32x4 acc[3] = {};

    for (int k0 = 0; k0 < 128; k0 += 32) {
        int grow = row0 + ar;
        uint4 p = make_uint4(0, 0, 0, 0);
        if (grow < M) p = *(const uint4*)(A + (size_t)grow * 128 + k0 + ak);
        *(uint4*)&As[ar * AS_LD + ak] = p;
        if (t < 96) {
            int bcol = t >> 1, bks = (t & 1) * 16;
            const ushortT* bp = BT + bcol * 128 + k0 + bks;
            *(uint4*)&Bs[bcol * AS_LD + bks]     = *(const uint4*)bp;
            *(uint4*)&Bs[bcol * AS_LD + bks + 8] = *(const uint4*)(bp + 8);
        }
        __syncthreads();
        short8v a = *(short8v*)&As[arow * AS_LD + ak8];
#pragma unroll
        for (int c = 0; c < 3; ++c) {
            short8v b = *(short8v*)&Bs[(c * 16 + (lane & 15)) * AS_LD + ak8];
            acc[c] = __builtin_amdgcn_mfma_f32_16x16x32_bf16(a, b, acc[c], 0, 0, 0);
        }
        __syncthreads();
    }
    int cl = lane & 15;
    int r0 = row0 + wr + ((lane >> 4) << 2);
#pragma unroll
    for (int r = 0; r < 4; ++r) {
        float v0 = acc[0][r], v1 = acc[1][r];
        float v2 = (cl < 8) ? acc[2][r] : -1e30f;
        float m = fmaxf(fmaxf(v0, v1), v2);
#pragma unroll
        for (int off = 1; off < 16; off <<= 1) m = fmaxf(m, __shfl_xor(m, off));
        float e = __expf(v0 - m) + __expf(v1 - m) + ((cl < 8) ? __expf(v2 - m) : 0.f);
#pragma unroll
        for (int off = 1; off < 16; off <<= 1) e += __shfl_xor(e, off);
        float ls = m + __logf(e);
        int rr = r0 + r;
        if (rr < M) {
            float* o = out + (size_t)rr * CLASSES;
            o[cl] = v0 - ls;
            o[16 + cl] = v1 - ls;
            if (cl < 8) o[32 + cl] = v2 - ls;
        }
    }
}

// ---------- CSR build via two-level bucket sort ----------
__global__ __launch_bounds__(256) void bucket_count(const int* __restrict__ ei,
                                                    int* __restrict__ bcnt) {
    __shared__ int hist[NBUCK];
    int t = threadIdx.x;
    if (t < NBUCK) hist[t] = 0;
    __syncthreads();
    int base = blockIdx.x * CHUNK;
    int end = min(base + CHUNK, EE);
    for (int i = base + t; i < end; i += 256) {
        int d = (i < N_EDGES) ? ei[N_EDGES + i] : (i - N_EDGES);
        atomicAdd(&hist[d >> BSHIFT], 1);
    }
    __syncthreads();
    if (t < NBUCK && hist[t]) atomicAdd(&bcnt[t], hist[t]);
}

__global__ void bucket_scan(const int* __restrict__ bcnt, int* __restrict__ bbase,
                            int* __restrict__ gcur, int* __restrict__ rowptr) {
    if (threadIdx.x == 0) {
        int run = 0;
        for (int b = 0; b < NBUCK; ++b) { bbase[b] = run; gcur[b] = run; run += bcnt[b]; }
        bbase[NBUCK] = run;
        rowptr[N_NODES] = run;   // == EE
    }
}

__global__ __launch_bounds__(256) void bucket_scatter(const int* __restrict__ ei,
                                                      int* __restrict__ gcur,
                                                      uintT* __restrict__ ebuf) {
    __shared__ int hist[NBUCK];
    __shared__ int rbase[NBUCK];
    int t = threadIdx.x;
    if (t < NBUCK) hist[t] = 0;
    __syncthreads();
    int base = blockIdx.x * CHUNK;
    int end = min(base + CHUNK, EE);
    for (int i = base + t; i < end; i += 256) {
        int d = (i < N_EDGES) ? ei[N_EDGES + i] : (i - N_EDGES);
        atomicAdd(&hist[d >> BSHIFT], 1);
    }
    __syncthreads();
    if (t < NBUCK) {
        int c = hist[t];
        rbase[t] = c ? atomicAdd(&gcur[t], c) : 0;
    }
    __syncthreads();
    if (t < NBUCK) hist[t] = 0;
    __syncthreads();
    for (int i = base + t; i < end; i += 256) {
        int s, d;
        if (i < N_EDGES) { s = ei[i]; d = ei[N_EDGES + i]; } else { s = d = i - N_EDGES; }
        int b = d >> BSHIFT;
        int pos = rbase[b] + atomicAdd(&hist[b], 1);
        ebuf[pos] = ((uintT)s << BSHIFT) | (uintT)(d & 511);   // src(16b) | local dst(9b)
    }
}

__global__ __launch_bounds__(256) void csr_local(const uintT* __restrict__ ebuf,
                                                 const int* __restrict__ bbase,
                                                 int* __restrict__ rowptr,
                                                 int* __restrict__ ssrc) {
    __shared__ int cnt[512];
    __shared__ int cur[512];
    __shared__ int wsum[4];
    int b = blockIdx.x;
    int t = threadIdx.x;
    int node0 = b << BSHIFT;
    int nb = min(512, N_NODES - node0);
    int beg = bbase[b], end = bbase[b + 1];
    cnt[t] = 0; cnt[t + 256] = 0;
    __syncthreads();
    for (int i = beg + t; i < end; i += 256)
        atomicAdd(&cnt[ebuf[i] & 511], 1);
    __syncthreads();
    int v0 = cnt[2 * t], v1 = cnt[2 * t + 1];
    int s = v0 + v1;
    int lane = t & 63, w = t >> 6;
    int x = s;
#pragma unroll
    for (int off = 1; off < 64; off <<= 1) { int y = __shfl_up(x, off); if (lane >= off) x += y; }
    if (lane == 63) wsum[w] = x;
    __syncthreads();
    if (t == 0) { int run = 0; for (int k = 0; k < 4; ++k) { int tmp = wsum[k]; wsum[k] = run; run += tmp; } }
    __syncthreads();
    int excl = wsum[w] + x - s;
    cnt[2 * t] = excl; cnt[2 * t + 1] = excl + v0;
    cur[2 * t] = excl; cur[2 * t + 1] = excl + v0;
    if (2 * t < nb)     rowptr[node0 + 2 * t]     = beg + excl;
    if (2 * t + 1 < nb) rowptr[node0 + 2 * t + 1] = beg + excl + v0;
    __syncthreads();
    for (int i = beg + t; i < end; i += 256) {
        uintT e = ebuf[i];
        int pos = beg + atomicAdd(&cur[e & 511], 1);
        ssrc[pos] = (int)(e >> BSHIFT);
    }
}

// ---------- GAT aggregate ----------
__device__ __forceinline__ float lrelu(float v) { return v > 0.f ? v : SLOPE * v; }

// single-node path (R10-proven): full wave on one node; sexp/ssrcl/sm are per-wave LDS
__device__ __forceinline__ void gat_one(
    int node, int beg, int deg, int lane,
    const int* __restrict__ ssrc, const float* __restrict__ asrc,
    const float* __restrict__ adst, const ushortT* __restrict__ hpb,
    const float* __restrict__ bias, ushortT* __restrict__ foutB,
    float* sexp, int* ssrcl, float* sm)
{
    float4 ad = *(const float4*)(adst + (size_t)node * 4);
    int g = lane >> 4, i0 = lane & 15;
    float acc0 = 0.f, acc1 = 0.f;
    float zinv;
    const ushortT* hrow = hpb + lane * 2;

    if (deg <= 64) {
        float4 lg = make_float4(-1e30f, -1e30f, -1e30f, -1e30f);
        int soff = 0;
        if (lane < deg) {
            int s = ssrc[beg + lane];
            float4 a = *(const float4*)(asrc + (size_t)s * 4);
            lg.x = lrelu(a.x + ad.x);
            lg.y = lrelu(a.y + ad.y);
            lg.z = lrelu(a.z + ad.z);
            lg.w = lrelu(a.w + ad.w);
            soff = s * HC;
        }
        ssrcl[lane] = soff;
        *(float4*)&sexp[lane * 4] = lg;
        asm volatile("s_waitcnt lgkmcnt(0)" ::: "memory");
        float mg =     sexp[i0 * 4 + g];
        mg = fmaxf(mg, sexp[(i0 + 16) * 4 + g]);
        mg = fmaxf(mg, sexp[(i0 + 32) * 4 + g]);
        mg = fmaxf(mg, sexp[(i0 + 48) * 4 + g]);
#pragma unroll
        for (int off = 1; off < 16; off <<= 1) mg = fmaxf(mg, __shfl_xor(mg, off));
        if (i0 == 0) sm[g] = mg;
        asm volatile("s_waitcnt lgkmcnt(0)" ::: "memory");
        float4 m = *(float4*)&sm[0];
        float4 ex;
        ex.x = __expf(lg.x - m.x);
        ex.y = __expf(lg.y - m.y);
        ex.z = __expf(lg.z - m.z);
        ex.w = __expf(lg.w - m.w);
        *(float4*)&sexp[lane * 4] = ex;
        asm volatile("s_waitcnt lgkmcnt(0)" ::: "memory");
        float zg = sexp[i0 * 4 + g];
        zg +=      sexp[(i0 + 16) * 4 + g];
        zg +=      sexp[(i0 + 32) * 4 + g];
        zg +=      sexp[(i0 + 48) * 4 + g];
#pragma unroll
        for (int off = 1; off < 16; off <<= 1) zg += __shfl_xor(zg, off);
        zinv = 1.f / zg;
#pragma unroll 4
        for (int i = 0; i < deg; ++i) {
            float e = sexp[i * 4 + g];
            int off = ssrcl[i];
            uintT u = *(const uintT*)(hrow + off);
            acc0 = fmaf(__uint_as_float(u << 16),         e, acc0);
            acc1 = fmaf(__uint_as_float(u & 0xffff0000u), e, acc1);
        }
    } else {
        float4 m = make_float4(-1e30f, -1e30f, -1e30f, -1e30f);
        for (int i = lane; i < deg; i += 64) {
            int s = ssrc[beg + i];
            float4 a = *(const float4*)(asrc + (size_t)s * 4);
            m.x = fmaxf(m.x, lrelu(a.x + ad.x));
            m.y = fmaxf(m.y, lrelu(a.y + ad.y));
            m.z = fmaxf(m.z, lrelu(a.z + ad.z));
            m.w = fmaxf(m.w, lrelu(a.w + ad.w));
        }
#pragma unroll
        for (int off = 1; off < 64; off <<= 1) {
            m.x = fmaxf(m.x, __shfl_xor(m.x, off));
            m.y = fmaxf(m.y, __shfl_xor(m.y, off));
            m.z = fmaxf(m.z, __shfl_xor(m.z, off));
            m.w = fmaxf(m.w, __shfl_xor(m.w, off));
        }
        float4 zp = make_float4(0.f, 0.f, 0.f, 0.f);
        for (int c0 = 0; c0 < deg; c0 += 64) {
            int n_ch = min(64, deg - c0);
            if (lane < n_ch) {
                int s = ssrc[beg + c0 + lane];
                float4 a = *(const float4*)(asrc + (size_t)s * 4);
                float4 ex;
                ex.x = __expf(lrelu(a.x + ad.x) - m.x);
                ex.y = __expf(lrelu(a.y + ad.y) - m.y);
                ex.z = __expf(lrelu(a.z + ad.z) - m.z);
                ex.w = __expf(lrelu(a.w + ad.w) - m.w);
                *(float4*)&sexp[lane * 4] = ex;
                ssrcl[lane] = s * HC;
                zp.x += ex.x; zp.y += ex.y; zp.z += ex.z; zp.w += ex.w;
            }
            asm volatile("s_waitcnt lgkmcnt(0)" ::: "memory");
#pragma unroll 4
            for (int i = 0; i < n_ch; ++i) {
                float e = sexp[i * 4 + g];
                int off = ssrcl[i];
                uintT u = *(const uintT*)(hrow + off);
                acc0 = fmaf(__uint_as_float(u << 16),         e, acc0);
                acc1 = fmaf(__uint_as_float(u & 0xffff0000u), e, acc1);
            }
        }
#pragma unroll
        for (int off = 1; off < 64; off <<= 1) {
            zp.x += __shfl_xor(zp.x, off);
            zp.y += __shfl_xor(zp.y, off);
            zp.z += __shfl_xor(zp.z, off);
            zp.w += __shfl_xor(zp.w, off);
        }
        float zh = (g == 0) ? zp.x : (g == 1) ? zp.y : (g == 2) ? zp.z : zp.w;
        zinv = 1.f / zh;
    }

    float b0 = bias[lane * 2], b1 = bias[lane * 2 + 1];
    float v0 = acc0 * zinv + b0; v0 = v0 > 0.f ? v0 : __expf(v0) - 1.f;
    float v1 = acc1 * zinv + b1; v1 = v1 > 0.f ? v1 : __expf(v1) - 1.f;
    *(uintT*)(foutB + (size_t)node * HC + lane * 2) =
        (uintT)f2bu(v0) | ((uintT)f2bu(v1) << 16);
}

// paired kernel: each wave serves 2 consecutive nodes (deg<=32 each, 99.96% of pairs)
#define WPB 4   // waves per block
__global__ __launch_bounds__(256) void gat_gather2(
    const int* __restrict__ rowptr, const int* __restrict__ ssrc,
    const float* __restrict__ asrc, const float* __restrict__ adst,
    const ushortT* __restrict__ hpb, const float* __restrict__ bias,
    ushortT* __restrict__ foutB)
{
    __shared__ __align__(16) float s_exp[WPB][64][4];
    __shared__ int   s_src[WPB][64];
    __shared__ __align__(16) float s_m[WPB][8];
    __shared__ __align__(16) float s_z[WPB][8];
    int w = threadIdx.x >> 6;
    int lane = threadIdx.x & 63;
    int widx = blockIdx.x * WPB + w;
    int n0 = widx * 2;
    if (n0 >= N_NODES) return;
    int beg0 = rowptr[n0];
    int mid  = rowptr[n0 + 1];
    int end1 = rowptr[n0 + 2];
    int deg0 = mid - beg0, deg1 = end1 - mid;

    if (deg0 <= 32 && deg1 <= 32) {
        int half = lane >> 5;        // which node this lane serves
        int ll = lane & 31;
        int nn = n0 + half;
        int mybeg = half ? mid : beg0;
        int mydeg = half ? deg1 : deg0;
        float4 ad = *(const float4*)(adst + (size_t)nn * 4);
        // ---- edge logits (slot ll = edge index) ----
        float4 lg = make_float4(-1e30f, -1e30f, -1e30f, -1e30f);
        int soff = 0;
        if (ll < mydeg) {
            int s = ssrc[mybeg + ll];
            float4 a = *(const float4*)(asrc + (size_t)s * 4);
            lg.x = lrelu(a.x + ad.x);
            lg.y = lrelu(a.y + ad.y);
            lg.z = lrelu(a.z + ad.z);
            lg.w = lrelu(a.w + ad.w);
            soff = s * HC;
        }
        s_src[w][lane] = soff;
        *(float4*)&s_exp[w][lane][0] = lg;
        asm volatile("s_waitcnt lgkmcnt(0)" ::: "memory");
        // ---- 8-group transpose max: grp = (node,head), 8 lanes each ----
        int grp = lane >> 3, gi = lane & 7;
        int gbase = (grp >> 2) << 5;   // 0 or 32
        int gh = grp & 3;
        float mg =     s_exp[w][gbase + gi][gh];
        mg = fmaxf(mg, s_exp[w][gbase + gi +  8][gh]);
        mg = fmaxf(mg, s_exp[w][gbase + gi + 16][gh]);
        mg = fmaxf(mg, s_exp[w][gbase + gi + 24][gh]);
        mg = fmaxf(mg, __shfl_xor(mg, 1));
        mg = fmaxf(mg, __shfl_xor(mg, 2));
        mg = fmaxf(mg, __shfl_xor(mg, 4));
        if (gi == 0) s_m[w][grp] = mg;
        asm volatile("s_waitcnt lgkmcnt(0)" ::: "memory");
        float4 m = *(float4*)&s_m[w][half * 4];
        float4 ex;
        ex.x = __expf(lg.x - m.x);   // pad slots: lg=-1e30 -> 0
        ex.y = __expf(lg.y - m.y);
        ex.z = __expf(lg.z - m.z);
        ex.w = __expf(lg.w - m.w);
        *(float4*)&s_exp[w][lane][0] = ex;
        asm volatile("s_waitcnt lgkmcnt(0)" ::: "memory");
        // ---- 8-group transpose sum for z ----
        float zg = s_exp[w][gbase + gi][gh];
        zg +=      s_exp[w][gbase + gi +  8][gh];
        zg +=      s_exp[w][gbase + gi + 16][gh];
        zg +=      s_exp[w][gbase + gi + 24][gh];
        zg += __shfl_xor(zg, 1);
        zg += __shfl_xor(zg, 2);
        zg += __shfl_xor(zg, 4);
        if (gi == 0) s_z[w][grp] = zg;
        asm volatile("s_waitcnt lgkmcnt(0)" ::: "memory");
        int hd = ll >> 3;            // head of this lane's 4 channels
        float zinv = 1.f / s_z[w][half * 4 + hd];
        // ---- gather: lane owns channels ll*4..+3 of its node; pad edges have e=0 ----
        int maxdeg = max(deg0, deg1);
        int ebase = half << 5;
        const ushortT* hrow = hpb + ll * 4;
        float a0 = 0.f, a1 = 0.f, a2 = 0.f, a3 = 0.f;
#pragma unroll 4
        for (int i = 0; i < maxdeg; ++i) {
            float e = s_exp[w][ebase + i][hd];
            int off = s_src[w][ebase + i];
            uint2 u = *(const uint2*)(hrow + off);
            a0 = fmaf(__uint_as_float(u.x << 16),         e, a0);
            a1 = fmaf(__uint_as_float(u.x & 0xffff0000u), e, a1);
            a2 = fmaf(__uint_as_float(u.y << 16),         e, a2);
            a3 = fmaf(__uint_as_float(u.y & 0xffff0000u), e, a3);
        }
        // ---- normalize + bias + ELU + store (no cross-lane reduce needed) ----
        const float* bp = bias + ll * 4;
        float v0 = a0 * zinv + bp[0]; v0 = v0 > 0.f ? v0 : __expf(v0) - 1.f;
        float v1 = a1 * zinv + bp[1]; v1 = v1 > 0.f ? v1 : __expf(v1) - 1.f;
        float v2 = a2 * zinv + bp[2]; v2 = v2 > 0.f ? v2 : __expf(v2) - 1.f;
        float v3 = a3 * zinv + bp[3]; v3 = v3 > 0.f ? v3 : __expf(v3) - 1.f;
        uint2 o;
        o.x = (uintT)f2bu(v0) | ((uintT)f2bu(v1) << 16);
        o.y = (uintT)f2bu(v2) | ((uintT)f2bu(v3) << 16);
        *(uint2*)(foutB + (size_t)nn * HC + ll * 4) = o;
    } else {
        // rare: run the proven single-node path for each node sequentially
        gat_one(n0,     beg0, deg0, lane, ssrc, asrc, adst, hpb, bias, foutB,
                &s_exp[w][0][0], &s_src[w][0], &s_m[w][0]);
        gat_one(n0 + 1, mid,  deg1, lane, ssrc, asrc, adst, hpb, bias, foutB,
                &s_exp[w][0][0], &s_src[w][0], &s_m[w][0]);
    }
}

extern "C" void kernel_launch(void* const* d_in, const int* in_sizes, int n_in,
                              void* d_out, int out_size, void* d_ws, size_t ws_size,
                              hipStream_t stream) {
    const float* x      = (const float*)d_in[0];
    const int*   ei     = (const int*)d_in[1];
    const float* w_in   = (const float*)d_in[2];
    const float* Ws     = (const float*)d_in[3];
    const float* atts   = (const float*)d_in[4];
    const float* biases = (const float*)d_in[5];
    const float* w_out  = (const float*)d_in[6];
    float* out = (float*)d_out;

    // workspace partition
    char* wp = (char*)d_ws;
    ushortT* hb0 = (ushortT*)wp; wp += (size_t)N_NODES * HC * 2;   // bf16 h / final gat out
    ushortT* hb1 = (ushortT*)wp; wp += (size_t)N_NODES * HC * 2;   // bf16 gat_l0 out
    ushortT* hpb = (ushortT*)wp; wp += (size_t)N_NODES * HC * 2;   // bf16 hp
    float* asrc  = (float*)wp;   wp += (size_t)N_NODES * HEADS * 4;
    float* adst  = (float*)wp;   wp += (size_t)N_NODES * HEADS * 4;
    int* rowptr  = (int*)wp;     wp += (size_t)(N_NODES + 4) * 4;
    int* ssrc    = (int*)wp;     wp += (size_t)EE * 4;
    uintT* ebuf  = (uintT*)wp;   wp += (size_t)EE * 4;
    int* bcnt    = (int*)wp;     wp += (size_t)(NBUCK + 4) * 4;
    int* bbase   = (int*)wp;     wp += (size_t)(NBUCK + 4) * 4;
    int* gcur    = (int*)wp;     wp += (size_t)(NBUCK + 4) * 4;
    ushortT* w_inT = (ushortT*)wp; wp += (size_t)HC * F_IN * 2;
    ushortT* WsT   = (ushortT*)wp; wp += (size_t)LAYERS * HC * HC * 2;
    ushortT* woutT = (ushortT*)wp; wp += (size_t)48 * HC * 2;

    // ---- prep: weight convert+transpose + bcnt zero (replaces hipMemsetAsync) ----
    wconv_all<<<(32768 + 32768 + 6144 + 255) / 256, 256, 0, stream>>>(
        w_in, Ws, w_out, w_inT, WsT, woutT, bcnt);

    // ---- CSR build: two-level bucket sort ----
    bucket_count<<<NBLK_E, 256, 0, stream>>>(ei, bcnt);
    bucket_scan<<<1, 64, 0, stream>>>(bcnt, bbase, gcur, rowptr);
    bucket_scatter<<<NBLK_E, 256, 0, stream>>>(ei, gcur, ebuf);
    csr_local<<<NBUCK, 256, 0, stream>>>(ebuf, bbase, rowptr, ssrc);

    int gblk = (N_NODES + 63) / 64;
    // h = x @ w_in  -> bf16 only
    gemm_mfma<true><<<gblk, 256, 0, stream>>>(x, w_inT, hb0, nullptr, nullptr, nullptr,
                                              N_NODES, F_IN);

    const ushortT* hin_b = hb0;
    ushortT* gout[LAYERS] = { hb1, hb0 };
    int g2blk = (N_NODES / 2 + WPB - 1) / WPB;
    for (int l = 0; l < LAYERS; ++l) {
        gemm_mfma<false><<<gblk, 256, 0, stream>>>(hin_b, WsT + (size_t)l * HC * HC, hpb,
                                                   atts + (size_t)l * HEADS * 2 * HID,
                                                   asrc, adst, N_NODES, HC);
        gat_gather2<<<g2blk, 64 * WPB, 0, stream>>>(
            rowptr, ssrc, asrc, adst, hpb, biases + (size_t)l * HC, gout[l]);
        hin_b = gout[l];
    }

    cls_mfma<<<gblk, 256, 0, stream>>>(hb0, woutT, out, N_NODES);
}

// Round 13
// 182.141 us; speedup vs baseline: 1.1853x; 1.0181x over previous
//
#include <hip/hip_runtime.h>
#include <hip/hip_bf16.h>
#include <math.h>

#define N_NODES 50000
#define N_EDGES 800000
#define F_IN 256
#define HID 32
#define HEADS 4
#define HC 128            // HID*HEADS
#define CLASSES 40
#define LAYERS 2
#define SLOPE 0.1f
#define EE (N_EDGES + N_NODES)   // edges + self loops

#define BSHIFT 9
#define NBUCK 98          // ceil(50000 / 512)
#define CHUNK 4096        // edges per block in bucket passes
#define NBLK_E ((EE + CHUNK - 1) / CHUNK)

typedef unsigned short ushortT;
typedef unsigned int uintT;
typedef __attribute__((ext_vector_type(8))) short short8v;   // 8 bf16 = 4 VGPRs
typedef __attribute__((ext_vector_type(4))) float f32x4;

__device__ __forceinline__ ushortT f2bu(float f) {
    __hip_bfloat16 h = __float2bfloat16(f);
    ushortT u; __builtin_memcpy(&u, &h, 2); return u;
}

// in-block exclusive prefix of bcnt[0..NBUCK-1] -> sbase[0..NBUCK] (wave 0 only)
__device__ __forceinline__ void scan_buckets(const int* __restrict__ bcnt,
                                             int* sbase, int t) {
    if (t < 64) {
        int i0 = 2 * t, i1 = 2 * t + 1;
        int v0 = (i0 < NBUCK) ? bcnt[i0] : 0;
        int v1 = (i1 < NBUCK) ? bcnt[i1] : 0;
        int s = v0 + v1;
        int x = s;
#pragma unroll
        for (int off = 1; off < 64; off <<= 1) {
            int y = __shfl_up(x, off);
            if (t >= off) x += y;
        }
        int excl = x - s;
        if (i0 <= NBUCK) sbase[i0] = excl;
        if (i1 <= NBUCK) sbase[i1] = excl + v0;
    }
    __syncthreads();
}

// ---------- weights + bcnt/gcur0 zero + rowptr[N]=EE, one kernel ----------
__global__ void wconv_all(const float* __restrict__ w_in, const float* __restrict__ Ws,
                          const float* __restrict__ w_out, ushortT* __restrict__ w_inT,
                          ushortT* __restrict__ WsT, ushortT* __restrict__ woutT,
                          int* __restrict__ bcnt, int* __restrict__ gcur0,
                          int* __restrict__ rowptr) {
    int i = blockIdx.x * 256 + threadIdx.x;
    if (i < NBUCK) { bcnt[i] = 0; gcur0[i] = 0; }
    if (i == NBUCK) rowptr[N_NODES] = EE;
    if (i < 32768) {                       // w_in[256][128] -> w_inT[128][256]
        int r = i >> 7, c = i & 127;
        w_inT[(size_t)c * F_IN + r] = f2bu(w_in[i]);
    } else if (i < 65536) {                // Ws[2][128][128] -> WsT[2][128][128]^T
        int j = i - 32768;
        int l = j >> 14, jj = j & 16383;
        int r = jj >> 7, c = jj & 127;
        WsT[l * 16384 + c * 128 + r] = f2bu(Ws[j]);
    } else if (i < 65536 + 6144) {         // w_out[128][40] -> woutT[48][128], pad 0
        int j = i - 65536;
        int c = j >> 7, k = j & 127;
        woutT[j] = (c < CLASSES) ? f2bu(w_out[k * CLASSES + c]) : (ushortT)0;
    }
}

// ---------- MFMA bf16 GEMM, N fixed 128, optional fused attention-dot epilogue ----------
#define AS_LD 40
template<bool AF32>
__global__ __launch_bounds__(256) void gemm_mfma(const void* __restrict__ Aptr,
                                                 const ushortT* __restrict__ BT,
                                                 ushortT* __restrict__ Cb,
                                                 const float* __restrict__ att,  // may be null
                                                 float* __restrict__ asrc,
                                                 float* __restrict__ adst,
                                                 int M, int K) {
    __shared__ ushortT As[64 * AS_LD];    // [row][k<32]
    __shared__ ushortT Bs[128 * AS_LD];   // [col][k<32]
    int t = threadIdx.x;
    int w = t >> 6, lane = t & 63;
    int row0 = blockIdx.x * 64;
    int ar = t >> 2, ak = (t & 3) * 8;
    int bcol = t >> 1, bks = (t & 1) * 16;
    int wr = w * 16;
    int arow = wr + (lane & 15);
    int ak8 = (lane >> 4) * 8;
    f32x4 acc[8] = {};

    for (int k0 = 0; k0 < K; k0 += 32) {
        int grow = row0 + ar;
        if (AF32) {
            const float* A = (const float*)Aptr;
            float4 v0 = make_float4(0.f, 0.f, 0.f, 0.f), v1 = v0;
            if (grow < M) {
                const float* ap = A + (size_t)grow * K + k0 + ak;
                v0 = *(const float4*)ap;
                v1 = *(const float4*)(ap + 4);
            }
            uint4 p;
            p.x = (uintT)f2bu(v0.x) | ((uintT)f2bu(v0.y) << 16);
            p.y = (uintT)f2bu(v0.z) | ((uintT)f2bu(v0.w) << 16);
            p.z = (uintT)f2bu(v1.x) | ((uintT)f2bu(v1.y) << 16);
            p.w = (uintT)f2bu(v1.z) | ((uintT)f2bu(v1.w) << 16);
            *(uint4*)&As[ar * AS_LD + ak] = p;
        } else {
            const ushortT* A = (const ushortT*)Aptr;
            uint4 p = make_uint4(0, 0, 0, 0);
            if (grow < M) p = *(const uint4*)(A + (size_t)grow * K + k0 + ak);
            *(uint4*)&As[ar * AS_LD + ak] = p;
        }
        {
            const ushortT* bp = BT + (size_t)bcol * K + k0 + bks;
            *(uint4*)&Bs[bcol * AS_LD + bks]     = *(const uint4*)bp;
            *(uint4*)&Bs[bcol * AS_LD + bks + 8] = *(const uint4*)(bp + 8);
        }
        __syncthreads();
        short8v a = *(short8v*)&As[arow * AS_LD + ak8];
#pragma unroll
        for (int c = 0; c < 8; ++c) {
            short8v b = *(short8v*)&Bs[(c * 16 + (lane & 15)) * AS_LD + ak8];
            acc[c] = __builtin_amdgcn_mfma_f32_16x16x32_bf16(a, b, acc[c], 0, 0, 0);
        }
        __syncthreads();
    }
    int cl = lane & 15;
    int r0 = row0 + wr + ((lane >> 4) << 2);
#pragma unroll
    for (int c = 0; c < 8; ++c) {
        int cc = c * 16 + cl;
#pragma unroll
        for (int r = 0; r < 4; ++r) {
            int rr = r0 + r;
            if (rr < M) Cb[(size_t)rr * 128 + cc] = f2bu(acc[c][r]);
        }
    }
    // fused attention dots: asrc/adst[row][h] = dot(hp_row[h*32..], att[h][..])
    if (att) {
#pragma unroll
        for (int h = 0; h < HEADS; ++h) {
            float as0 = att[h * 64 + cl];
            float as1 = att[h * 64 + 16 + cl];
            float ad0 = att[h * 64 + 32 + cl];
            float ad1 = att[h * 64 + 48 + cl];
#pragma unroll
            for (int r = 0; r < 4; ++r) {
                float ps = acc[2 * h][r] * as0 + acc[2 * h + 1][r] * as1;
                float pd = acc[2 * h][r] * ad0 + acc[2 * h + 1][r] * ad1;
#pragma unroll
                for (int off = 1; off < 16; off <<= 1) {
                    ps += __shfl_xor(ps, off);
                    pd += __shfl_xor(pd, off);
                }
                int rr = r0 + r;
                if (cl == 0 && rr < M) {
                    asrc[rr * 4 + h] = ps;
                    adst[rr * 4 + h] = pd;
                }
            }
        }
    }
}

// ---------- fused MFMA classifier + in-register log_softmax ----------
__global__ __launch_bounds__(256) void cls_mfma(const ushortT* __restrict__ A,
                                                const ushortT* __restrict__ BT,
                                                float* __restrict__ out, int M) {
    __shared__ ushortT As[64 * AS_LD];
    __shared__ ushortT Bs[48 * AS_LD];
    int t = threadIdx.x;
    int w = t >> 6, lane = t & 63;
    int row0 = blockIdx.x * 64;
    int ar = t >> 2, ak = (t & 3) * 8;
    int wr = w * 16;
    int arow = wr + (lane & 15);
    int ak8 = (lane >> 4) * 8;
    f32x4 acc[3] = {};

    for (int k0 = 0; k0 < 128; k0 += 32) {
        int grow = row0 + ar;
        uint4 p = make_uint4(0, 0, 0, 0);
        if (grow < M) p = *(const uint4*)(A + (size_t)grow * 128 + k0 + ak);
        *(uint4*)&As[ar * AS_LD + ak] = p;
        if (t < 96) {
            int bcol = t >> 1, bks = (t & 1) * 16;
            const ushortT* bp = BT + bcol * 128 + k0 + bks;
            *(uint4*)&Bs[bcol * AS_LD + bks]     = *(const uint4*)bp;
            *(uint4*)&Bs[bcol * AS_LD + bks + 8] = *(const uint4*)(bp + 8);
        }
        __syncthreads();
        short8v a = *(short8v*)&As[arow * AS_LD + ak8];
#pragma unroll
        for (int c = 0; c < 3; ++c) {
            short8v b = *(short8v*)&Bs[(c * 16 + (lane & 15)) * AS_LD + ak8];
            acc[c] = __builtin_amdgcn_mfma_f32_16x16x32_bf16(a, b, acc[c], 0, 0, 0);
        }
        __syncthreads();
    }
    int cl = lane & 15;
    int r0 = row0 + wr + ((lane >> 4) << 2);
#pragma unroll
    for (int r = 0; r < 4; ++r) {
        float v0 = acc[0][r], v1 = acc[1][r];
        float v2 = (cl < 8) ? acc[2][r] : -1e30f;
        float m = fmaxf(fmaxf(v0, v1), v2);
#pragma unroll
        for (int off = 1; off < 16; off <<= 1) m = fmaxf(m, __shfl_xor(m, off));
        float e = __expf(v0 - m) + __expf(v1 - m) + ((cl < 8) ? __expf(v2 - m) : 0.f);
#pragma unroll
        for (int off = 1; off < 16; off <<= 1) e += __shfl_xor(e, off);
        float ls = m + __logf(e);
        int rr = r0 + r;
        if (rr < M) {
            float* o = out + (size_t)rr * CLASSES;
            o[cl] = v0 - ls;
            o[16 + cl] = v1 - ls;
            if (cl < 8) o[32 + cl] = v2 - ls;
        }
    }
}

// ---------- CSR build via two-level bucket sort (no serial scan kernel) ----------
__global__ __launch_bounds__(256) void bucket_count(const int* __restrict__ ei,
                                                    int* __restrict__ bcnt) {
    __shared__ int hist[NBUCK];
    int t = threadIdx.x;
    if (t < NBUCK) hist[t] = 0;
    __syncthreads();
    int base = blockIdx.x * CHUNK;
    int end = min(base + CHUNK, EE);
    for (int i = base + t; i < end; i += 256) {
        int d = (i < N_EDGES) ? ei[N_EDGES + i] : (i - N_EDGES);
        atomicAdd(&hist[d >> BSHIFT], 1);
    }
    __syncthreads();
    if (t < NBUCK && hist[t]) atomicAdd(&bcnt[t], hist[t]);
}

__global__ __launch_bounds__(256) void bucket_scatter(const int* __restrict__ ei,
                                                      const int* __restrict__ bcnt,
                                                      int* __restrict__ gcur0,
                                                      uintT* __restrict__ ebuf) {
    __shared__ int sbase[NBUCK + 2];
    __shared__ int hist[NBUCK];
    __shared__ int rbase[NBUCK];
    int t = threadIdx.x;
    scan_buckets(bcnt, sbase, t);          // sbase[b] = bucket base offset
    if (t < NBUCK) hist[t] = 0;
    __syncthreads();
    int base = blockIdx.x * CHUNK;
    int end = min(base + CHUNK, EE);
    for (int i = base + t; i < end; i += 256) {
        int d = (i < N_EDGES) ? ei[N_EDGES + i] : (i - N_EDGES);
        atomicAdd(&hist[d >> BSHIFT], 1);
    }
    __syncthreads();
    if (t < NBUCK) {
        int c = hist[t];
        rbase[t] = c ? (sbase[t] + atomicAdd(&gcur0[t], c)) : 0;
    }
    __syncthreads();
    if (t < NBUCK) hist[t] = 0;
    __syncthreads();
    for (int i = base + t; i < end; i += 256) {
        int s, d;
        if (i < N_EDGES) { s = ei[i]; d = ei[N_EDGES + i]; } else { s = d = i - N_EDGES; }
        int b = d >> BSHIFT;
        int pos = rbase[b] + atomicAdd(&hist[b], 1);
        ebuf[pos] = ((uintT)s << BSHIFT) | (uintT)(d & 511);   // src(16b) | local dst(9b)
    }
}

__global__ __launch_bounds__(256) void csr_local(const uintT* __restrict__ ebuf,
                                                 const int* __restrict__ bcnt,
                                                 int* __restrict__ rowptr,
                                                 int* __restrict__ ssrc) {
    __shared__ int sbase[NBUCK + 2];
    __shared__ int cnt[512];
    __shared__ int cur[512];
    __shared__ int wsum[4];
    int b = blockIdx.x;
    int t = threadIdx.x;
    scan_buckets(bcnt, sbase, t);
    int node0 = b << BSHIFT;
    int nb = min(512, N_NODES - node0);
    int beg = sbase[b], end = sbase[b + 1];
    cnt[t] = 0; cnt[t + 256] = 0;
    __syncthreads();
    for (int i = beg + t; i < end; i += 256)
        atomicAdd(&cnt[ebuf[i] & 511], 1);
    __syncthreads();
    int v0 = cnt[2 * t], v1 = cnt[2 * t + 1];
    int s = v0 + v1;
    int lane = t & 63, w = t >> 6;
    int x = s;
#pragma unroll
    for (int off = 1; off < 64; off <<= 1) { int y = __shfl_up(x, off); if (lane >= off) x += y; }
    if (lane == 63) wsum[w] = x;
    __syncthreads();
    if (t == 0) { int run = 0; for (int k = 0; k < 4; ++k) { int tmp = wsum[k]; wsum[k] = run; run += tmp; } }
    __syncthreads();
    int excl = wsum[w] + x - s;
    cnt[2 * t] = excl; cnt[2 * t + 1] = excl + v0;
    cur[2 * t] = excl; cur[2 * t + 1] = excl + v0;
    if (2 * t < nb)     rowptr[node0 + 2 * t]     = beg + excl;
    if (2 * t + 1 < nb) rowptr[node0 + 2 * t + 1] = beg + excl + v0;
    __syncthreads();
    for (int i = beg + t; i < end; i += 256) {
        uintT e = ebuf[i];
        int pos = beg + atomicAdd(&cur[e & 511], 1);
        ssrc[pos] = (int)(e >> BSHIFT);
    }
}

// ---------- GAT aggregate ----------
__device__ __forceinline__ float lrelu(float v) { return v > 0.f ? v : SLOPE * v; }

// single-node path (R10-proven): full wave on one node
__device__ __forceinline__ void gat_one(
    int node, int beg, int deg, int lane,
    const int* __restrict__ ssrc, const float* __restrict__ asrc,
    const float* __restrict__ adst, const ushortT* __restrict__ hpb,
    const float* __restrict__ bias, ushortT* __restrict__ foutB,
    float* sexp, int* ssrcl, float* sm)
{
    float4 ad = *(const float4*)(adst + (size_t)node * 4);
    int g = lane >> 4, i0 = lane & 15;
    float acc0 = 0.f, acc1 = 0.f;
    float zinv;
    const ushortT* hrow = hpb + lane * 2;

    if (deg <= 64) {
        float4 lg = make_float4(-1e30f, -1e30f, -1e30f, -1e30f);
        int soff = 0;
        if (lane < deg) {
            int s = ssrc[beg + lane];
            float4 a = *(const float4*)(asrc + (size_t)s * 4);
            lg.x = lrelu(a.x + ad.x);
            lg.y = lrelu(a.y + ad.y);
            lg.z = lrelu(a.z + ad.z);
            lg.w = lrelu(a.w + ad.w);
            soff = s * HC;
        }
        ssrcl[lane] = soff;
        *(float4*)&sexp[lane * 4] = lg;
        asm volatile("s_waitcnt lgkmcnt(0)" ::: "memory");
        float mg =     sexp[i0 * 4 + g];
        mg = fmaxf(mg, sexp[(i0 + 16) * 4 + g]);
        mg = fmaxf(mg, sexp[(i0 + 32) * 4 + g]);
        mg = fmaxf(mg, sexp[(i0 + 48) * 4 + g]);
#pragma unroll
        for (int off = 1; off < 16; off <<= 1) mg = fmaxf(mg, __shfl_xor(mg, off));
        if (i0 == 0) sm[g] = mg;
        asm volatile("s_waitcnt lgkmcnt(0)" ::: "memory");
        float4 m = *(float4*)&sm[0];
        float4 ex;
        ex.x = __expf(lg.x - m.x);
        ex.y = __expf(lg.y - m.y);
        ex.z = __expf(lg.z - m.z);
        ex.w = __expf(lg.w - m.w);
        *(float4*)&sexp[lane * 4] = ex;
        asm volatile("s_waitcnt lgkmcnt(0)" ::: "memory");
        float zg = sexp[i0 * 4 + g];
        zg +=      sexp[(i0 + 16) * 4 + g];
        zg +=      sexp[(i0 + 32) * 4 + g];
        zg +=      sexp[(i0 + 48) * 4 + g];
#pragma unroll
        for (int off = 1; off < 16; off <<= 1) zg += __shfl_xor(zg, off);
        zinv = 1.f / zg;
#pragma unroll 4
        for (int i = 0; i < deg; ++i) {
            float e = sexp[i * 4 + g];
            int off = ssrcl[i];
            uintT u = *(const uintT*)(hrow + off);
            acc0 = fmaf(__uint_as_float(u << 16),         e, acc0);
            acc1 = fmaf(__uint_as_float(u & 0xffff0000u), e, acc1);
        }
    } else {
        float4 m = make_float4(-1e30f, -1e30f, -1e30f, -1e30f);
        for (int i = lane; i < deg; i += 64) {
            int s = ssrc[beg + i];
            float4 a = *(const float4*)(asrc + (size_t)s * 4);
            m.x = fmaxf(m.x, lrelu(a.x + ad.x));
            m.y = fmaxf(m.y, lrelu(a.y + ad.y));
            m.z = fmaxf(m.z, lrelu(a.z + ad.z));
            m.w = fmaxf(m.w, lrelu(a.w + ad.w));
        }
#pragma unroll
        for (int off = 1; off < 64; off <<= 1) {
            m.x = fmaxf(m.x, __shfl_xor(m.x, off));
            m.y = fmaxf(m.y, __shfl_xor(m.y, off));
            m.z = fmaxf(m.z, __shfl_xor(m.z, off));
            m.w = fmaxf(m.w, __shfl_xor(m.w, off));
        }
        float4 zp = make_float4(0.f, 0.f, 0.f, 0.f);
        for (int c0 = 0; c0 < deg; c0 += 64) {
            int n_ch = min(64, deg - c0);
            if (lane < n_ch) {
                int s = ssrc[beg + c0 + lane];
                float4 a = *(const float4*)(asrc + (size_t)s * 4);
                float4 ex;
                ex.x = __expf(lrelu(a.x + ad.x) - m.x);
                ex.y = __expf(lrelu(a.y + ad.y) - m.y);
                ex.z = __expf(lrelu(a.z + ad.z) - m.z);
                ex.w = __expf(lrelu(a.w + ad.w) - m.w);
                *(float4*)&sexp[lane * 4] = ex;
                ssrcl[lane] = s * HC;
                zp.x += ex.x; zp.y += ex.y; zp.z += ex.z; zp.w += ex.w;
            }
            asm volatile("s_waitcnt lgkmcnt(0)" ::: "memory");
#pragma unroll 4
            for (int i = 0; i < n_ch; ++i) {
                float e = sexp[i * 4 + g];
                int off = ssrcl[i];
                uintT u = *(const uintT*)(hrow + off);
                acc0 = fmaf(__uint_as_float(u << 16),         e, acc0);
                acc1 = fmaf(__uint_as_float(u & 0xffff0000u), e, acc1);
            }
        }
#pragma unroll
        for (int off = 1; off < 64; off <<= 1) {
            zp.x += __shfl_xor(zp.x, off);
            zp.y += __shfl_xor(zp.y, off);
            zp.z += __shfl_xor(zp.z, off);
            zp.w += __shfl_xor(zp.w, off);
        }
        float zh = (g == 0) ? zp.x : (g == 1) ? zp.y : (g == 2) ? zp.z : zp.w;
        zinv = 1.f / zh;
    }

    float b0 = bias[lane * 2], b1 = bias[lane * 2 + 1];
    float v0 = acc0 * zinv + b0; v0 = v0 > 0.f ? v0 : __expf(v0) - 1.f;
    float v1 = acc1 * zinv + b1; v1 = v1 > 0.f ? v1 : __expf(v1) - 1.f;
    *(uintT*)(foutB + (size_t)node * HC + lane * 2) =
        (uintT)f2bu(v0) | ((uintT)f2bu(v1) << 16);
}

// paired kernel: each wave serves 2 consecutive nodes (deg<=32 each, 99.96% of pairs)
#define WPB 4   // waves per block
__global__ __launch_bounds__(256) void gat_gather2(
    const int* __restrict__ rowptr, const int* __restrict__ ssrc,
    const float* __restrict__ asrc, const float* __restrict__ adst,
    const ushortT* __restrict__ hpb, const float* __restrict__ bias,
    ushortT* __restrict__ foutB)
{
    __shared__ __align__(16) float s_exp[WPB][64][4];
    __shared__ int   s_src[WPB][64];
    __shared__ __align__(16) float s_m[WPB][8];
    __shared__ __align__(16) float s_z[WPB][8];
    int w = threadIdx.x >> 6;
    int lane = threadIdx.x & 63;
    int widx = blockIdx.x * WPB + w;
    int n0 = widx * 2;
    if (n0 >= N_NODES) return;
    int beg0 = rowptr[n0];
    int mid  = rowptr[n0 + 1];
    int end1 = rowptr[n0 + 2];
    int deg0 = mid - beg0, deg1 = end1 - mid;

    if (deg0 <= 32 && deg1 <= 32) {
        int half = lane >> 5;        // which node this lane serves
        int ll = lane & 31;
        int nn = n0 + half;
        int mybeg = half ? mid : beg0;
        int mydeg = half ? deg1 : deg0;
        float4 ad = *(const float4*)(adst + (size_t)nn * 4);
        // ---- edge logits (slot ll = edge index) ----
        float4 lg = make_float4(-1e30f, -1e30f, -1e30f, -1e30f);
        int soff = 0;
        if (ll < mydeg) {
            int s = ssrc[mybeg + ll];
            float4 a = *(const float4*)(asrc + (size_t)s * 4);
            lg.x = lrelu(a.x + ad.x);
            lg.y = lrelu(a.y + ad.y);
            lg.z = lrelu(a.z + ad.z);
            lg.w = lrelu(a.w + ad.w);
            soff = s * HC;
        }
        s_src[w][lane] = soff;
        *(float4*)&s_exp[w][lane][0] = lg;
        asm volatile("s_waitcnt lgkmcnt(0)" ::: "memory");
        // ---- 8-group transpose max: grp = (node,head), 8 lanes each ----
        int grp = lane >> 3, gi = lane & 7;
        int gbase = (grp >> 2) << 5;   // 0 or 32
        int gh = grp & 3;
        float mg =     s_exp[w][gbase + gi][gh];
        mg = fmaxf(mg, s_exp[w][gbase + gi +  8][gh]);
        mg = fmaxf(mg, s_exp[w][gbase + gi + 16][gh]);
        mg = fmaxf(mg, s_exp[w][gbase + gi + 24][gh]);
        mg = fmaxf(mg, __shfl_xor(mg, 1));
        mg = fmaxf(mg, __shfl_xor(mg, 2));
        mg = fmaxf(mg, __shfl_xor(mg, 4));
        if (gi == 0) s_m[w][grp] = mg;
        asm volatile("s_waitcnt lgkmcnt(0)" ::: "memory");
        float4 m = *(float4*)&s_m[w][half * 4];
        float4 ex;
        ex.x = __expf(lg.x - m.x);   // pad slots: lg=-1e30 -> 0
        ex.y = __expf(lg.y - m.y);
        ex.z = __expf(lg.z - m.z);
        ex.w = __expf(lg.w - m.w);
        *(float4*)&s_exp[w][lane][0] = ex;
        asm volatile("s_waitcnt lgkmcnt(0)" ::: "memory");
        // ---- 8-group transpose sum for z ----
        float zg = s_exp[w][gbase + gi][gh];
        zg +=      s_exp[w][gbase + gi +  8][gh];
        zg +=      s_exp[w][gbase + gi + 16][gh];
        zg +=      s_exp[w][gbase + gi + 24][gh];
        zg += __shfl_xor(zg, 1);
        zg += __shfl_xor(zg, 2);
        zg += __shfl_xor(zg, 4);
        if (gi == 0) s_z[w][grp] = zg;
        asm volatile("s_waitcnt lgkmcnt(0)" ::: "memory");
        int hd = ll >> 3;            // head of this lane's 4 channels
        float zinv = 1.f / s_z[w][half * 4 + hd];
        // ---- gather: lane owns channels ll*4..+3 of its node; pad edges have e=0 ----
        int maxdeg = max(deg0, deg1);
        int ebase = half << 5;
        const ushortT* hrow = hpb + ll * 4;
        float a0 = 0.f, a1 = 0.f, a2 = 0.f, a3 = 0.f;
#pragma unroll 4
        for (int i = 0; i < maxdeg; ++i) {
            float e = s_exp[w][ebase + i][hd];
            int off = s_src[w][ebase + i];
            uint2 u = *(const uint2*)(hrow + off);
            a0 = fmaf(__uint_as_float(u.x << 16),         e, a0);
            a1 = fmaf(__uint_as_float(u.x & 0xffff0000u), e, a1);
            a2 = fmaf(__uint_as_float(u.y << 16),         e, a2);
            a3 = fmaf(__uint_as_float(u.y & 0xffff0000u), e, a3);
        }
        // ---- normalize + bias + ELU + store (no cross-lane reduce needed) ----
        const float* bp = bias + ll * 4;
        float v0 = a0 * zinv + bp[0]; v0 = v0 > 0.f ? v0 : __expf(v0) - 1.f;
        float v1 = a1 * zinv + bp[1]; v1 = v1 > 0.f ? v1 : __expf(v1) - 1.f;
        float v2 = a2 * zinv + bp[2]; v2 = v2 > 0.f ? v2 : __expf(v2) - 1.f;
        float v3 = a3 * zinv + bp[3]; v3 = v3 > 0.f ? v3 : __expf(v3) - 1.f;
        uint2 o;
        o.x = (uintT)f2bu(v0) | ((uintT)f2bu(v1) << 16);
        o.y = (uintT)f2bu(v2) | ((uintT)f2bu(v3) << 16);
        *(uint2*)(foutB + (size_t)nn * HC + ll * 4) = o;
    } else {
        // rare: run the proven single-node path for each node sequentially
        gat_one(n0,     beg0, deg0, lane, ssrc, asrc, adst, hpb, bias, foutB,
                &s_exp[w][0][0], &s_src[w][0], &s_m[w][0]);
        gat_one(n0 + 1, mid,  deg1, lane, ssrc, asrc, adst, hpb, bias, foutB,
                &s_exp[w][0][0], &s_src[w][0], &s_m[w][0]);
    }
}

extern "C" void kernel_launch(void* const* d_in, const int* in_sizes, int n_in,
                              void* d_out, int out_size, void* d_ws, size_t ws_size,
                              hipStream_t stream) {
    const float* x      = (const float*)d_in[0];
    const int*   ei     = (const int*)d_in[1];
    const float* w_in   = (const float*)d_in[2];
    const float* Ws     = (const float*)d_in[3];
    const float* atts   = (const float*)d_in[4];
    const float* biases = (const float*)d_in[5];
    const float* w_out  = (const float*)d_in[6];
    float* out = (float*)d_out;

    // workspace partition
    char* wp = (char*)d_ws;
    ushortT* hb0 = (ushortT*)wp; wp += (size_t)N_NODES * HC * 2;   // bf16 h / final gat out
    ushortT* hb1 = (ushortT*)wp; wp += (size_t)N_NODES * HC * 2;   // bf16 gat_l0 out
    ushortT* hpb = (ushortT*)wp; wp += (size_t)N_NODES * HC * 2;   // bf16 hp
    float* asrc  = (float*)wp;   wp += (size_t)N_NODES * HEADS * 4;
    float* adst  = (float*)wp;   wp += (size_t)N_NODES * HEADS * 4;
    int* rowptr  = (int*)wp;     wp += (size_t)(N_NODES + 4) * 4;
    int* ssrc    = (int*)wp;     wp += (size_t)EE * 4;
    uintT* ebuf  = (uintT*)wp;   wp += (size_t)EE * 4;
    int* bcnt    = (int*)wp;     wp += (size_t)(NBUCK + 4) * 4;
    int* gcur0   = (int*)wp;     wp += (size_t)(NBUCK + 4) * 4;
    ushortT* w_inT = (ushortT*)wp; wp += (size_t)HC * F_IN * 2;
    ushortT* WsT   = (ushortT*)wp; wp += (size_t)LAYERS * HC * HC * 2;
    ushortT* woutT = (ushortT*)wp; wp += (size_t)48 * HC * 2;

    // ---- prep: weights + bcnt/gcur0 zero + rowptr[N]=EE ----
    wconv_all<<<(32768 + 32768 + 6144 + 255) / 256, 256, 0, stream>>>(
        w_in, Ws, w_out, w_inT, WsT, woutT, bcnt, gcur0, rowptr);

    // ---- CSR build: two-level bucket sort (scan computed in-block) ----
    bucket_count<<<NBLK_E, 256, 0, stream>>>(ei, bcnt);
    bucket_scatter<<<NBLK_E, 256, 0, stream>>>(ei, bcnt, gcur0, ebuf);
    csr_local<<<NBUCK, 256, 0, stream>>>(ebuf, bcnt, rowptr, ssrc);

    int gblk = (N_NODES + 63) / 64;
    // h = x @ w_in  -> bf16 only
    gemm_mfma<true><<<gblk, 256, 0, stream>>>(x, w_inT, hb0, nullptr, nullptr, nullptr,
                                              N_NODES, F_IN);

    const ushortT* hin_b = hb0;
    ushortT* gout[LAYERS] = { hb1, hb0 };
    int g2blk = (N_NODES / 2 + WPB - 1) / WPB;
    for (int l = 0; l < LAYERS; ++l) {
        gemm_mfma<false><<<gblk, 256, 0, stream>>>(hin_b, WsT + (size_t)l * HC * HC, hpb,
                                                   atts + (size_t)l * HEADS * 2 * HID,
                                                   asrc, adst, N_NODES, HC);
        gat_gather2<<<g2blk, 64 * WPB, 0, stream>>>(
            rowptr, ssrc, asrc, adst, hpb, biases + (size_t)l * HC, gout[l]);
        hin_b = gout[l];
    }

    cls_mfma<<<gblk, 256, 0, stream>>>(hb0, woutT, out, N_NODES);
}

// Round 14
// 165.879 us; speedup vs baseline: 1.3015x; 1.0980x over previous
//
#include <hip/hip_runtime.h>
#include <hip/hip_bf16.h>
#include <math.h>

#define N_NODES 50000
#define N_EDGES 800000
#define F_IN 256
#define HID 32
#define HEADS 4
#define HC 128            // HID*HEADS
#define CLASSES 40
#define LAYERS 2
#define SLOPE 0.1f
#define EE (N_EDGES + N_NODES)   // edges + self loops

#define BSHIFT 9
#define NBUCK 98          // ceil(50000 / 512)
#define CHUNK 4096        // edges per block in bucket passes
#define NBLK_E ((EE + CHUNK - 1) / CHUNK)
#define GEMM_BLOCKS ((N_NODES + 63) / 64)   // 782

typedef unsigned short ushortT;
typedef unsigned int uintT;
typedef __attribute__((ext_vector_type(8))) short short8v;   // 8 bf16 = 4 VGPRs
typedef __attribute__((ext_vector_type(4))) float f32x4;

__device__ __forceinline__ ushortT f2bu(float f) {
    __hip_bfloat16 h = __float2bfloat16(f);
    ushortT u; __builtin_memcpy(&u, &h, 2); return u;
}

// in-block exclusive prefix of bcnt[0..NBUCK-1] -> sbase[0..NBUCK] (wave 0 only)
__device__ __forceinline__ void scan_buckets(const int* __restrict__ bcnt,
                                             int* sbase, int t) {
    if (t < 64) {
        int i0 = 2 * t, i1 = 2 * t + 1;
        int v0 = (i0 < NBUCK) ? bcnt[i0] : 0;
        int v1 = (i1 < NBUCK) ? bcnt[i1] : 0;
        int s = v0 + v1;
        int x = s;
#pragma unroll
        for (int off = 1; off < 64; off <<= 1) {
            int y = __shfl_up(x, off);
            if (t >= off) x += y;
        }
        int excl = x - s;
        if (i0 <= NBUCK) sbase[i0] = excl;
        if (i1 <= NBUCK) sbase[i1] = excl + v0;
    }
    __syncthreads();
}

// ---------- weights + bcnt/gcur0 zero + rowptr[N]=EE, one kernel ----------
__global__ void wconv_all(const float* __restrict__ w_in, const float* __restrict__ Ws,
                          const float* __restrict__ w_out, ushortT* __restrict__ w_inT,
                          ushortT* __restrict__ WsT, ushortT* __restrict__ woutT,
                          int* __restrict__ bcnt, int* __restrict__ gcur0,
                          int* __restrict__ rowptr) {
    int i = blockIdx.x * 256 + threadIdx.x;
    if (i < NBUCK) { bcnt[i] = 0; gcur0[i] = 0; }
    if (i == NBUCK) rowptr[N_NODES] = EE;
    if (i < 32768) {                       // w_in[256][128] -> w_inT[128][256]
        int r = i >> 7, c = i & 127;
        w_inT[(size_t)c * F_IN + r] = f2bu(w_in[i]);
    } else if (i < 65536) {                // Ws[2][128][128] -> WsT[2][128][128]^T
        int j = i - 32768;
        int l = j >> 14, jj = j & 16383;
        int r = jj >> 7, c = jj & 127;
        WsT[l * 16384 + c * 128 + r] = f2bu(Ws[j]);
    } else if (i < 65536 + 6144) {         // w_out[128][40] -> woutT[48][128], pad 0
        int j = i - 65536;
        int c = j >> 7, k = j & 127;
        woutT[j] = (c < CLASSES) ? f2bu(w_out[k * CLASSES + c]) : (ushortT)0;
    }
}

// ---------- MFMA bf16 GEMM body (device fn so it can be fused) ----------
#define AS_LD 40
template<bool AF32>
__device__ __forceinline__ void gemm_body(ushortT* As, ushortT* Bs,
                                          const void* __restrict__ Aptr,
                                          const ushortT* __restrict__ BT,
                                          ushortT* __restrict__ Cb,
                                          const float* __restrict__ att,
                                          float* __restrict__ asrc,
                                          float* __restrict__ adst,
                                          int M, int K, int bid) {
    int t = threadIdx.x;
    int w = t >> 6, lane = t & 63;
    int row0 = bid * 64;
    int ar = t >> 2, ak = (t & 3) * 8;
    int bcol = t >> 1, bks = (t & 1) * 16;
    int wr = w * 16;
    int arow = wr + (lane & 15);
    int ak8 = (lane >> 4) * 8;
    f32x4 acc[8] = {};

    for (int k0 = 0; k0 < K; k0 += 32) {
        int grow = row0 + ar;
        if (AF32) {
            const float* A = (const float*)Aptr;
            float4 v0 = make_float4(0.f, 0.f, 0.f, 0.f), v1 = v0;
            if (grow < M) {
                const float* ap = A + (size_t)grow * K + k0 + ak;
                v0 = *(const float4*)ap;
                v1 = *(const float4*)(ap + 4);
            }
            uint4 p;
            p.x = (uintT)f2bu(v0.x) | ((uintT)f2bu(v0.y) << 16);
            p.y = (uintT)f2bu(v0.z) | ((uintT)f2bu(v0.w) << 16);
            p.z = (uintT)f2bu(v1.x) | ((uintT)f2bu(v1.y) << 16);
            p.w = (uintT)f2bu(v1.z) | ((uintT)f2bu(v1.w) << 16);
            *(uint4*)&As[ar * AS_LD + ak] = p;
        } else {
            const ushortT* A = (const ushortT*)Aptr;
            uint4 p = make_uint4(0, 0, 0, 0);
            if (grow < M) p = *(const uint4*)(A + (size_t)grow * K + k0 + ak);
            *(uint4*)&As[ar * AS_LD + ak] = p;
        }
        {
            const ushortT* bp = BT + (size_t)bcol * K + k0 + bks;
            *(uint4*)&Bs[bcol * AS_LD + bks]     = *(const uint4*)bp;
            *(uint4*)&Bs[bcol * AS_LD + bks + 8] = *(const uint4*)(bp + 8);
        }
        __syncthreads();
        short8v a = *(short8v*)&As[arow * AS_LD + ak8];
#pragma unroll
        for (int c = 0; c < 8; ++c) {
            short8v b = *(short8v*)&Bs[(c * 16 + (lane & 15)) * AS_LD + ak8];
            acc[c] = __builtin_amdgcn_mfma_f32_16x16x32_bf16(a, b, acc[c], 0, 0, 0);
        }
        __syncthreads();
    }
    int cl = lane & 15;
    int r0 = row0 + wr + ((lane >> 4) << 2);
#pragma unroll
    for (int c = 0; c < 8; ++c) {
        int cc = c * 16 + cl;
#pragma unroll
        for (int r = 0; r < 4; ++r) {
            int rr = r0 + r;
            if (rr < M) Cb[(size_t)rr * 128 + cc] = f2bu(acc[c][r]);
        }
    }
    if (att) {
#pragma unroll
        for (int h = 0; h < HEADS; ++h) {
            float as0 = att[h * 64 + cl];
            float as1 = att[h * 64 + 16 + cl];
            float ad0 = att[h * 64 + 32 + cl];
            float ad1 = att[h * 64 + 48 + cl];
#pragma unroll
            for (int r = 0; r < 4; ++r) {
                float ps = acc[2 * h][r] * as0 + acc[2 * h + 1][r] * as1;
                float pd = acc[2 * h][r] * ad0 + acc[2 * h + 1][r] * ad1;
#pragma unroll
                for (int off = 1; off < 16; off <<= 1) {
                    ps += __shfl_xor(ps, off);
                    pd += __shfl_xor(pd, off);
                }
                int rr = r0 + r;
                if (cl == 0 && rr < M) {
                    asrc[rr * 4 + h] = ps;
                    adst[rr * 4 + h] = pd;
                }
            }
        }
    }
}

// standalone GEMM (layer 1)
template<bool AF32>
__global__ __launch_bounds__(256) void gemm_mfma(const void* __restrict__ Aptr,
                                                 const ushortT* __restrict__ BT,
                                                 ushortT* __restrict__ Cb,
                                                 const float* __restrict__ att,
                                                 float* __restrict__ asrc,
                                                 float* __restrict__ adst,
                                                 int M, int K) {
    __shared__ ushortT As[64 * AS_LD];
    __shared__ ushortT Bs[128 * AS_LD];
    gemm_body<AF32>(As, Bs, Aptr, BT, Cb, att, asrc, adst, M, K, blockIdx.x);
}

// ---------- csr_local body (device fn so it can be fused) ----------
__device__ __forceinline__ void csr_local_body(const uintT* __restrict__ ebuf,
                                               const int* __restrict__ bcnt,
                                               int* __restrict__ rowptr,
                                               int* __restrict__ ssrc, int b,
                                               int* sbase, int* cnt, int* cur,
                                               int* wsum) {
    int t = threadIdx.x;
    scan_buckets(bcnt, sbase, t);
    int node0 = b << BSHIFT;
    int nb = min(512, N_NODES - node0);
    int beg = sbase[b], end = sbase[b + 1];
    cnt[t] = 0; cnt[t + 256] = 0;
    __syncthreads();
    for (int i = beg + t; i < end; i += 256)
        atomicAdd(&cnt[ebuf[i] & 511], 1);
    __syncthreads();
    int v0 = cnt[2 * t], v1 = cnt[2 * t + 1];
    int s = v0 + v1;
    int lane = t & 63, w = t >> 6;
    int x = s;
#pragma unroll
    for (int off = 1; off < 64; off <<= 1) { int y = __shfl_up(x, off); if (lane >= off) x += y; }
    if (lane == 63) wsum[w] = x;
    __syncthreads();
    if (t == 0) { int run = 0; for (int k = 0; k < 4; ++k) { int tmp = wsum[k]; wsum[k] = run; run += tmp; } }
    __syncthreads();
    int excl = wsum[w] + x - s;
    cnt[2 * t] = excl; cnt[2 * t + 1] = excl + v0;
    cur[2 * t] = excl; cur[2 * t + 1] = excl + v0;
    if (2 * t < nb)     rowptr[node0 + 2 * t]     = beg + excl;
    if (2 * t + 1 < nb) rowptr[node0 + 2 * t + 1] = beg + excl + v0;
    __syncthreads();
    for (int i = beg + t; i < end; i += 256) {
        uintT e = ebuf[i];
        int pos = beg + atomicAdd(&cur[e & 511], 1);
        ssrc[pos] = (int)(e >> BSHIFT);
    }
}

// ---------- fused: gemm0 (x @ w_in) + bucket_count ----------
__global__ __launch_bounds__(256) void gemm0_count(const float* __restrict__ x,
                                                   const ushortT* __restrict__ w_inT,
                                                   ushortT* __restrict__ hb0,
                                                   const int* __restrict__ ei,
                                                   int* __restrict__ bcnt) {
    __shared__ ushortT As[64 * AS_LD];
    __shared__ ushortT Bs[128 * AS_LD];
    __shared__ int hist[NBUCK];
    if (blockIdx.x < GEMM_BLOCKS) {
        gemm_body<true>(As, Bs, x, w_inT, hb0, nullptr, nullptr, nullptr,
                        N_NODES, F_IN, blockIdx.x);
    } else {
        int t = threadIdx.x;
        if (t < NBUCK) hist[t] = 0;
        __syncthreads();
        int base = (blockIdx.x - GEMM_BLOCKS) * CHUNK;
        int end = min(base + CHUNK, EE);
        for (int i = base + t; i < end; i += 256) {
            int d = (i < N_EDGES) ? ei[N_EDGES + i] : (i - N_EDGES);
            atomicAdd(&hist[d >> BSHIFT], 1);
        }
        __syncthreads();
        if (t < NBUCK && hist[t]) atomicAdd(&bcnt[t], hist[t]);
    }
}

// ---------- fused: gemm layer-0 + csr_local ----------
__global__ __launch_bounds__(256) void gemm_csr(const ushortT* __restrict__ hin,
                                                const ushortT* __restrict__ BT,
                                                ushortT* __restrict__ hpb,
                                                const float* __restrict__ att,
                                                float* __restrict__ asrc,
                                                float* __restrict__ adst,
                                                const uintT* __restrict__ ebuf,
                                                const int* __restrict__ bcnt,
                                                int* __restrict__ rowptr,
                                                int* __restrict__ ssrc) {
    __shared__ ushortT As[64 * AS_LD];
    __shared__ ushortT Bs[128 * AS_LD];
    __shared__ int sbase[NBUCK + 2];
    __shared__ int cnt[512];
    __shared__ int cur[512];
    __shared__ int wsum[4];
    if (blockIdx.x < GEMM_BLOCKS) {
        gemm_body<false>(As, Bs, hin, BT, hpb, att, asrc, adst,
                         N_NODES, HC, blockIdx.x);
    } else {
        csr_local_body(ebuf, bcnt, rowptr, ssrc, blockIdx.x - GEMM_BLOCKS,
                       sbase, cnt, cur, wsum);
    }
}

// ---------- bucket_scatter (standalone: between count and csr_local) ----------
__global__ __launch_bounds__(256) void bucket_scatter(const int* __restrict__ ei,
                                                      const int* __restrict__ bcnt,
                                                      int* __restrict__ gcur0,
                                                      uintT* __restrict__ ebuf) {
    __shared__ int sbase[NBUCK + 2];
    __shared__ int hist[NBUCK];
    __shared__ int rbase[NBUCK];
    int t = threadIdx.x;
    scan_buckets(bcnt, sbase, t);          // sbase[b] = bucket base offset
    if (t < NBUCK) hist[t] = 0;
    __syncthreads();
    int base = blockIdx.x * CHUNK;
    int end = min(base + CHUNK, EE);
    for (int i = base + t; i < end; i += 256) {
        int d = (i < N_EDGES) ? ei[N_EDGES + i] : (i - N_EDGES);
        atomicAdd(&hist[d >> BSHIFT], 1);
    }
    __syncthreads();
    if (t < NBUCK) {
        int c = hist[t];
        rbase[t] = c ? (sbase[t] + atomicAdd(&gcur0[t], c)) : 0;
    }
    __syncthreads();
    if (t < NBUCK) hist[t] = 0;
    __syncthreads();
    for (int i = base + t; i < end; i += 256) {
        int s, d;
        if (i < N_EDGES) { s = ei[i]; d = ei[N_EDGES + i]; } else { s = d = i - N_EDGES; }
        int b = d >> BSHIFT;
        int pos = rbase[b] + atomicAdd(&hist[b], 1);
        ebuf[pos] = ((uintT)s << BSHIFT) | (uintT)(d & 511);   // src(16b) | local dst(9b)
    }
}

// ---------- fused MFMA classifier + in-register log_softmax ----------
__global__ __launch_bounds__(256) void cls_mfma(const ushortT* __restrict__ A,
                                                const ushortT* __restrict__ BT,
                                                float* __restrict__ out, int M) {
    __shared__ ushortT As[64 * AS_LD];
    __shared__ ushortT Bs[48 * AS_LD];
    int t = threadIdx.x;
    int w = t >> 6, lane = t & 63;
    int row0 = blockIdx.x * 64;
    int ar = t >> 2, ak = (t & 3) * 8;
    int wr = w * 16;
    int arow = wr + (lane & 15);
    int ak8 = (lane >> 4) * 8;
    f32x4 acc[3] = {};

    for (int k0 = 0; k0 < 128; k0 += 32) {
        int grow = row0 + ar;
        uint4 p = make_uint4(0, 0, 0, 0);
        if (grow < M) p = *(const uint4*)(A + (size_t)grow * 128 + k0 + ak);
        *(uint4*)&As[ar * AS_LD + ak] = p;
        if (t < 96) {
            int bcol = t >> 1, bks = (t & 1) * 16;
            const ushortT* bp = BT + bcol * 128 + k0 + bks;
            *(uint4*)&Bs[bcol * AS_LD + bks]     = *(const uint4*)bp;
            *(uint4*)&Bs[bcol * AS_LD + bks + 8] = *(const uint4*)(bp + 8);
        }
        __syncthreads();
        short8v a = *(short8v*)&As[arow * AS_LD + ak8];
#pragma unroll
        for (int c = 0; c < 3; ++c) {
            short8v b = *(short8v*)&Bs[(c * 16 + (lane & 15)) * AS_LD + ak8];
            acc[c] = __builtin_amdgcn_mfma_f32_16x16x32_bf16(a, b, acc[c], 0, 0, 0);
        }
        __syncthreads();
    }
    int cl = lane & 15;
    int r0 = row0 + wr + ((lane >> 4) << 2);
#pragma unroll
    for (int r = 0; r < 4; ++r) {
        float v0 = acc[0][r], v1 = acc[1][r];
        float v2 = (cl < 8) ? acc[2][r] : -1e30f;
        float m = fmaxf(fmaxf(v0, v1), v2);
#pragma unroll
        for (int off = 1; off < 16; off <<= 1) m = fmaxf(m, __shfl_xor(m, off));
        float e = __expf(v0 - m) + __expf(v1 - m) + ((cl < 8) ? __expf(v2 - m) : 0.f);
#pragma unroll
        for (int off = 1; off < 16; off <<= 1) e += __shfl_xor(e, off);
        float ls = m + __logf(e);
        int rr = r0 + r;
        if (rr < M) {
            float* o = out + (size_t)rr * CLASSES;
            o[cl] = v0 - ls;
            o[16 + cl] = v1 - ls;
            if (cl < 8) o[32 + cl] = v2 - ls;
        }
    }
}

// ---------- GAT aggregate ----------
__device__ __forceinline__ float lrelu(float v) { return v > 0.f ? v : SLOPE * v; }

// single-node path (R10-proven): full wave on one node
__device__ __forceinline__ void gat_one(
    int node, int beg, int deg, int lane,
    const int* __restrict__ ssrc, const float* __restrict__ asrc,
    const float* __restrict__ adst, const ushortT* __restrict__ hpb,
    const float* __restrict__ bias, ushortT* __restrict__ foutB,
    float* sexp, int* ssrcl, float* sm)
{
    float4 ad = *(const float4*)(adst + (size_t)node * 4);
    int g = lane >> 4, i0 = lane & 15;
    float acc0 = 0.f, acc1 = 0.f;
    float zinv;
    const ushortT* hrow = hpb + lane * 2;

    if (deg <= 64) {
        float4 lg = make_float4(-1e30f, -1e30f, -1e30f, -1e30f);
        int soff = 0;
        if (lane < deg) {
            int s = ssrc[beg + lane];
            float4 a = *(const float4*)(asrc + (size_t)s * 4);
            lg.x = lrelu(a.x + ad.x);
            lg.y = lrelu(a.y + ad.y);
            lg.z = lrelu(a.z + ad.z);
            lg.w = lrelu(a.w + ad.w);
            soff = s * HC;
        }
        ssrcl[lane] = soff;
        *(float4*)&sexp[lane * 4] = lg;
        asm volatile("s_waitcnt lgkmcnt(0)" ::: "memory");
        float mg =     sexp[i0 * 4 + g];
        mg = fmaxf(mg, sexp[(i0 + 16) * 4 + g]);
        mg = fmaxf(mg, sexp[(i0 + 32) * 4 + g]);
        mg = fmaxf(mg, sexp[(i0 + 48) * 4 + g]);
#pragma unroll
        for (int off = 1; off < 16; off <<= 1) mg = fmaxf(mg, __shfl_xor(mg, off));
        if (i0 == 0) sm[g] = mg;
        asm volatile("s_waitcnt lgkmcnt(0)" ::: "memory");
        float4 m = *(float4*)&sm[0];
        float4 ex;
        ex.x = __expf(lg.x - m.x);
        ex.y = __expf(lg.y - m.y);
        ex.z = __expf(lg.z - m.z);
        ex.w = __expf(lg.w - m.w);
        *(float4*)&sexp[lane * 4] = ex;
        asm volatile("s_waitcnt lgkmcnt(0)" ::: "memory");
        float zg = sexp[i0 * 4 + g];
        zg +=      sexp[(i0 + 16) * 4 + g];
        zg +=      sexp[(i0 + 32) * 4 + g];
        zg +=      sexp[(i0 + 48) * 4 + g];
#pragma unroll
        for (int off = 1; off < 16; off <<= 1) zg += __shfl_xor(zg, off);
        zinv = 1.f / zg;
#pragma unroll 4
        for (int i = 0; i < deg; ++i) {
            float e = sexp[i * 4 + g];
            int off = ssrcl[i];
            uintT u = *(const uintT*)(hrow + off);
            acc0 = fmaf(__uint_as_float(u << 16),         e, acc0);
            acc1 = fmaf(__uint_as_float(u & 0xffff0000u), e, acc1);
        }
    } else {
        float4 m = make_float4(-1e30f, -1e30f, -1e30f, -1e30f);
        for (int i = lane; i < deg; i += 64) {
            int s = ssrc[beg + i];
            float4 a = *(const float4*)(asrc + (size_t)s * 4);
            m.x = fmaxf(m.x, lrelu(a.x + ad.x));
            m.y = fmaxf(m.y, lrelu(a.y + ad.y));
            m.z = fmaxf(m.z, lrelu(a.z + ad.z));
            m.w = fmaxf(m.w, lrelu(a.w + ad.w));
        }
#pragma unroll
        for (int off = 1; off < 64; off <<= 1) {
            m.x = fmaxf(m.x, __shfl_xor(m.x, off));
            m.y = fmaxf(m.y, __shfl_xor(m.y, off));
            m.z = fmaxf(m.z, __shfl_xor(m.z, off));
            m.w = fmaxf(m.w, __shfl_xor(m.w, off));
        }
        float4 zp = make_float4(0.f, 0.f, 0.f, 0.f);
        for (int c0 = 0; c0 < deg; c0 += 64) {
            int n_ch = min(64, deg - c0);
            if (lane < n_ch) {
                int s = ssrc[beg + c0 + lane];
                float4 a = *(const float4*)(asrc + (size_t)s * 4);
                float4 ex;
                ex.x = __expf(lrelu(a.x + ad.x) - m.x);
                ex.y = __expf(lrelu(a.y + ad.y) - m.y);
                ex.z = __expf(lrelu(a.z + ad.z) - m.z);
                ex.w = __expf(lrelu(a.w + ad.w) - m.w);
                *(float4*)&sexp[lane * 4] = ex;
                ssrcl[lane] = s * HC;
                zp.x += ex.x; zp.y += ex.y; zp.z += ex.z; zp.w += ex.w;
            }
            asm volatile("s_waitcnt lgkmcnt(0)" ::: "memory");
#pragma unroll 4
            for (int i = 0; i < n_ch; ++i) {
                float e = sexp[i * 4 + g];
                int off = ssrcl[i];
                uintT u = *(const uintT*)(hrow + off);
                acc0 = fmaf(__uint_as_float(u << 16),         e, acc0);
                acc1 = fmaf(__uint_as_float(u & 0xffff0000u), e, acc1);
            }
        }
#pragma unroll
        for (int off = 1; off < 64; off <<= 1) {
            zp.x += __shfl_xor(zp.x, off);
            zp.y += __shfl_xor(zp.y, off);
            zp.z += __shfl_xor(zp.z, off);
            zp.w += __shfl_xor(zp.w, off);
        }
        float zh = (g == 0) ? zp.x : (g == 1) ? zp.y : (g == 2) ? zp.z : zp.w;
        zinv = 1.f / zh;
    }

    float b0 = bias[lane * 2], b1 = bias[lane * 2 + 1];
    float v0 = acc0 * zinv + b0; v0 = v0 > 0.f ? v0 : __expf(v0) - 1.f;
    float v1 = acc1 * zinv + b1; v1 = v1 > 0.f ? v1 : __expf(v1) - 1.f;
    *(uintT*)(foutB + (size_t)node * HC + lane * 2) =
        (uintT)f2bu(v0) | ((uintT)f2bu(v1) << 16);
}

// paired kernel: each wave serves 2 consecutive nodes (deg<=32 each, 99.96% of pairs)
#define WPB 4   // waves per block
__global__ __launch_bounds__(256) void gat_gather2(
    const int* __restrict__ rowptr, const int* __restrict__ ssrc,
    const float* __restrict__ asrc, const float* __restrict__ adst,
    const ushortT* __restrict__ hpb, const float* __restrict__ bias,
    ushortT* __restrict__ foutB)
{
    __shared__ __align__(16) float s_exp[WPB][64][4];
    __shared__ int   s_src[WPB][64];
    __shared__ __align__(16) float s_m[WPB][8];
    __shared__ __align__(16) float s_z[WPB][8];
    int w = threadIdx.x >> 6;
    int lane = threadIdx.x & 63;
    int widx = blockIdx.x * WPB + w;
    int n0 = widx * 2;
    if (n0 >= N_NODES) return;
    int beg0 = rowptr[n0];
    int mid  = rowptr[n0 + 1];
    int end1 = rowptr[n0 + 2];
    int deg0 = mid - beg0, deg1 = end1 - mid;

    if (deg0 <= 32 && deg1 <= 32) {
        int half = lane >> 5;        // which node this lane serves
        int ll = lane & 31;
        int nn = n0 + half;
        int mybeg = half ? mid : beg0;
        int mydeg = half ? deg1 : deg0;
        float4 ad = *(const float4*)(adst + (size_t)nn * 4);
        // ---- edge logits (slot ll = edge index) ----
        float4 lg = make_float4(-1e30f, -1e30f, -1e30f, -1e30f);
        int soff = 0;
        if (ll < mydeg) {
            int s = ssrc[mybeg + ll];
            float4 a = *(const float4*)(asrc + (size_t)s * 4);
            lg.x = lrelu(a.x + ad.x);
            lg.y = lrelu(a.y + ad.y);
            lg.z = lrelu(a.z + ad.z);
            lg.w = lrelu(a.w + ad.w);
            soff = s * HC;
        }
        s_src[w][lane] = soff;
        *(float4*)&s_exp[w][lane][0] = lg;
        asm volatile("s_waitcnt lgkmcnt(0)" ::: "memory");
        // ---- 8-group transpose max: grp = (node,head), 8 lanes each ----
        int grp = lane >> 3, gi = lane & 7;
        int gbase = (grp >> 2) << 5;   // 0 or 32
        int gh = grp & 3;
        float mg =     s_exp[w][gbase + gi][gh];
        mg = fmaxf(mg, s_exp[w][gbase + gi +  8][gh]);
        mg = fmaxf(mg, s_exp[w][gbase + gi + 16][gh]);
        mg = fmaxf(mg, s_exp[w][gbase + gi + 24][gh]);
        mg = fmaxf(mg, __shfl_xor(mg, 1));
        mg = fmaxf(mg, __shfl_xor(mg, 2));
        mg = fmaxf(mg, __shfl_xor(mg, 4));
        if (gi == 0) s_m[w][grp] = mg;
        asm volatile("s_waitcnt lgkmcnt(0)" ::: "memory");
        float4 m = *(float4*)&s_m[w][half * 4];
        float4 ex;
        ex.x = __expf(lg.x - m.x);   // pad slots: lg=-1e30 -> 0
        ex.y = __expf(lg.y - m.y);
        ex.z = __expf(lg.z - m.z);
        ex.w = __expf(lg.w - m.w);
        *(float4*)&s_exp[w][lane][0] = ex;
        asm volatile("s_waitcnt lgkmcnt(0)" ::: "memory");
        // ---- 8-group transpose sum for z ----
        float zg = s_exp[w][gbase + gi][gh];
        zg +=      s_exp[w][gbase + gi +  8][gh];
        zg +=      s_exp[w][gbase + gi + 16][gh];
        zg +=      s_exp[w][gbase + gi + 24][gh];
        zg += __shfl_xor(zg, 1);
        zg += __shfl_xor(zg, 2);
        zg += __shfl_xor(zg, 4);
        if (gi == 0) s_z[w][grp] = zg;
        asm volatile("s_waitcnt lgkmcnt(0)" ::: "memory");
        int hd = ll >> 3;            // head of this lane's 4 channels
        float zinv = 1.f / s_z[w][half * 4 + hd];
        // ---- gather: lane owns channels ll*4..+3 of its node; pad edges have e=0 ----
        int maxdeg = max(deg0, deg1);
        int ebase = half << 5;
        const ushortT* hrow = hpb + ll * 4;
        float a0 = 0.f, a1 = 0.f, a2 = 0.f, a3 = 0.f;
#pragma unroll 4
        for (int i = 0; i < maxdeg; ++i) {
            float e = s_exp[w][ebase + i][hd];
            int off = s_src[w][ebase + i];
            uint2 u = *(const uint2*)(hrow + off);
            a0 = fmaf(__uint_as_float(u.x << 16),         e, a0);
            a1 = fmaf(__uint_as_float(u.x & 0xffff0000u), e, a1);
            a2 = fmaf(__uint_as_float(u.y << 16),         e, a2);
            a3 = fmaf(__uint_as_float(u.y & 0xffff0000u), e, a3);
        }
        // ---- normalize + bias + ELU + store (no cross-lane reduce needed) ----
        const float* bp = bias + ll * 4;
        float v0 = a0 * zinv + bp[0]; v0 = v0 > 0.f ? v0 : __expf(v0) - 1.f;
        float v1 = a1 * zinv + bp[1]; v1 = v1 > 0.f ? v1 : __expf(v1) - 1.f;
        float v2 = a2 * zinv + bp[2]; v2 = v2 > 0.f ? v2 : __expf(v2) - 1.f;
        float v3 = a3 * zinv + bp[3]; v3 = v3 > 0.f ? v3 : __expf(v3) - 1.f;
        uint2 o;
        o.x = (uintT)f2bu(v0) | ((uintT)f2bu(v1) << 16);
        o.y = (uintT)f2bu(v2) | ((uintT)f2bu(v3) << 16);
        *(uint2*)(foutB + (size_t)nn * HC + ll * 4) = o;
    } else {
        // rare: run the proven single-node path for each node sequentially
        gat_one(n0,     beg0, deg0, lane, ssrc, asrc, adst, hpb, bias, foutB,
                &s_exp[w][0][0], &s_src[w][0], &s_m[w][0]);
        gat_one(n0 + 1, mid,  deg1, lane, ssrc, asrc, adst, hpb, bias, foutB,
                &s_exp[w][0][0], &s_src[w][0], &s_m[w][0]);
    }
}

extern "C" void kernel_launch(void* const* d_in, const int* in_sizes, int n_in,
                              void* d_out, int out_size, void* d_ws, size_t ws_size,
                              hipStream_t stream) {
    const float* x      = (const float*)d_in[0];
    const int*   ei     = (const int*)d_in[1];
    const float* w_in   = (const float*)d_in[2];
    const float* Ws     = (const float*)d_in[3];
    const float* atts   = (const float*)d_in[4];
    const float* biases = (const float*)d_in[5];
    const float* w_out  = (const float*)d_in[6];
    float* out = (float*)d_out;

    // workspace partition
    char* wp = (char*)d_ws;
    ushortT* hb0 = (ushortT*)wp; wp += (size_t)N_NODES * HC * 2;   // bf16 h / final gat out
    ushortT* hb1 = (ushortT*)wp; wp += (size_t)N_NODES * HC * 2;   // bf16 gat_l0 out
    ushortT* hpb = (ushortT*)wp; wp += (size_t)N_NODES * HC * 2;   // bf16 hp
    float* asrc  = (float*)wp;   wp += (size_t)N_NODES * HEADS * 4;
    float* adst  = (float*)wp;   wp += (size_t)N_NODES * HEADS * 4;
    int* rowptr  = (int*)wp;     wp += (size_t)(N_NODES + 4) * 4;
    int* ssrc    = (int*)wp;     wp += (size_t)EE * 4;
    uintT* ebuf  = (uintT*)wp;   wp += (size_t)EE * 4;
    int* bcnt    = (int*)wp;     wp += (size_t)(NBUCK + 4) * 4;
    int* gcur0   = (int*)wp;     wp += (size_t)(NBUCK + 4) * 4;
    ushortT* w_inT = (ushortT*)wp; wp += (size_t)HC * F_IN * 2;
    ushortT* WsT   = (ushortT*)wp; wp += (size_t)LAYERS * HC * HC * 2;
    ushortT* woutT = (ushortT*)wp; wp += (size_t)48 * HC * 2;

    // ---- prep: weights + bcnt/gcur0 zero + rowptr[N]=EE ----
    wconv_all<<<(32768 + 32768 + 6144 + 255) / 256, 256, 0, stream>>>(
        w_in, Ws, w_out, w_inT, WsT, woutT, bcnt, gcur0, rowptr);

    // ---- fused: gemm0 (x @ w_in -> hb0)  ∥  bucket_count ----
    gemm0_count<<<GEMM_BLOCKS + NBLK_E, 256, 0, stream>>>(x, w_inT, hb0, ei, bcnt);

    // ---- bucket_scatter (needs bcnt complete) ----
    bucket_scatter<<<NBLK_E, 256, 0, stream>>>(ei, bcnt, gcur0, ebuf);

    // ---- fused: gemm layer-0 (hb0 @ Ws0 -> hpb, att dots)  ∥  csr_local ----
    gemm_csr<<<GEMM_BLOCKS + NBUCK, 256, 0, stream>>>(
        hb0, WsT, hpb, atts, asrc, adst, ebuf, bcnt, rowptr, ssrc);

    int g2blk = (N_NODES / 2 + WPB - 1) / WPB;
    // ---- layer 0 gather ----
    gat_gather2<<<g2blk, 64 * WPB, 0, stream>>>(
        rowptr, ssrc, asrc, adst, hpb, biases, hb1);

    // ---- layer 1: gemm + gather ----
    gemm_mfma<false><<<GEMM_BLOCKS, 256, 0, stream>>>(
        hb1, WsT + (size_t)HC * HC, hpb, atts + (size_t)HEADS * 2 * HID,
        asrc, adst, N_NODES, HC);
    gat_gather2<<<g2blk, 64 * WPB, 0, stream>>>(
        rowptr, ssrc, asrc, adst, hpb, biases + HC, hb0);

    // ---- classifier ----
    cls_mfma<<<GEMM_BLOCKS, 256, 0, stream>>>(hb0, woutT, out, N_NODES);
}

// Round 15
// 151.982 us; speedup vs baseline: 1.4205x; 1.0914x over previous
//
#include <hip/hip_runtime.h>
#include <hip/hip_bf16.h>
#include <math.h>

#define N_NODES 50000
#define N_EDGES 800000
#define F_IN 256
#define HID 32
#define HEADS 4
#define HC 128            // HID*HEADS
#define CLASSES 40
#define LAYERS 2
#define SLOPE 0.1f
#define EE (N_EDGES + N_NODES)   // edges + self loops

#define BSHIFT 9
#define NBUCK 98          // ceil(50000 / 512)
#define BCAP 16384        // fixed per-bucket capacity (expected 8674, ~80 sigma headroom)
#define CHUNK 4096        // edges per block in bucket passes
#define NBLK_E ((EE + CHUNK - 1) / CHUNK)
#define GEMM_BLOCKS ((N_NODES + 63) / 64)   // 782

typedef unsigned short ushortT;
typedef unsigned int uintT;
typedef __attribute__((ext_vector_type(8))) short short8v;   // 8 bf16 = 4 VGPRs
typedef __attribute__((ext_vector_type(4))) float f32x4;

__device__ __forceinline__ ushortT f2bu(float f) {
    __hip_bfloat16 h = __float2bfloat16(f);
    ushortT u; __builtin_memcpy(&u, &h, 2); return u;
}

// ---------- weights + gcur zero, one kernel ----------
__global__ void wconv_all(const float* __restrict__ w_in, const float* __restrict__ Ws,
                          const float* __restrict__ w_out, ushortT* __restrict__ w_inT,
                          ushortT* __restrict__ WsT, ushortT* __restrict__ woutT,
                          int* __restrict__ gcur) {
    int i = blockIdx.x * 256 + threadIdx.x;
    if (i < NBUCK) gcur[i] = 0;
    if (i < 32768) {                       // w_in[256][128] -> w_inT[128][256]
        int r = i >> 7, c = i & 127;
        w_inT[(size_t)c * F_IN + r] = f2bu(w_in[i]);
    } else if (i < 65536) {                // Ws[2][128][128] -> WsT[2][128][128]^T
        int j = i - 32768;
        int l = j >> 14, jj = j & 16383;
        int r = jj >> 7, c = jj & 127;
        WsT[l * 16384 + c * 128 + r] = f2bu(Ws[j]);
    } else if (i < 65536 + 6144) {         // w_out[128][40] -> woutT[48][128], pad 0
        int j = i - 65536;
        int c = j >> 7, k = j & 127;
        woutT[j] = (c < CLASSES) ? f2bu(w_out[k * CLASSES + c]) : (ushortT)0;
    }
}

// ---------- MFMA bf16 GEMM body (device fn so it can be fused) ----------
#define AS_LD 40
template<bool AF32>
__device__ __forceinline__ void gemm_body(ushortT* As, ushortT* Bs,
                                          const void* __restrict__ Aptr,
                                          const ushortT* __restrict__ BT,
                                          ushortT* __restrict__ Cb,
                                          const float* __restrict__ att,
                                          float* __restrict__ asrc,
                                          float* __restrict__ adst,
                                          int M, int K, int bid) {
    int t = threadIdx.x;
    int w = t >> 6, lane = t & 63;
    int row0 = bid * 64;
    int ar = t >> 2, ak = (t & 3) * 8;
    int bcol = t >> 1, bks = (t & 1) * 16;
    int wr = w * 16;
    int arow = wr + (lane & 15);
    int ak8 = (lane >> 4) * 8;
    f32x4 acc[8] = {};

    for (int k0 = 0; k0 < K; k0 += 32) {
        int grow = row0 + ar;
        if (AF32) {
            const float* A = (const float*)Aptr;
            float4 v0 = make_float4(0.f, 0.f, 0.f, 0.f), v1 = v0;
            if (grow < M) {
                const float* ap = A + (size_t)grow * K + k0 + ak;
                v0 = *(const float4*)ap;
                v1 = *(const float4*)(ap + 4);
            }
            uint4 p;
            p.x = (uintT)f2bu(v0.x) | ((uintT)f2bu(v0.y) << 16);
            p.y = (uintT)f2bu(v0.z) | ((uintT)f2bu(v0.w) << 16);
            p.z = (uintT)f2bu(v1.x) | ((uintT)f2bu(v1.y) << 16);
            p.w = (uintT)f2bu(v1.z) | ((uintT)f2bu(v1.w) << 16);
            *(uint4*)&As[ar * AS_LD + ak] = p;
        } else {
            const ushortT* A = (const ushortT*)Aptr;
            uint4 p = make_uint4(0, 0, 0, 0);
            if (grow < M) p = *(const uint4*)(A + (size_t)grow * K + k0 + ak);
            *(uint4*)&As[ar * AS_LD + ak] = p;
        }
        {
            const ushortT* bp = BT + (size_t)bcol * K + k0 + bks;
            *(uint4*)&Bs[bcol * AS_LD + bks]     = *(const uint4*)bp;
            *(uint4*)&Bs[bcol * AS_LD + bks + 8] = *(const uint4*)(bp + 8);
        }
        __syncthreads();
        short8v a = *(short8v*)&As[arow * AS_LD + ak8];
#pragma unroll
        for (int c = 0; c < 8; ++c) {
            short8v b = *(short8v*)&Bs[(c * 16 + (lane & 15)) * AS_LD + ak8];
            acc[c] = __builtin_amdgcn_mfma_f32_16x16x32_bf16(a, b, acc[c], 0, 0, 0);
        }
        __syncthreads();
    }
    int cl = lane & 15;
    int r0 = row0 + wr + ((lane >> 4) << 2);
#pragma unroll
    for (int c = 0; c < 8; ++c) {
        int cc = c * 16 + cl;
#pragma unroll
        for (int r = 0; r < 4; ++r) {
            int rr = r0 + r;
            if (rr < M) Cb[(size_t)rr * 128 + cc] = f2bu(acc[c][r]);
        }
    }
    if (att) {
#pragma unroll
        for (int h = 0; h < HEADS; ++h) {
            float as0 = att[h * 64 + cl];
            float as1 = att[h * 64 + 16 + cl];
            float ad0 = att[h * 64 + 32 + cl];
            float ad1 = att[h * 64 + 48 + cl];
#pragma unroll
            for (int r = 0; r < 4; ++r) {
                float ps = acc[2 * h][r] * as0 + acc[2 * h + 1][r] * as1;
                float pd = acc[2 * h][r] * ad0 + acc[2 * h + 1][r] * ad1;
#pragma unroll
                for (int off = 1; off < 16; off <<= 1) {
                    ps += __shfl_xor(ps, off);
                    pd += __shfl_xor(pd, off);
                }
                int rr = r0 + r;
                if (cl == 0 && rr < M) {
                    asrc[rr * 4 + h] = ps;
                    adst[rr * 4 + h] = pd;
                }
            }
        }
    }
}

// standalone GEMM (layer 1)
template<bool AF32>
__global__ __launch_bounds__(256) void gemm_mfma(const void* __restrict__ Aptr,
                                                 const ushortT* __restrict__ BT,
                                                 ushortT* __restrict__ Cb,
                                                 const float* __restrict__ att,
                                                 float* __restrict__ asrc,
                                                 float* __restrict__ adst,
                                                 int M, int K) {
    __shared__ ushortT As[64 * AS_LD];
    __shared__ ushortT Bs[128 * AS_LD];
    gemm_body<AF32>(As, Bs, Aptr, BT, Cb, att, asrc, adst, M, K, blockIdx.x);
}

// ---------- fused: gemm0 (x @ w_in) + bucket_scatter (fixed-capacity buckets) ----------
__global__ __launch_bounds__(256) void gemm0_scatter(const float* __restrict__ x,
                                                     const ushortT* __restrict__ w_inT,
                                                     ushortT* __restrict__ hb0,
                                                     const int* __restrict__ ei,
                                                     int* __restrict__ gcur,
                                                     uintT* __restrict__ ebuf) {
    __shared__ ushortT As[64 * AS_LD];
    __shared__ ushortT Bs[128 * AS_LD];
    __shared__ int hist[NBUCK];
    __shared__ int rbase[NBUCK];
    if (blockIdx.x < GEMM_BLOCKS) {
        gemm_body<true>(As, Bs, x, w_inT, hb0, nullptr, nullptr, nullptr,
                        N_NODES, F_IN, blockIdx.x);
    } else {
        int t = threadIdx.x;
        if (t < NBUCK) hist[t] = 0;
        __syncthreads();
        int base = (blockIdx.x - GEMM_BLOCKS) * CHUNK;
        int end = min(base + CHUNK, EE);
        for (int i = base + t; i < end; i += 256) {
            int d = (i < N_EDGES) ? ei[N_EDGES + i] : (i - N_EDGES);
            atomicAdd(&hist[d >> BSHIFT], 1);
        }
        __syncthreads();
        if (t < NBUCK) {
            int c = hist[t];
            rbase[t] = c ? (t * BCAP + atomicAdd(&gcur[t], c)) : 0;
        }
        __syncthreads();
        if (t < NBUCK) hist[t] = 0;
        __syncthreads();
        for (int i = base + t; i < end; i += 256) {
            int s, d;
            if (i < N_EDGES) { s = ei[i]; d = ei[N_EDGES + i]; } else { s = d = i - N_EDGES; }
            int b = d >> BSHIFT;
            int pos = rbase[b] + atomicAdd(&hist[b], 1);
            ebuf[pos] = ((uintT)s << BSHIFT) | (uintT)(d & 511);   // src(16b) | local dst(9b)
        }
    }
}

// ---------- csr_local body: bucket b region [b*BCAP, b*BCAP+gcur[b]) ----------
__device__ __forceinline__ void csr_local_body(const uintT* __restrict__ ebuf,
                                               const int* __restrict__ gcur,
                                               int2* __restrict__ rowinfo,
                                               int* __restrict__ ssrc, int b,
                                               int* cnt, int* cur, int* wsum) {
    int t = threadIdx.x;
    int node0 = b << BSHIFT;
    int nb = min(512, N_NODES - node0);
    int beg = b * BCAP;
    int end = beg + gcur[b];
    cnt[t] = 0; cnt[t + 256] = 0;
    __syncthreads();
    for (int i = beg + t; i < end; i += 256)
        atomicAdd(&cnt[ebuf[i] & 511], 1);
    __syncthreads();
    int v0 = cnt[2 * t], v1 = cnt[2 * t + 1];
    int s = v0 + v1;
    int lane = t & 63, w = t >> 6;
    int x = s;
#pragma unroll
    for (int off = 1; off < 64; off <<= 1) { int y = __shfl_up(x, off); if (lane >= off) x += y; }
    if (lane == 63) wsum[w] = x;
    __syncthreads();
    if (t == 0) { int run = 0; for (int k = 0; k < 4; ++k) { int tmp = wsum[k]; wsum[k] = run; run += tmp; } }
    __syncthreads();
    int excl = wsum[w] + x - s;
    cnt[2 * t] = excl; cnt[2 * t + 1] = excl + v0;
    cur[2 * t] = excl; cur[2 * t + 1] = excl + v0;
    if (2 * t < nb)     rowinfo[node0 + 2 * t]     = make_int2(beg + excl, v0);
    if (2 * t + 1 < nb) rowinfo[node0 + 2 * t + 1] = make_int2(beg + excl + v0, v1);
    __syncthreads();
    for (int i = beg + t; i < end; i += 256) {
        uintT e = ebuf[i];
        int pos = beg + atomicAdd(&cur[e & 511], 1);
        ssrc[pos] = (int)(e >> BSHIFT);
    }
}

// ---------- fused: gemm layer-0 + csr_local ----------
__global__ __launch_bounds__(256) void gemm_csr(const ushortT* __restrict__ hin,
                                                const ushortT* __restrict__ BT,
                                                ushortT* __restrict__ hpb,
                                                const float* __restrict__ att,
                                                float* __restrict__ asrc,
                                                float* __restrict__ adst,
                                                const uintT* __restrict__ ebuf,
                                                const int* __restrict__ gcur,
                                                int2* __restrict__ rowinfo,
                                                int* __restrict__ ssrc) {
    __shared__ ushortT As[64 * AS_LD];
    __shared__ ushortT Bs[128 * AS_LD];
    __shared__ int cnt[512];
    __shared__ int cur[512];
    __shared__ int wsum[4];
    if (blockIdx.x < GEMM_BLOCKS) {
        gemm_body<false>(As, Bs, hin, BT, hpb, att, asrc, adst,
                         N_NODES, HC, blockIdx.x);
    } else {
        csr_local_body(ebuf, gcur, rowinfo, ssrc, blockIdx.x - GEMM_BLOCKS,
                       cnt, cur, wsum);
    }
}

// ---------- fused MFMA classifier + in-register log_softmax ----------
__global__ __launch_bounds__(256) void cls_mfma(const ushortT* __restrict__ A,
                                                const ushortT* __restrict__ BT,
                                                float* __restrict__ out, int M) {
    __shared__ ushortT As[64 * AS_LD];
    __shared__ ushortT Bs[48 * AS_LD];
    int t = threadIdx.x;
    int w = t >> 6, lane = t & 63;
    int row0 = blockIdx.x * 64;
    int ar = t >> 2, ak = (t & 3) * 8;
    int wr = w * 16;
    int arow = wr + (lane & 15);
    int ak8 = (lane >> 4) * 8;
    f32x4 acc[3] = {};

    for (int k0 = 0; k0 < 128; k0 += 32) {
        int grow = row0 + ar;
        uint4 p = make_uint4(0, 0, 0, 0);
        if (grow < M) p = *(const uint4*)(A + (size_t)grow * 128 + k0 + ak);
        *(uint4*)&As[ar * AS_LD + ak] = p;
        if (t < 96) {
            int bcol = t >> 1, bks = (t & 1) * 16;
            const ushortT* bp = BT + bcol * 128 + k0 + bks;
            *(uint4*)&Bs[bcol * AS_LD + bks]     = *(const uint4*)bp;
            *(uint4*)&Bs[bcol * AS_LD + bks + 8] = *(const uint4*)(bp + 8);
        }
        __syncthreads();
        short8v a = *(short8v*)&As[arow * AS_LD + ak8];
#pragma unroll
        for (int c = 0; c < 3; ++c) {
            short8v b = *(short8v*)&Bs[(c * 16 + (lane & 15)) * AS_LD + ak8];
            acc[c] = __builtin_amdgcn_mfma_f32_16x16x32_bf16(a, b, acc[c], 0, 0, 0);
        }
        __syncthreads();
    }
    int cl = lane & 15;
    int r0 = row0 + wr + ((lane >> 4) << 2);
#pragma unroll
    for (int r = 0; r < 4; ++r) {
        float v0 = acc[0][r], v1 = acc[1][r];
        float v2 = (cl < 8) ? acc[2][r] : -1e30f;
        float m = fmaxf(fmaxf(v0, v1), v2);
#pragma unroll
        for (int off = 1; off < 16; off <<= 1) m = fmaxf(m, __shfl_xor(m, off));
        float e = __expf(v0 - m) + __expf(v1 - m) + ((cl < 8) ? __expf(v2 - m) : 0.f);
#pragma unroll
        for (int off = 1; off < 16; off <<= 1) e += __shfl_xor(e, off);
        float ls = m + __logf(e);
        int rr = r0 + r;
        if (rr < M) {
            float* o = out + (size_t)rr * CLASSES;
            o[cl] = v0 - ls;
            o[16 + cl] = v1 - ls;
            if (cl < 8) o[32 + cl] = v2 - ls;
        }
    }
}

// ---------- GAT aggregate ----------
__device__ __forceinline__ float lrelu(float v) { return v > 0.f ? v : SLOPE * v; }

// single-node path (R10-proven): full wave on one node
__device__ __forceinline__ void gat_one(
    int node, int beg, int deg, int lane,
    const int* __restrict__ ssrc, const float* __restrict__ asrc,
    const float* __restrict__ adst, const ushortT* __restrict__ hpb,
    const float* __restrict__ bias, ushortT* __restrict__ foutB,
    float* sexp, int* ssrcl, float* sm)
{
    float4 ad = *(const float4*)(adst + (size_t)node * 4);
    int g = lane >> 4, i0 = lane & 15;
    float acc0 = 0.f, acc1 = 0.f;
    float zinv;
    const ushortT* hrow = hpb + lane * 2;

    if (deg <= 64) {
        float4 lg = make_float4(-1e30f, -1e30f, -1e30f, -1e30f);
        int soff = 0;
        if (lane < deg) {
            int s = ssrc[beg + lane];
            float4 a = *(const float4*)(asrc + (size_t)s * 4);
            lg.x = lrelu(a.x + ad.x);
            lg.y = lrelu(a.y + ad.y);
            lg.z = lrelu(a.z + ad.z);
            lg.w = lrelu(a.w + ad.w);
            soff = s * HC;
        }
        ssrcl[lane] = soff;
        *(float4*)&sexp[lane * 4] = lg;
        asm volatile("s_waitcnt lgkmcnt(0)" ::: "memory");
        float mg =     sexp[i0 * 4 + g];
        mg = fmaxf(mg, sexp[(i0 + 16) * 4 + g]);
        mg = fmaxf(mg, sexp[(i0 + 32) * 4 + g]);
        mg = fmaxf(mg, sexp[(i0 + 48) * 4 + g]);
#pragma unroll
        for (int off = 1; off < 16; off <<= 1) mg = fmaxf(mg, __shfl_xor(mg, off));
        if (i0 == 0) sm[g] = mg;
        asm volatile("s_waitcnt lgkmcnt(0)" ::: "memory");
        float4 m = *(float4*)&sm[0];
        float4 ex;
        ex.x = __expf(lg.x - m.x);
        ex.y = __expf(lg.y - m.y);
        ex.z = __expf(lg.z - m.z);
        ex.w = __expf(lg.w - m.w);
        *(float4*)&sexp[lane * 4] = ex;
        asm volatile("s_waitcnt lgkmcnt(0)" ::: "memory");
        float zg = sexp[i0 * 4 + g];
        zg +=      sexp[(i0 + 16) * 4 + g];
        zg +=      sexp[(i0 + 32) * 4 + g];
        zg +=      sexp[(i0 + 48) * 4 + g];
#pragma unroll
        for (int off = 1; off < 16; off <<= 1) zg += __shfl_xor(zg, off);
        zinv = 1.f / zg;
#pragma unroll 4
        for (int i = 0; i < deg; ++i) {
            float e = sexp[i * 4 + g];
            int off = ssrcl[i];
            uintT u = *(const uintT*)(hrow + off);
            acc0 = fmaf(__uint_as_float(u << 16),         e, acc0);
            acc1 = fmaf(__uint_as_float(u & 0xffff0000u), e, acc1);
        }
    } else {
        float4 m = make_float4(-1e30f, -1e30f, -1e30f, -1e30f);
        for (int i = lane; i < deg; i += 64) {
            int s = ssrc[beg + i];
            float4 a = *(const float4*)(asrc + (size_t)s * 4);
            m.x = fmaxf(m.x, lrelu(a.x + ad.x));
            m.y = fmaxf(m.y, lrelu(a.y + ad.y));
            m.z = fmaxf(m.z, lrelu(a.z + ad.z));
            m.w = fmaxf(m.w, lrelu(a.w + ad.w));
        }
#pragma unroll
        for (int off = 1; off < 64; off <<= 1) {
            m.x = fmaxf(m.x, __shfl_xor(m.x, off));
            m.y = fmaxf(m.y, __shfl_xor(m.y, off));
            m.z = fmaxf(m.z, __shfl_xor(m.z, off));
            m.w = fmaxf(m.w, __shfl_xor(m.w, off));
        }
        float4 zp = make_float4(0.f, 0.f, 0.f, 0.f);
        for (int c0 = 0; c0 < deg; c0 += 64) {
            int n_ch = min(64, deg - c0);
            if (lane < n_ch) {
                int s = ssrc[beg + c0 + lane];
                float4 a = *(const float4*)(asrc + (size_t)s * 4);
                float4 ex;
                ex.x = __expf(lrelu(a.x + ad.x) - m.x);
                ex.y = __expf(lrelu(a.y + ad.y) - m.y);
                ex.z = __expf(lrelu(a.z + ad.z) - m.z);
                ex.w = __expf(lrelu(a.w + ad.w) - m.w);
                *(float4*)&sexp[lane * 4] = ex;
                ssrcl[lane] = s * HC;
                zp.x += ex.x; zp.y += ex.y; zp.z += ex.z; zp.w += ex.w;
            }
            asm volatile("s_waitcnt lgkmcnt(0)" ::: "memory");
#pragma unroll 4
            for (int i = 0; i < n_ch; ++i) {
                float e = sexp[i * 4 + g];
                int off = ssrcl[i];
                uintT u = *(const uintT*)(hrow + off);
                acc0 = fmaf(__uint_as_float(u << 16),         e, acc0);
                acc1 = fmaf(__uint_as_float(u & 0xffff0000u), e, acc1);
            }
        }
#pragma unroll
        for (int off = 1; off < 64; off <<= 1) {
            zp.x += __shfl_xor(zp.x, off);
            zp.y += __shfl_xor(zp.y, off);
            zp.z += __shfl_xor(zp.z, off);
            zp.w += __shfl_xor(zp.w, off);
        }
        float zh = (g == 0) ? zp.x : (g == 1) ? zp.y : (g == 2) ? zp.z : zp.w;
        zinv = 1.f / zh;
    }

    float b0 = bias[lane * 2], b1 = bias[lane * 2 + 1];
    float v0 = acc0 * zinv + b0; v0 = v0 > 0.f ? v0 : __expf(v0) - 1.f;
    float v1 = acc1 * zinv + b1; v1 = v1 > 0.f ? v1 : __expf(v1) - 1.f;
    *(uintT*)(foutB + (size_t)node * HC + lane * 2) =
        (uintT)f2bu(v0) | ((uintT)f2bu(v1) << 16);
}

// paired kernel: each wave serves 2 consecutive nodes (deg<=32 each, 99.96% of pairs)
#define WPB 4   // waves per block
__global__ __launch_bounds__(256) void gat_gather2(
    const int2* __restrict__ rowinfo, const int* __restrict__ ssrc,
    const float* __restrict__ asrc, const float* __restrict__ adst,
    const ushortT* __restrict__ hpb, const float* __restrict__ bias,
    ushortT* __restrict__ foutB)
{
    __shared__ __align__(16) float s_exp[WPB][64][4];
    __shared__ int   s_src[WPB][64];
    __shared__ __align__(16) float s_m[WPB][8];
    __shared__ __align__(16) float s_z[WPB][8];
    int w = threadIdx.x >> 6;
    int lane = threadIdx.x & 63;
    int widx = blockIdx.x * WPB + w;
    int n0 = widx * 2;
    if (n0 >= N_NODES) return;
    int2 ri0 = rowinfo[n0];
    int2 ri1 = rowinfo[n0 + 1];
    int beg0 = ri0.x, deg0 = ri0.y;
    int beg1 = ri1.x, deg1 = ri1.y;

    if (deg0 <= 32 && deg1 <= 32) {
        int half = lane >> 5;        // which node this lane serves
        int ll = lane & 31;
        int nn = n0 + half;
        int mybeg = half ? beg1 : beg0;
        int mydeg = half ? deg1 : deg0;
        float4 ad = *(const float4*)(adst + (size_t)nn * 4);
        // ---- edge logits (slot ll = edge index) ----
        float4 lg = make_float4(-1e30f, -1e30f, -1e30f, -1e30f);
        int soff = 0;
        if (ll < mydeg) {
            int s = ssrc[mybeg + ll];
            float4 a = *(const float4*)(asrc + (size_t)s * 4);
            lg.x = lrelu(a.x + ad.x);
            lg.y = lrelu(a.y + ad.y);
            lg.z = lrelu(a.z + ad.z);
            lg.w = lrelu(a.w + ad.w);
            soff = s * HC;
        }
        s_src[w][lane] = soff;
        *(float4*)&s_exp[w][lane][0] = lg;
        asm volatile("s_waitcnt lgkmcnt(0)" ::: "memory");
        // ---- 8-group transpose max: grp = (node,head), 8 lanes each ----
        int grp = lane >> 3, gi = lane & 7;
        int gbase = (grp >> 2) << 5;   // 0 or 32
        int gh = grp & 3;
        float mg =     s_exp[w][gbase + gi][gh];
        mg = fmaxf(mg, s_exp[w][gbase + gi +  8][gh]);
        mg = fmaxf(mg, s_exp[w][gbase + gi + 16][gh]);
        mg = fmaxf(mg, s_exp[w][gbase + gi + 24][gh]);
        mg = fmaxf(mg, __shfl_xor(mg, 1));
        mg = fmaxf(mg, __shfl_xor(mg, 2));
        mg = fmaxf(mg, __shfl_xor(mg, 4));
        if (gi == 0) s_m[w][grp] = mg;
        asm volatile("s_waitcnt lgkmcnt(0)" ::: "memory");
        float4 m = *(float4*)&s_m[w][half * 4];
        float4 ex;
        ex.x = __expf(lg.x - m.x);   // pad slots: lg=-1e30 -> 0
        ex.y = __expf(lg.y - m.y);
        ex.z = __expf(lg.z - m.z);
        ex.w = __expf(lg.w - m.w);
        *(float4*)&s_exp[w][lane][0] = ex;
        asm volatile("s_waitcnt lgkmcnt(0)" ::: "memory");
        // ---- 8-group transpose sum for z ----
        float zg = s_exp[w][gbase + gi][gh];
        zg +=      s_exp[w][gbase + gi +  8][gh];
        zg +=      s_exp[w][gbase + gi + 16][gh];
        zg +=      s_exp[w][gbase + gi + 24][gh];
        zg += __shfl_xor(zg, 1);
        zg += __shfl_xor(zg, 2);
        zg += __shfl_xor(zg, 4);
        if (gi == 0) s_z[w][grp] = zg;
        asm volatile("s_waitcnt lgkmcnt(0)" ::: "memory");
        int hd = ll >> 3;            // head of this lane's 4 channels
        float zinv = 1.f / s_z[w][half * 4 + hd];
        // ---- gather: lane owns channels ll*4..+3 of its node; pad edges have e=0 ----
        int maxdeg = max(deg0, deg1);
        int ebase = half << 5;
        const ushortT* hrow = hpb + ll * 4;
        float a0 = 0.f, a1 = 0.f, a2 = 0.f, a3 = 0.f;
#pragma unroll 4
        for (int i = 0; i < maxdeg; ++i) {
            float e = s_exp[w][ebase + i][hd];
            int off = s_src[w][ebase + i];
            uint2 u = *(const uint2*)(hrow + off);
            a0 = fmaf(__uint_as_float(u.x << 16),         e, a0);
            a1 = fmaf(__uint_as_float(u.x & 0xffff0000u), e, a1);
            a2 = fmaf(__uint_as_float(u.y << 16),         e, a2);
            a3 = fmaf(__uint_as_float(u.y & 0xffff0000u), e, a3);
        }
        // ---- normalize + bias + ELU + store (no cross-lane reduce needed) ----
        const float* bp = bias + ll * 4;
        float v0 = a0 * zinv + bp[0]; v0 = v0 > 0.f ? v0 : __expf(v0) - 1.f;
        float v1 = a1 * zinv + bp[1]; v1 = v1 > 0.f ? v1 : __expf(v1) - 1.f;
        float v2 = a2 * zinv + bp[2]; v2 = v2 > 0.f ? v2 : __expf(v2) - 1.f;
        float v3 = a3 * zinv + bp[3]; v3 = v3 > 0.f ? v3 : __expf(v3) - 1.f;
        uint2 o;
        o.x = (uintT)f2bu(v0) | ((uintT)f2bu(v1) << 16);
        o.y = (uintT)f2bu(v2) | ((uintT)f2bu(v3) << 16);
        *(uint2*)(foutB + (size_t)nn * HC + ll * 4) = o;
    } else {
        // rare: run the proven single-node path for each node sequentially
        gat_one(n0,     beg0, deg0, lane, ssrc, asrc, adst, hpb, bias, foutB,
                &s_exp[w][0][0], &s_src[w][0], &s_m[w][0]);
        gat_one(n0 + 1, beg1, deg1, lane, ssrc, asrc, adst, hpb, bias, foutB,
                &s_exp[w][0][0], &s_src[w][0], &s_m[w][0]);
    }
}

extern "C" void kernel_launch(void* const* d_in, const int* in_sizes, int n_in,
                              void* d_out, int out_size, void* d_ws, size_t ws_size,
                              hipStream_t stream) {
    const float* x      = (const float*)d_in[0];
    const int*   ei     = (const int*)d_in[1];
    const float* w_in   = (const float*)d_in[2];
    const float* Ws     = (const float*)d_in[3];
    const float* atts   = (const float*)d_in[4];
    const float* biases = (const float*)d_in[5];
    const float* w_out  = (const float*)d_in[6];
    float* out = (float*)d_out;

    // workspace partition
    char* wp = (char*)d_ws;
    ushortT* hb0 = (ushortT*)wp; wp += (size_t)N_NODES * HC * 2;   // bf16 h / final gat out
    ushortT* hb1 = (ushortT*)wp; wp += (size_t)N_NODES * HC * 2;   // bf16 gat_l0 out
    ushortT* hpb = (ushortT*)wp; wp += (size_t)N_NODES * HC * 2;   // bf16 hp
    float* asrc  = (float*)wp;   wp += (size_t)N_NODES * HEADS * 4;
    float* adst  = (float*)wp;   wp += (size_t)N_NODES * HEADS * 4;
    int2* rowinfo = (int2*)wp;   wp += (size_t)N_NODES * 8;
    int* ssrc    = (int*)wp;     wp += (size_t)NBUCK * BCAP * 4;
    uintT* ebuf  = (uintT*)wp;   wp += (size_t)NBUCK * BCAP * 4;
    int* gcur    = (int*)wp;     wp += (size_t)(NBUCK + 4) * 4;
    ushortT* w_inT = (ushortT*)wp; wp += (size_t)HC * F_IN * 2;
    ushortT* WsT   = (ushortT*)wp; wp += (size_t)LAYERS * HC * HC * 2;
    ushortT* woutT = (ushortT*)wp; wp += (size_t)48 * HC * 2;

    // ---- prep: weights + gcur zero ----
    wconv_all<<<(32768 + 32768 + 6144 + 255) / 256, 256, 0, stream>>>(
        w_in, Ws, w_out, w_inT, WsT, woutT, gcur);

    // ---- fused: gemm0 (x @ w_in -> hb0)  ∥  bucket_scatter (fixed-cap) ----
    gemm0_scatter<<<GEMM_BLOCKS + NBLK_E, 256, 0, stream>>>(x, w_inT, hb0, ei, gcur, ebuf);

    // ---- fused: gemm layer-0 (hb0 @ Ws0 -> hpb, att dots)  ∥  csr_local ----
    gemm_csr<<<GEMM_BLOCKS + NBUCK, 256, 0, stream>>>(
        hb0, WsT, hpb, atts, asrc, adst, ebuf, gcur, rowinfo, ssrc);

    int g2blk = (N_NODES / 2 + WPB - 1) / WPB;
    // ---- layer 0 gather ----
    gat_gather2<<<g2blk, 64 * WPB, 0, stream>>>(
        rowinfo, ssrc, asrc, adst, hpb, biases, hb1);

    // ---- layer 1: gemm + gather ----
    gemm_mfma<false><<<GEMM_BLOCKS, 256, 0, stream>>>(
        hb1, WsT + (size_t)HC * HC, hpb, atts + (size_t)HEADS * 2 * HID,
        asrc, adst, N_NODES, HC);
    gat_gather2<<<g2blk, 64 * WPB, 0, stream>>>(
        rowinfo, ssrc, asrc, adst, hpb, biases + HC, hb0);

    // ---- classifier ----
    cls_mfma<<<GEMM_BLOCKS, 256, 0, stream>>>(hb0, woutT, out, N_NODES);
}